// Round 2
// baseline (7581.786 us; speedup 1.0000x reference)
//
#include <hip/hip_runtime.h>
#include <math.h>

#define NB 2048
#define NS 100
#define NF 158
#define ND 512
#define NH 8
#define CB 256                 // batches per chunk
#define NCHUNK (NB / CB)       // 8
#define CM (CB * NS)           // 25600 rows per chunk

// ---------------------------------------------------------------------------
// prep_w: Wqf/Wkf/Wvf[r,f] = sum_d W{q,k,v}[r,d] * W_feat[d,f]   ([512,158])
// ---------------------------------------------------------------------------
__global__ __launch_bounds__(256) void prep_w_kernel(
    const float* __restrict__ Wq, const float* __restrict__ Wk,
    const float* __restrict__ Wv, const float* __restrict__ Wf,
    float* __restrict__ Wqf, float* __restrict__ Wkf, float* __restrict__ Wvf)
{
    int bid = blockIdx.x;           // 0..1535
    int sel = bid >> 9;
    int r = bid & 511;
    const float* Wsrc = (sel == 0) ? Wq : (sel == 1) ? Wk : Wv;
    float* Wdst = (sel == 0) ? Wqf : (sel == 1) ? Wkf : Wvf;
    __shared__ float wrow[ND];
    int t = threadIdx.x;
    wrow[t] = Wsrc[(size_t)r * ND + t];
    wrow[t + 256] = Wsrc[(size_t)r * ND + t + 256];
    __syncthreads();
    if (t < NF) {
        float acc = 0.f;
        for (int d = 0; d < ND; ++d)
            acc += wrow[d] * Wf[(size_t)d * NF + t];   // coalesced across t
        Wdst[(size_t)r * NF + t] = acc;
    }
}

// ---------------------------------------------------------------------------
// prep_c: C{q,k,v}[s,r] = sum_d (b_feat[d]+pe[s,d]) * W[r,d] + b[r]  ([100,512])
// ---------------------------------------------------------------------------
__global__ __launch_bounds__(256) void prep_c_kernel(
    const float* __restrict__ Wq, const float* __restrict__ Wk, const float* __restrict__ Wv,
    const float* __restrict__ bq, const float* __restrict__ bk, const float* __restrict__ bv,
    const float* __restrict__ bfeat, const float* __restrict__ pe,
    float* __restrict__ Cq, float* __restrict__ Ck, float* __restrict__ Cv)
{
    int bid = blockIdx.x;           // 0..299
    int sel = bid / 100;
    int s = bid - sel * 100;
    const float* Wsrc = (sel == 0) ? Wq : (sel == 1) ? Wk : Wv;
    const float* bsrc = (sel == 0) ? bq : (sel == 1) ? bk : bv;
    float* dst = (sel == 0) ? Cq : (sel == 1) ? Ck : Cv;
    __shared__ float xv[ND];
    int t = threadIdx.x;
    xv[t] = bfeat[t] + pe[(size_t)s * ND + t];
    xv[t + 256] = bfeat[t + 256] + pe[(size_t)s * ND + t + 256];
    __syncthreads();
    #pragma unroll
    for (int rr = 0; rr < 2; ++rr) {
        int r = t + (rr << 8);
        const float* wr = Wsrc + (size_t)r * ND;
        float acc = bsrc[r];
        for (int d = 0; d < ND; d += 4) {
            float4 w4 = *(const float4*)(wr + d);
            acc += w4.x * xv[d] + w4.y * xv[d+1] + w4.z * xv[d+2] + w4.w * xv[d+3];
        }
        dst[(size_t)s * ND + r] = acc;
    }
}

// ---------------------------------------------------------------------------
// Tiled SGEMM: C[M,N] = A[M,K] @ W[N,K]^T (+bias[n]) (+tab[m%100, n]) (+relu)
// 128x128 tile, TK=8, 256 threads, 8x8 per thread (4 quadrants of 4x4).
// M must be a multiple of 128. N,K arbitrary (guarded).
// ---------------------------------------------------------------------------
template<bool K4, bool N4, bool RELU, bool ADDTAB>
__global__ __launch_bounds__(256) void gemm_tn(
    const float* __restrict__ A, const float* __restrict__ W,
    const float* __restrict__ bias, const float* __restrict__ tab,
    float* __restrict__ C, int M, int N, int K)
{
    __shared__ float As[8][128];
    __shared__ float Bs[8][128];
    int t = threadIdx.x;
    int tx = t & 15, ty = t >> 4;
    int m0 = blockIdx.y << 7;
    int n0 = blockIdx.x << 7;

    float acc[2][2][4][4];
    #pragma unroll
    for (int a = 0; a < 2; ++a)
        #pragma unroll
        for (int b2 = 0; b2 < 2; ++b2)
            #pragma unroll
            for (int i = 0; i < 4; ++i)
                #pragma unroll
                for (int j = 0; j < 4; ++j) acc[a][b2][i][j] = 0.f;

    int lrow = t >> 1;              // 0..127
    int lkq = (t & 1) << 2;         // 0 or 4
    const float* Arow = A + (size_t)(m0 + lrow) * K + lkq;
    int wr = n0 + lrow;
    bool wvalid = wr < N;
    const float* Wrow = W + (size_t)wr * K + lkq;

    int KT = (K + 7) >> 3;
    for (int kt = 0; kt < KT; ++kt) {
        int kbase = (kt << 3) + lkq;
        float a0, a1, a2, a3, w0, w1, w2, w3;
        if (K4) {
            float4 av = *(const float4*)(Arow + (kt << 3));
            a0 = av.x; a1 = av.y; a2 = av.z; a3 = av.w;
            if (wvalid) {
                float4 w4 = *(const float4*)(Wrow + (kt << 3));
                w0 = w4.x; w1 = w4.y; w2 = w4.z; w3 = w4.w;
            } else { w0 = w1 = w2 = w3 = 0.f; }
        } else {
            a0 = (kbase + 0 < K) ? Arow[(kt << 3) + 0] : 0.f;
            a1 = (kbase + 1 < K) ? Arow[(kt << 3) + 1] : 0.f;
            a2 = (kbase + 2 < K) ? Arow[(kt << 3) + 2] : 0.f;
            a3 = (kbase + 3 < K) ? Arow[(kt << 3) + 3] : 0.f;
            w0 = (wvalid && kbase + 0 < K) ? Wrow[(kt << 3) + 0] : 0.f;
            w1 = (wvalid && kbase + 1 < K) ? Wrow[(kt << 3) + 1] : 0.f;
            w2 = (wvalid && kbase + 2 < K) ? Wrow[(kt << 3) + 2] : 0.f;
            w3 = (wvalid && kbase + 3 < K) ? Wrow[(kt << 3) + 3] : 0.f;
        }
        __syncthreads();
        As[lkq + 0][lrow] = a0; As[lkq + 1][lrow] = a1;
        As[lkq + 2][lrow] = a2; As[lkq + 3][lrow] = a3;
        Bs[lkq + 0][lrow] = w0; Bs[lkq + 1][lrow] = w1;
        Bs[lkq + 2][lrow] = w2; Bs[lkq + 3][lrow] = w3;
        __syncthreads();
        #pragma unroll
        for (int kk = 0; kk < 8; ++kk) {
            float4 af0 = *(const float4*)&As[kk][ty << 2];
            float4 af1 = *(const float4*)&As[kk][64 + (ty << 2)];
            float4 bf0 = *(const float4*)&Bs[kk][tx << 2];
            float4 bf1 = *(const float4*)&Bs[kk][64 + (tx << 2)];
            float ar[2][4] = {{af0.x, af0.y, af0.z, af0.w}, {af1.x, af1.y, af1.z, af1.w}};
            float br[2][4] = {{bf0.x, bf0.y, bf0.z, bf0.w}, {bf1.x, bf1.y, bf1.z, bf1.w}};
            #pragma unroll
            for (int a = 0; a < 2; ++a)
                #pragma unroll
                for (int i = 0; i < 4; ++i)
                    #pragma unroll
                    for (int b2 = 0; b2 < 2; ++b2)
                        #pragma unroll
                        for (int j = 0; j < 4; ++j)
                            acc[a][b2][i][j] += ar[a][i] * br[b2][j];
        }
    }

    #pragma unroll
    for (int a = 0; a < 2; ++a) {
        #pragma unroll
        for (int i = 0; i < 4; ++i) {
            int r = m0 + (a << 6) + (ty << 2) + i;
            float* Crow = C + (size_t)r * N;
            const float* trow = nullptr;
            if (ADDTAB) { int s = r % NS; trow = tab + (size_t)s * ND; }
            #pragma unroll
            for (int b2 = 0; b2 < 2; ++b2) {
                int c = n0 + (b2 << 6) + (tx << 2);
                if (N4) {
                    float4 v;
                    v.x = acc[a][b2][i][0]; v.y = acc[a][b2][i][1];
                    v.z = acc[a][b2][i][2]; v.w = acc[a][b2][i][3];
                    if (bias) {
                        float4 bv4 = *(const float4*)(bias + c);
                        v.x += bv4.x; v.y += bv4.y; v.z += bv4.z; v.w += bv4.w;
                    }
                    if (ADDTAB) {
                        float4 tv = *(const float4*)(trow + c);
                        v.x += tv.x; v.y += tv.y; v.z += tv.z; v.w += tv.w;
                    }
                    if (RELU) {
                        v.x = fmaxf(v.x, 0.f); v.y = fmaxf(v.y, 0.f);
                        v.z = fmaxf(v.z, 0.f); v.w = fmaxf(v.w, 0.f);
                    }
                    *(float4*)(Crow + c) = v;
                } else {
                    #pragma unroll
                    for (int j = 0; j < 4; ++j) {
                        int cc = c + j;
                        if (cc < N) {
                            float v = acc[a][b2][i][j];
                            if (bias) v += bias[cc];
                            if (ADDTAB) v += trow[cc];
                            if (RELU) v = fmaxf(v, 0.f);
                            Crow[cc] = v;
                        }
                    }
                }
            }
        }
    }
}

// ---------------------------------------------------------------------------
// Attention: one block per (b_local,h). Q/K/V head slices staged to LDS,
// scores+softmax in LDS, P@V back to global. O may alias Q (block-private).
// LDS: 30.5+30.5+27.2+50.6 KB = 138.8 KB < 160 KB (1 block/CU).
// ---------------------------------------------------------------------------
__global__ __launch_bounds__(256) void attn_kernel(
    const float* __restrict__ Q, const float* __restrict__ Kb,
    const float* __restrict__ V, float* __restrict__ O)
{
    __shared__ float Qs[112][68];
    __shared__ float Ks[112][68];
    __shared__ float Vs[100][68];
    __shared__ float Ps[112][113];

    int t = threadIdx.x;
    int bh = blockIdx.x;
    int b = bh >> 3, h = bh & 7;
    const size_t base = (size_t)b * NS * ND + (size_t)(h << 6);

    for (int l = t; l < 1600; l += 256) {       // 100*64/4 float4s
        int s = l >> 4;
        int cq = (l & 15) << 2;
        const size_t g = base + (size_t)s * ND + cq;
        *(float4*)&Qs[s][cq] = *(const float4*)(Q + g);
        *(float4*)&Ks[s][cq] = *(const float4*)(Kb + g);
        *(float4*)&Vs[s][cq] = *(const float4*)(V + g);
    }
    for (int l = t; l < 12 * 64; l += 256) {    // zero pad rows 100..111
        int s = 100 + (l >> 6);
        int c = l & 63;
        Qs[s][c] = 0.f; Ks[s][c] = 0.f;
    }
    __syncthreads();

    int ti = t >> 4, tj = t & 15;
    float sc[7][7];
    #pragma unroll
    for (int m = 0; m < 7; ++m)
        #pragma unroll
        for (int n = 0; n < 7; ++n) sc[m][n] = 0.f;

    for (int k = 0; k < 64; ++k) {
        float qf[7], kf[7];
        #pragma unroll
        for (int m = 0; m < 7; ++m) qf[m] = Qs[ti + (m << 4)][k];
        #pragma unroll
        for (int n = 0; n < 7; ++n) kf[n] = Ks[tj + (n << 4)][k];
        #pragma unroll
        for (int m = 0; m < 7; ++m)
            #pragma unroll
            for (int n = 0; n < 7; ++n) sc[m][n] += qf[m] * kf[n];
    }
    #pragma unroll
    for (int m = 0; m < 7; ++m)
        #pragma unroll
        for (int n = 0; n < 7; ++n) Ps[ti + (m << 4)][tj + (n << 4)] = sc[m][n];
    __syncthreads();

    if (t < NS) {   // softmax over row t (scale 1/8 applied in exp)
        float mx = -3.0e38f;
        for (int j = 0; j < NS; ++j) mx = fmaxf(mx, Ps[t][j]);
        float sum = 0.f;
        for (int j = 0; j < NS; ++j) {
            float e = expf((Ps[t][j] - mx) * 0.125f);
            Ps[t][j] = e; sum += e;
        }
        float inv = 1.f / sum;
        for (int j = 0; j < NS; ++j) Ps[t][j] *= inv;
    }
    __syncthreads();

    float4 o[7];
    #pragma unroll
    for (int m = 0; m < 7; ++m) o[m] = make_float4(0.f, 0.f, 0.f, 0.f);
    for (int j = 0; j < NS; ++j) {
        float4 vv = *(const float4*)&Vs[j][tj << 2];
        #pragma unroll
        for (int m = 0; m < 7; ++m) {
            float p = Ps[ti + (m << 4)][j];
            o[m].x += p * vv.x; o[m].y += p * vv.y;
            o[m].z += p * vv.z; o[m].w += p * vv.w;
        }
    }
    #pragma unroll
    for (int m = 0; m < 7; ++m) {
        int i = ti + (m << 4);
        if (i < NS)
            *(float4*)(O + base + (size_t)i * ND + (tj << 2)) = o[m];
    }
}

// ---------------------------------------------------------------------------
// y = x + LayerNorm(x)*w + b   — one wave per 512-float row, 4 rows/block
// ---------------------------------------------------------------------------
__global__ __launch_bounds__(256) void lnadd_kernel(
    const float* __restrict__ X, const float* __restrict__ lw,
    const float* __restrict__ lb, float* __restrict__ Y)
{
    int wid = threadIdx.x >> 6, lane = threadIdx.x & 63;
    size_t row = (size_t)blockIdx.x * 4 + wid;
    const float* x = X + row * ND;
    float* y = Y + row * ND;
    int c0 = lane << 2;
    float4 v0 = *(const float4*)(x + c0);
    float4 v1 = *(const float4*)(x + 256 + c0);
    float s = v0.x + v0.y + v0.z + v0.w + v1.x + v1.y + v1.z + v1.w;
    float q = v0.x*v0.x + v0.y*v0.y + v0.z*v0.z + v0.w*v0.w
            + v1.x*v1.x + v1.y*v1.y + v1.z*v1.z + v1.w*v1.w;
    #pragma unroll
    for (int off = 32; off > 0; off >>= 1) {
        s += __shfl_xor(s, off);
        q += __shfl_xor(q, off);
    }
    float mean = s * (1.f / 512.f);
    float var = q * (1.f / 512.f) - mean * mean;
    float rstd = rsqrtf(var + 1e-5f);
    float4 w0 = *(const float4*)(lw + c0), w1 = *(const float4*)(lw + 256 + c0);
    float4 b0 = *(const float4*)(lb + c0), b1 = *(const float4*)(lb + 256 + c0);
    float4 r0, r1;
    r0.x = v0.x + (v0.x - mean) * rstd * w0.x + b0.x;
    r0.y = v0.y + (v0.y - mean) * rstd * w0.y + b0.y;
    r0.z = v0.z + (v0.z - mean) * rstd * w0.z + b0.z;
    r0.w = v0.w + (v0.w - mean) * rstd * w0.w + b0.w;
    r1.x = v1.x + (v1.x - mean) * rstd * w1.x + b1.x;
    r1.y = v1.y + (v1.y - mean) * rstd * w1.y + b1.y;
    r1.z = v1.z + (v1.z - mean) * rstd * w1.z + b1.z;
    r1.w = v1.w + (v1.w - mean) * rstd * w1.w + b1.w;
    *(float4*)(y + c0) = r0;
    *(float4*)(y + 256 + c0) = r1;
}

// ---------------------------------------------------------------------------
// Pooling head, one block per b:
//   t1 = Wt @ y2[b,99];  u = Wt^T @ t1;  lam = softmax_s(y2[b,s]·u);
//   pooled = sum_s lam_s y2[b,s];  out[b] = pooled·W_out + b_out
// ---------------------------------------------------------------------------
__global__ __launch_bounds__(256) void pool_kernel(
    const float* __restrict__ Y2, const float* __restrict__ Wt,
    const float* __restrict__ Wout, const float* __restrict__ bout,
    float* __restrict__ out)
{
    __shared__ float yL[ND];
    __shared__ float t1[ND];
    __shared__ float u[ND];
    __shared__ float lam[128];
    __shared__ float red[4];
    int t = threadIdx.x;
    int b = blockIdx.x;
    const float* y2b = Y2 + (size_t)b * NS * ND;
    yL[t] = y2b[99 * ND + t];
    yL[t + 256] = y2b[99 * ND + t + 256];
    __syncthreads();
    #pragma unroll
    for (int rr = 0; rr < 2; ++rr) {           // t1 = Wt @ yL
        int r = t + (rr << 8);
        const float* wr = Wt + (size_t)r * ND;
        float acc = 0.f;
        for (int k = 0; k < ND; k += 4) {
            float4 w4 = *(const float4*)(wr + k);
            acc += w4.x*yL[k] + w4.y*yL[k+1] + w4.z*yL[k+2] + w4.w*yL[k+3];
        }
        t1[r] = acc;
    }
    __syncthreads();
    #pragma unroll
    for (int cc = 0; cc < 2; ++cc) {           // u = Wt^T @ t1 (coalesced)
        int c = t + (cc << 8);
        float acc = 0.f;
        for (int r = 0; r < ND; ++r)
            acc += Wt[(size_t)r * ND + c] * t1[r];
        u[c] = acc;
    }
    __syncthreads();
    int wid = t >> 6, lane = t & 63;
    int c0 = lane << 2;
    for (int s = wid; s < NS; s += 4) {        // logits
        const float* yr = y2b + (size_t)s * ND;
        float4 p0 = *(const float4*)(yr + c0);
        float4 p1 = *(const float4*)(yr + 256 + c0);
        float a = p0.x*u[c0] + p0.y*u[c0+1] + p0.z*u[c0+2] + p0.w*u[c0+3]
                + p1.x*u[256+c0] + p1.y*u[256+c0+1] + p1.z*u[256+c0+2] + p1.w*u[256+c0+3];
        #pragma unroll
        for (int off = 32; off > 0; off >>= 1) a += __shfl_xor(a, off);
        if (lane == 0) lam[s] = a;
    }
    __syncthreads();
    if (t < 64) {                               // softmax over 100 logits
        float l0 = lam[t];
        float l1 = (t + 64 < NS) ? lam[t + 64] : -3.0e38f;
        float mx = fmaxf(l0, l1);
        #pragma unroll
        for (int off = 32; off > 0; off >>= 1) mx = fmaxf(mx, __shfl_xor(mx, off));
        float e0 = expf(l0 - mx);
        float e1 = (t + 64 < NS) ? expf(l1 - mx) : 0.f;
        float ssum = e0 + e1;
        #pragma unroll
        for (int off = 32; off > 0; off >>= 1) ssum += __shfl_xor(ssum, off);
        float inv = 1.f / ssum;
        lam[t] = e0 * inv;
        if (t + 64 < NS) lam[t + 64] = e1 * inv;
    }
    __syncthreads();
    float p0 = 0.f, p1 = 0.f;                   // pooled (2 cols per thread)
    for (int s = 0; s < NS; ++s) {
        float lm = lam[s];
        const float* yr = y2b + (size_t)s * ND;
        p0 += lm * yr[t];
        p1 += lm * yr[t + 256];
    }
    float vd = p0 * Wout[t] + p1 * Wout[t + 256];
    #pragma unroll
    for (int off = 32; off > 0; off >>= 1) vd += __shfl_xor(vd, off);
    if (lane == 0) red[wid] = vd;
    __syncthreads();
    if (t == 0) out[b] = red[0] + red[1] + red[2] + red[3] + bout[0];
}

// ---------------------------------------------------------------------------
extern "C" void kernel_launch(void* const* d_in, const int* in_sizes, int n_in,
                              void* d_out, int out_size, void* d_ws, size_t ws_size,
                              hipStream_t stream)
{
    const float* src   = (const float*)d_in[0];
    const float* Wfeat = (const float*)d_in[1];
    const float* bfeat = (const float*)d_in[2];
    const float* pe    = (const float*)d_in[3];
    const float* Wq    = (const float*)d_in[4];
    const float* bq    = (const float*)d_in[5];
    const float* Wk    = (const float*)d_in[6];
    const float* bk    = (const float*)d_in[7];
    const float* Wv    = (const float*)d_in[8];
    const float* bv    = (const float*)d_in[9];
    const float* Wo    = (const float*)d_in[10];
    const float* bo    = (const float*)d_in[11];
    const float* lnw   = (const float*)d_in[12];
    const float* lnb   = (const float*)d_in[13];
    const float* W1    = (const float*)d_in[14];
    const float* b1    = (const float*)d_in[15];
    const float* W2    = (const float*)d_in[16];
    const float* b2    = (const float*)d_in[17];
    const float* Wt    = (const float*)d_in[18];
    const float* Wout  = (const float*)d_in[19];
    const float* bout  = (const float*)d_in[20];
    float* out = (float*)d_out;

    // workspace: 3 x [25600,512] f32 chunk buffers (52.4 MB each) + weights
    // total ~159 MB (R1 used 1.26 GB -> presumed ws overflow -> GPU fault)
    const size_t big = (size_t)CM * ND;
    float* bufA = (float*)d_ws;
    float* bufB = bufA + big;
    float* bufC = bufB + big;
    float* Wqf = bufC + big;
    float* Wkf = Wqf + (size_t)ND * NF;
    float* Wvf = Wkf + (size_t)ND * NF;
    float* Cq = Wvf + (size_t)ND * NF;
    float* Ck = Cq + (size_t)NS * ND;
    float* Cv = Ck + (size_t)NS * ND;

    prep_w_kernel<<<3 * ND, 256, 0, stream>>>(Wq, Wk, Wv, Wfeat, Wqf, Wkf, Wvf);
    prep_c_kernel<<<3 * NS, 256, 0, stream>>>(Wq, Wk, Wv, bq, bk, bv, bfeat, pe, Cq, Ck, Cv);

    dim3 g512(ND / 128, CM / 128);   // (4,200)
    dim3 g158(2, CM / 128);          // (2,200)

    for (int c = 0; c < NCHUNK; ++c) {
        const float* srcC = src + (size_t)c * CM * NF;
        float* outC = out + (size_t)c * CB;

        // q,k,v = srcC @ Wxf^T + Cx[s]   (K=158, folded feat+PE+bias)
        gemm_tn<false, true, false, true><<<g512, 256, 0, stream>>>(srcC, Wqf, nullptr, Cq, bufA, CM, ND, NF);
        gemm_tn<false, true, false, true><<<g512, 256, 0, stream>>>(srcC, Wkf, nullptr, Ck, bufB, CM, ND, NF);
        gemm_tn<false, true, false, true><<<g512, 256, 0, stream>>>(srcC, Wvf, nullptr, Cv, bufC, CM, ND, NF);

        // attention, writes attn over q's buffer (block-private in-place)
        attn_kernel<<<CB * NH, 256, 0, stream>>>(bufA, bufB, bufC, bufA);

        // attn_out = attn @ Wo^T + bo
        gemm_tn<true, true, false, false><<<g512, 256, 0, stream>>>(bufA, Wo, bo, nullptr, bufB, CM, ND, ND);
        // y1 = attn_out + LN(attn_out)
        lnadd_kernel<<<CM / 4, 256, 0, stream>>>(bufB, lnw, lnb, bufC);
        // act = relu(y1 @ W1^T + b1)   [25600,158]
        gemm_tn<true, false, true, false><<<g158, 256, 0, stream>>>(bufC, W1, b1, nullptr, bufA, CM, NF, ND);
        // ffn = act @ W2^T + b2
        gemm_tn<false, true, false, false><<<g512, 256, 0, stream>>>(bufA, W2, b2, nullptr, bufB, CM, ND, NF);
        // y2 = ffn + LN(ffn)
        lnadd_kernel<<<CM / 4, 256, 0, stream>>>(bufB, lnw, lnb, bufC);
        // temporal pooling + output head
        pool_kernel<<<CB, 256, 0, stream>>>(bufC, Wt, Wout, bout, outC);
    }

    (void)in_sizes; (void)n_in; (void)out_size; (void)ws_size;
}

// Round 3
// 4930.388 us; speedup vs baseline: 1.5378x; 1.5378x over previous
//
#include <hip/hip_runtime.h>
#include <math.h>

#define NB 2048
#define NS 100
#define NF 158
#define ND 512
#define NH 8
#define CB 128                 // batches per chunk
#define NCHUNK (NB / CB)       // 16
#define CM (CB * NS)           // 12800 rows per chunk

typedef unsigned short u16;
typedef __attribute__((ext_vector_type(8))) short bf16x8;
typedef __attribute__((ext_vector_type(4))) float f32x4;

__device__ __forceinline__ u16 f2bf(float f) {
    union { float f; unsigned u; } v; v.f = f;
    unsigned u = v.u;
    return (u16)((u + 0x7fffu + ((u >> 16) & 1u)) >> 16);   // RNE
}

__device__ __forceinline__ void gload16(const void* g, void* l) {
    __builtin_amdgcn_global_load_lds(
        (const __attribute__((address_space(1))) unsigned*)g,
        (__attribute__((address_space(3))) unsigned*)l, 16, 0, 0);
}

// ---------------------------------------------------------------------------
// prep_w: Wxf16[r,f] = bf16( sum_d Wx[r,d] * W_feat[d,f] ), padded to [512,160]
// ---------------------------------------------------------------------------
__global__ __launch_bounds__(256) void prep_w_kernel(
    const float* __restrict__ Wq, const float* __restrict__ Wk,
    const float* __restrict__ Wv, const float* __restrict__ Wf,
    u16* __restrict__ Wqf, u16* __restrict__ Wkf, u16* __restrict__ Wvf)
{
    int bid = blockIdx.x;           // 0..1535
    int sel = bid >> 9;
    int r = bid & 511;
    const float* Wsrc = (sel == 0) ? Wq : (sel == 1) ? Wk : Wv;
    u16* Wdst = (sel == 0) ? Wqf : (sel == 1) ? Wkf : Wvf;
    __shared__ float wrow[ND];
    int t = threadIdx.x;
    wrow[t] = Wsrc[(size_t)r * ND + t];
    wrow[t + 256] = Wsrc[(size_t)r * ND + t + 256];
    __syncthreads();
    if (t < 160) {
        float acc = 0.f;
        if (t < NF)
            for (int d = 0; d < ND; ++d)
                acc += wrow[d] * Wf[(size_t)d * NF + t];
        Wdst[(size_t)r * 160 + t] = f2bf(acc);
    }
}

// ---------------------------------------------------------------------------
// prep_c: C{q,k,v}[s,r] = sum_d (b_feat[d]+pe[s,d]) * W[r,d] + b[r]  (fp32)
// ---------------------------------------------------------------------------
__global__ __launch_bounds__(256) void prep_c_kernel(
    const float* __restrict__ Wq, const float* __restrict__ Wk, const float* __restrict__ Wv,
    const float* __restrict__ bq, const float* __restrict__ bk, const float* __restrict__ bv,
    const float* __restrict__ bfeat, const float* __restrict__ pe,
    float* __restrict__ Cq, float* __restrict__ Ck, float* __restrict__ Cv)
{
    int bid = blockIdx.x;           // 0..299
    int sel = bid / 100;
    int s = bid - sel * 100;
    const float* Wsrc = (sel == 0) ? Wq : (sel == 1) ? Wk : Wv;
    const float* bsrc = (sel == 0) ? bq : (sel == 1) ? bk : bv;
    float* dst = (sel == 0) ? Cq : (sel == 1) ? Ck : Cv;
    __shared__ float xv[ND];
    int t = threadIdx.x;
    xv[t] = bfeat[t] + pe[(size_t)s * ND + t];
    xv[t + 256] = bfeat[t + 256] + pe[(size_t)s * ND + t + 256];
    __syncthreads();
    #pragma unroll
    for (int rr = 0; rr < 2; ++rr) {
        int r = t + (rr << 8);
        const float* wr = Wsrc + (size_t)r * ND;
        float acc = bsrc[r];
        for (int d = 0; d < ND; d += 4) {
            float4 w4 = *(const float4*)(wr + d);
            acc += w4.x * xv[d] + w4.y * xv[d+1] + w4.z * xv[d+2] + w4.w * xv[d+3];
        }
        dst[(size_t)s * ND + r] = acc;
    }
}

// ---------------------------------------------------------------------------
// pad_cast: dst_bf16[Rp x Cp] = pad(src_f32[R x C])
// ---------------------------------------------------------------------------
__global__ __launch_bounds__(256) void pad_cast_kernel(
    const float* __restrict__ src, u16* __restrict__ dst,
    int R, int C, int Cp, int total)
{
    int idx = blockIdx.x * 256 + threadIdx.x;
    if (idx >= total) return;
    int r = idx / Cp, c = idx - r * Cp;
    float v = (r < R && c < C) ? src[(size_t)r * C + c] : 0.f;
    dst[idx] = f2bf(v);
}

__global__ __launch_bounds__(256) void pad_b1_kernel(
    const float* __restrict__ b1, float* __restrict__ b1p)
{
    int t = threadIdx.x;
    b1p[t] = (t < NF) ? b1[t] : 0.f;
}

// ---------------------------------------------------------------------------
// cast_src: chunk of src [CM,158] f32 -> [CM,160] bf16 (zero-padded)
// ---------------------------------------------------------------------------
__global__ __launch_bounds__(256) void cast_src_kernel(
    const float* __restrict__ src, u16* __restrict__ dst)
{
    int idx = blockIdx.x * 256 + threadIdx.x;   // < CM*160
    int r = idx / 160, c = idx - r * 160;
    float v = (c < NF) ? src[(size_t)r * NF + c] : 0.f;
    dst[idx] = f2bf(v);
}

// ---------------------------------------------------------------------------
// bf16 MFMA GEMM: C[M,N] = A[M,K](bf16) @ W[N,K](bf16)^T (+bias)(+tab)(relu)
// 128x128 tile, BK=32, 256 thr = 4 waves, each wave 64x64 via 4x4 MFMA tiles.
// M%128==0, N%128==0, K%32==0 (pre-padded). OUTMODE: 0=f32, 1=bf16.
// ---------------------------------------------------------------------------
template<int OUTMODE, bool RELU, bool ADDTAB>
__global__ __launch_bounds__(256) void gemm_bf16(
    const u16* __restrict__ A, const u16* __restrict__ W,
    const float* __restrict__ bias, const float* __restrict__ tab,
    void* __restrict__ Cv, int K, int ldc)
{
    __shared__ short As[128 * 32];
    __shared__ short Bs[128 * 32];
    int t = threadIdx.x;
    int lane = t & 63, wave = t >> 6;
    int quad = lane >> 4, l16 = lane & 15;
    int wr = wave >> 1, wc = wave & 1;
    int m0 = blockIdx.y << 7, n0 = blockIdx.x << 7;

    f32x4 acc[4][4];
    f32x4 z = {0.f, 0.f, 0.f, 0.f};
    #pragma unroll
    for (int mi = 0; mi < 4; ++mi)
        #pragma unroll
        for (int ni = 0; ni < 4; ++ni) acc[mi][ni] = z;

    int rowA = t >> 2;              // 0..63
    int cch = (t & 3) << 3;         // k element offset 0/8/16/24
    const u16* aSrc0 = A + (size_t)(m0 + rowA) * K + cch;
    const u16* aSrc1 = A + (size_t)(m0 + rowA + 64) * K + cch;
    const u16* bSrc0 = W + (size_t)(n0 + rowA) * K + cch;
    const u16* bSrc1 = W + (size_t)(n0 + rowA + 64) * K + cch;
    short* aDst0 = As + t * 8;
    short* aDst1 = As + (t + 256) * 8;
    short* bDst0 = Bs + t * 8;
    short* bDst1 = Bs + (t + 256) * 8;

    int nk = K >> 5;
    for (int kc = 0; kc < nk; ++kc) {
        if (kc) __syncthreads();
        gload16(aSrc0, aDst0);
        gload16(aSrc1, aDst1);
        gload16(bSrc0, bDst0);
        gload16(bSrc1, bDst1);
        aSrc0 += 32; aSrc1 += 32; bSrc0 += 32; bSrc1 += 32;
        __syncthreads();    // drains vmcnt -> LDS valid

        bf16x8 af[4], bw[4];
        #pragma unroll
        for (int mi = 0; mi < 4; ++mi)
            af[mi] = *(const bf16x8*)(As + ((size_t)((wr << 6) + (mi << 4) + l16) * 32 + (quad << 3)));
        #pragma unroll
        for (int ni = 0; ni < 4; ++ni)
            bw[ni] = *(const bf16x8*)(Bs + ((size_t)((wc << 6) + (ni << 4) + l16) * 32 + (quad << 3)));
        #pragma unroll
        for (int mi = 0; mi < 4; ++mi)
            #pragma unroll
            for (int ni = 0; ni < 4; ++ni)
                acc[mi][ni] = __builtin_amdgcn_mfma_f32_16x16x32_bf16(af[mi], bw[ni], acc[mi][ni], 0, 0, 0);
    }

    // epilogue: row = m0+wr*64+mi*16+quad*4+r, col = n0+wc*64+ni*16+l16
    #pragma unroll
    for (int mi = 0; mi < 4; ++mi) {
        #pragma unroll
        for (int r = 0; r < 4; ++r) {
            int row = m0 + (wr << 6) + (mi << 4) + (quad << 2) + r;
            const float* trow = ADDTAB ? (tab + (size_t)(row % NS) * ND) : nullptr;
            #pragma unroll
            for (int ni = 0; ni < 4; ++ni) {
                int col = n0 + (wc << 6) + (ni << 4) + l16;
                float v = acc[mi][ni][r];
                if (bias) v += bias[col];
                if (ADDTAB) v += trow[col];
                if (RELU) v = fmaxf(v, 0.f);
                if (OUTMODE == 0)
                    ((float*)Cv)[(size_t)row * ldc + col] = v;
                else
                    ((u16*)Cv)[(size_t)row * ldc + col] = f2bf(v);
            }
        }
    }
}

// ---------------------------------------------------------------------------
// Attention: one block per (b_local,h). fp32 compute, bf16 output.
// LDS 135.5 KB < 160 KB.
// ---------------------------------------------------------------------------
__global__ __launch_bounds__(256) void attn_kernel(
    const float* __restrict__ Q, const float* __restrict__ Kb,
    const float* __restrict__ V, u16* __restrict__ O)
{
    __shared__ float Qs[112][68];
    __shared__ float Ks[112][68];
    __shared__ float Vs[100][68];
    __shared__ float Ps[112][113];

    int t = threadIdx.x;
    int bh = blockIdx.x;
    int b = bh >> 3, h = bh & 7;
    const size_t base = (size_t)b * NS * ND + (size_t)(h << 6);

    for (int l = t; l < 1600; l += 256) {
        int s = l >> 4;
        int cq = (l & 15) << 2;
        const size_t g = base + (size_t)s * ND + cq;
        *(float4*)&Qs[s][cq] = *(const float4*)(Q + g);
        *(float4*)&Ks[s][cq] = *(const float4*)(Kb + g);
        *(float4*)&Vs[s][cq] = *(const float4*)(V + g);
    }
    for (int l = t; l < 12 * 64; l += 256) {
        int s = 100 + (l >> 6);
        int c = l & 63;
        Qs[s][c] = 0.f; Ks[s][c] = 0.f;
    }
    __syncthreads();

    int ti = t >> 4, tj = t & 15;
    float sc[7][7];
    #pragma unroll
    for (int m = 0; m < 7; ++m)
        #pragma unroll
        for (int n = 0; n < 7; ++n) sc[m][n] = 0.f;

    for (int k = 0; k < 64; ++k) {
        float qf[7], kf[7];
        #pragma unroll
        for (int m = 0; m < 7; ++m) qf[m] = Qs[ti + (m << 4)][k];
        #pragma unroll
        for (int n = 0; n < 7; ++n) kf[n] = Ks[tj + (n << 4)][k];
        #pragma unroll
        for (int m = 0; m < 7; ++m)
            #pragma unroll
            for (int n = 0; n < 7; ++n) sc[m][n] += qf[m] * kf[n];
    }
    #pragma unroll
    for (int m = 0; m < 7; ++m)
        #pragma unroll
        for (int n = 0; n < 7; ++n) Ps[ti + (m << 4)][tj + (n << 4)] = sc[m][n];
    __syncthreads();

    if (t < NS) {
        float mx = -3.0e38f;
        for (int j = 0; j < NS; ++j) mx = fmaxf(mx, Ps[t][j]);
        float sum = 0.f;
        for (int j = 0; j < NS; ++j) {
            float e = expf((Ps[t][j] - mx) * 0.125f);
            Ps[t][j] = e; sum += e;
        }
        float inv = 1.f / sum;
        for (int j = 0; j < NS; ++j) Ps[t][j] *= inv;
    }
    __syncthreads();

    float4 o[7];
    #pragma unroll
    for (int m = 0; m < 7; ++m) o[m] = make_float4(0.f, 0.f, 0.f, 0.f);
    for (int j = 0; j < NS; ++j) {
        float4 vv = *(const float4*)&Vs[j][tj << 2];
        #pragma unroll
        for (int m = 0; m < 7; ++m) {
            float p = Ps[ti + (m << 4)][j];
            o[m].x += p * vv.x; o[m].y += p * vv.y;
            o[m].z += p * vv.z; o[m].w += p * vv.w;
        }
    }
    #pragma unroll
    for (int m = 0; m < 7; ++m) {
        int i = ti + (m << 4);
        if (i < NS) {
            ushort4 ov;
            ov.x = f2bf(o[m].x); ov.y = f2bf(o[m].y);
            ov.z = f2bf(o[m].z); ov.w = f2bf(o[m].w);
            *(ushort4*)(O + base + (size_t)i * ND + (tj << 2)) = ov;
        }
    }
}

// ---------------------------------------------------------------------------
// y = x + LayerNorm(x)*w + b — wave/row, 4 rows/block; out f32 or bf16
// ---------------------------------------------------------------------------
template<bool BF16OUT>
__global__ __launch_bounds__(256) void lnadd_kernel(
    const float* __restrict__ X, const float* __restrict__ lw,
    const float* __restrict__ lb, void* __restrict__ Yv)
{
    int wid = threadIdx.x >> 6, lane = threadIdx.x & 63;
    size_t row = (size_t)blockIdx.x * 4 + wid;
    const float* x = X + row * ND;
    int c0 = lane << 2;
    float4 v0 = *(const float4*)(x + c0);
    float4 v1 = *(const float4*)(x + 256 + c0);
    float s = v0.x + v0.y + v0.z + v0.w + v1.x + v1.y + v1.z + v1.w;
    float q = v0.x*v0.x + v0.y*v0.y + v0.z*v0.z + v0.w*v0.w
            + v1.x*v1.x + v1.y*v1.y + v1.z*v1.z + v1.w*v1.w;
    #pragma unroll
    for (int off = 32; off > 0; off >>= 1) {
        s += __shfl_xor(s, off);
        q += __shfl_xor(q, off);
    }
    float mean = s * (1.f / 512.f);
    float var = q * (1.f / 512.f) - mean * mean;
    float rstd = rsqrtf(var + 1e-5f);
    float4 w0 = *(const float4*)(lw + c0), w1 = *(const float4*)(lw + 256 + c0);
    float4 b0 = *(const float4*)(lb + c0), b1 = *(const float4*)(lb + 256 + c0);
    float4 r0, r1;
    r0.x = v0.x + (v0.x - mean) * rstd * w0.x + b0.x;
    r0.y = v0.y + (v0.y - mean) * rstd * w0.y + b0.y;
    r0.z = v0.z + (v0.z - mean) * rstd * w0.z + b0.z;
    r0.w = v0.w + (v0.w - mean) * rstd * w0.w + b0.w;
    r1.x = v1.x + (v1.x - mean) * rstd * w1.x + b1.x;
    r1.y = v1.y + (v1.y - mean) * rstd * w1.y + b1.y;
    r1.z = v1.z + (v1.z - mean) * rstd * w1.z + b1.z;
    r1.w = v1.w + (v1.w - mean) * rstd * w1.w + b1.w;
    if (BF16OUT) {
        u16* y = (u16*)Yv + row * ND;
        ushort4 a, bq4;
        a.x = f2bf(r0.x); a.y = f2bf(r0.y); a.z = f2bf(r0.z); a.w = f2bf(r0.w);
        bq4.x = f2bf(r1.x); bq4.y = f2bf(r1.y); bq4.z = f2bf(r1.z); bq4.w = f2bf(r1.w);
        *(ushort4*)(y + c0) = a;
        *(ushort4*)(y + 256 + c0) = bq4;
    } else {
        float* y = (float*)Yv + row * ND;
        *(float4*)(y + c0) = r0;
        *(float4*)(y + 256 + c0) = r1;
    }
}

// ---------------------------------------------------------------------------
// Pooling head, one block per b (fp32 y2)
// ---------------------------------------------------------------------------
__global__ __launch_bounds__(256) void pool_kernel(
    const float* __restrict__ Y2, const float* __restrict__ Wt,
    const float* __restrict__ Wout, const float* __restrict__ bout,
    float* __restrict__ out)
{
    __shared__ float yL[ND];
    __shared__ float t1[ND];
    __shared__ float u[ND];
    __shared__ float lam[128];
    __shared__ float red[4];
    int t = threadIdx.x;
    int b = blockIdx.x;
    const float* y2b = Y2 + (size_t)b * NS * ND;
    yL[t] = y2b[99 * ND + t];
    yL[t + 256] = y2b[99 * ND + t + 256];
    __syncthreads();
    #pragma unroll
    for (int rr = 0; rr < 2; ++rr) {
        int r = t + (rr << 8);
        const float* wr = Wt + (size_t)r * ND;
        float acc = 0.f;
        for (int k = 0; k < ND; k += 4) {
            float4 w4 = *(const float4*)(wr + k);
            acc += w4.x*yL[k] + w4.y*yL[k+1] + w4.z*yL[k+2] + w4.w*yL[k+3];
        }
        t1[r] = acc;
    }
    __syncthreads();
    #pragma unroll
    for (int cc = 0; cc < 2; ++cc) {
        int c = t + (cc << 8);
        float acc = 0.f;
        for (int r = 0; r < ND; ++r)
            acc += Wt[(size_t)r * ND + c] * t1[r];
        u[c] = acc;
    }
    __syncthreads();
    int wid = t >> 6, lane = t & 63;
    int c0 = lane << 2;
    for (int s = wid; s < NS; s += 4) {
        const float* yr = y2b + (size_t)s * ND;
        float4 p0 = *(const float4*)(yr + c0);
        float4 p1 = *(const float4*)(yr + 256 + c0);
        float a = p0.x*u[c0] + p0.y*u[c0+1] + p0.z*u[c0+2] + p0.w*u[c0+3]
                + p1.x*u[256+c0] + p1.y*u[256+c0+1] + p1.z*u[256+c0+2] + p1.w*u[256+c0+3];
        #pragma unroll
        for (int off = 32; off > 0; off >>= 1) a += __shfl_xor(a, off);
        if (lane == 0) lam[s] = a;
    }
    __syncthreads();
    if (t < 64) {
        float l0 = lam[t];
        float l1 = (t + 64 < NS) ? lam[t + 64] : -3.0e38f;
        float mx = fmaxf(l0, l1);
        #pragma unroll
        for (int off = 32; off > 0; off >>= 1) mx = fmaxf(mx, __shfl_xor(mx, off));
        float e0 = expf(l0 - mx);
        float e1 = (t + 64 < NS) ? expf(l1 - mx) : 0.f;
        float ssum = e0 + e1;
        #pragma unroll
        for (int off = 32; off > 0; off >>= 1) ssum += __shfl_xor(ssum, off);
        float inv = 1.f / ssum;
        lam[t] = e0 * inv;
        if (t + 64 < NS) lam[t + 64] = e1 * inv;
    }
    __syncthreads();
    float p0 = 0.f, p1 = 0.f;
    for (int s = 0; s < NS; ++s) {
        float lm = lam[s];
        const float* yr = y2b + (size_t)s * ND;
        p0 += lm * yr[t];
        p1 += lm * yr[t + 256];
    }
    float vd = p0 * Wout[t] + p1 * Wout[t + 256];
    #pragma unroll
    for (int off = 32; off > 0; off >>= 1) vd += __shfl_xor(vd, off);
    if (lane == 0) red[wid] = vd;
    __syncthreads();
    if (t == 0) out[b] = red[0] + red[1] + red[2] + red[3] + bout[0];
}

// ---------------------------------------------------------------------------
extern "C" void kernel_launch(void* const* d_in, const int* in_sizes, int n_in,
                              void* d_out, int out_size, void* d_ws, size_t ws_size,
                              hipStream_t stream)
{
    const float* src   = (const float*)d_in[0];
    const float* Wfeat = (const float*)d_in[1];
    const float* bfeat = (const float*)d_in[2];
    const float* pe    = (const float*)d_in[3];
    const float* Wq    = (const float*)d_in[4];
    const float* bq    = (const float*)d_in[5];
    const float* Wk    = (const float*)d_in[6];
    const float* bk    = (const float*)d_in[7];
    const float* Wv    = (const float*)d_in[8];
    const float* bv    = (const float*)d_in[9];
    const float* Wo    = (const float*)d_in[10];
    const float* bo    = (const float*)d_in[11];
    const float* lnw   = (const float*)d_in[12];
    const float* lnb   = (const float*)d_in[13];
    const float* W1    = (const float*)d_in[14];
    const float* b1    = (const float*)d_in[15];
    const float* W2    = (const float*)d_in[16];
    const float* b2    = (const float*)d_in[17];
    const float* Wt    = (const float*)d_in[18];
    const float* Wout  = (const float*)d_in[19];
    const float* bout  = (const float*)d_in[20];
    float* out = (float*)d_out;

    // ---- workspace layout (~100 MB, well under R2-proven 159 MB) ----
    const size_t cm512 = (size_t)CM * ND;          // 6.5536M elements
    float* R1 = (float*)d_ws;                      // 26.2 MB f32
    float* R2 = R1 + cm512;                        // 26.2 MB f32
    float* R3 = R2 + cm512;                        // 26.2 MB f32 (also bf16 y1 view)
    u16*   R4 = (u16*)(R3 + cm512);                // CM*512 bf16 (attn out) 13.1 MB
    u16*   S16 = R4 + cm512;                       // CM*160 bf16 (src chunk) 4.1 MB
    u16*   Wqf16 = S16 + (size_t)CM * 160;
    u16*   Wkf16 = Wqf16 + 512 * 160;
    u16*   Wvf16 = Wkf16 + 512 * 160;
    u16*   Wo16  = Wvf16 + 512 * 160;              // [512,512]
    u16*   W116  = Wo16 + 512 * 512;               // [256,512]
    u16*   W216  = W116 + 256 * 512;               // [512,256]
    float* Cq  = (float*)(W216 + 512 * 256);       // [100,512] f32
    float* Ck  = Cq + NS * ND;
    float* Cv  = Ck + NS * ND;
    float* b1p = Cv + NS * ND;                     // [256] f32

    // ---- weight prep (once per launch) ----
    prep_w_kernel<<<3 * ND, 256, 0, stream>>>(Wq, Wk, Wv, Wfeat, Wqf16, Wkf16, Wvf16);
    prep_c_kernel<<<3 * NS, 256, 0, stream>>>(Wq, Wk, Wv, bq, bk, bv, bfeat, pe, Cq, Ck, Cv);
    pad_cast_kernel<<<(512 * 512) / 256, 256, 0, stream>>>(Wo, Wo16, 512, 512, 512, 512 * 512);
    pad_cast_kernel<<<(256 * 512) / 256, 256, 0, stream>>>(W1, W116, NF, 512, 512, 256 * 512);
    pad_cast_kernel<<<(512 * 256) / 256, 256, 0, stream>>>(W2, W216, 512, NF, 256, 512 * 256);
    pad_b1_kernel<<<1, 256, 0, stream>>>(b1, b1p);

    dim3 g512(4, CM / 128);   // (4,100)
    dim3 g256(2, CM / 128);   // (2,100)

    for (int c = 0; c < NCHUNK; ++c) {
        const float* srcC = src + (size_t)c * CM * NF;
        float* outC = out + (size_t)c * CB;

        cast_src_kernel<<<(CM * 160) / 256, 256, 0, stream>>>(srcC, S16);

        // q,k,v = src16 @ Wxf16^T + Cx[s]   (K=160, f32 out)
        gemm_bf16<0, false, true><<<g512, 256, 0, stream>>>(S16, Wqf16, nullptr, Cq, R1, 160, ND);
        gemm_bf16<0, false, true><<<g512, 256, 0, stream>>>(S16, Wkf16, nullptr, Ck, R2, 160, ND);
        gemm_bf16<0, false, true><<<g512, 256, 0, stream>>>(S16, Wvf16, nullptr, Cv, R3, 160, ND);

        // attention (fp32 compute) -> bf16 R4
        attn_kernel<<<CB * NH, 256, 0, stream>>>(R1, R2, R3, R4);

        // attn_out = R4 @ Wo16^T + bo  (K=512, f32 -> R2)
        gemm_bf16<0, false, false><<<g512, 256, 0, stream>>>(R4, Wo16, bo, nullptr, R2, 512, ND);
        // y1 = attn_out + LN(attn_out) -> bf16 in R3
        lnadd_kernel<true><<<CM / 4, 256, 0, stream>>>(R2, lnw, lnb, R3);
        // act = relu(y1 @ W116^T + b1p) -> bf16 [CM,256] in R1 (cols 158.. zero)
        gemm_bf16<1, true, false><<<g256, 256, 0, stream>>>((const u16*)R3, W116, b1p, nullptr, R1, 512, 256);
        // ffn = act @ W216^T + b2  (K=256, f32 -> R2)
        gemm_bf16<0, false, false><<<g512, 256, 0, stream>>>((const u16*)R1, W216, b2, nullptr, R2, 256, ND);
        // y2 = ffn + LN(ffn) -> f32 R3
        lnadd_kernel<false><<<CM / 4, 256, 0, stream>>>(R2, lnw, lnb, R3);
        // temporal pooling + output head
        pool_kernel<<<CB, 256, 0, stream>>>(R3, Wt, Wout, bout, outC);
    }

    (void)in_sizes; (void)n_in; (void)out_size; (void)ws_size;
}

// Round 4
// 2814.909 us; speedup vs baseline: 2.6934x; 1.7515x over previous
//
#include <hip/hip_runtime.h>
#include <math.h>

#define NB 2048
#define NS 100
#define NF 158
#define ND 512
#define NH 8

typedef unsigned short u16;
typedef __attribute__((ext_vector_type(8))) short bf16x8;
typedef __attribute__((ext_vector_type(8))) unsigned short u16x8;
typedef __attribute__((ext_vector_type(4))) float f32x4;

__device__ __forceinline__ u16 f2bf(float f) {
    union { float f; unsigned u; } v; v.f = f;
    unsigned u = v.u;
    return (u16)((u + 0x7fffu + ((u >> 16) & 1u)) >> 16);   // RNE
}

__device__ __forceinline__ void gload16(const void* g, void* l) {
    __builtin_amdgcn_global_load_lds(
        (const __attribute__((address_space(1))) unsigned*)g,
        (__attribute__((address_space(3))) unsigned*)l, 16, 0, 0);
}

// ---------------------------------------------------------------------------
// prep_w: Wqkv16[n,f] (n 0..1535) = bf16(sum_d W{q|k|v}[n&511,d] * Wf[d,f]),
// padded f to [*,160]
// ---------------------------------------------------------------------------
__global__ __launch_bounds__(256) void prep_w_kernel(
    const float* __restrict__ Wq, const float* __restrict__ Wk,
    const float* __restrict__ Wv, const float* __restrict__ Wf,
    u16* __restrict__ Wqkv)
{
    int bid = blockIdx.x;           // 0..1535
    int sel = bid >> 9;
    int r = bid & 511;
    const float* Wsrc = (sel == 0) ? Wq : (sel == 1) ? Wk : Wv;
    __shared__ float wrow[ND];
    int t = threadIdx.x;
    wrow[t] = Wsrc[(size_t)r * ND + t];
    wrow[t + 256] = Wsrc[(size_t)r * ND + t + 256];
    __syncthreads();
    if (t < 160) {
        float acc = 0.f;
        if (t < NF)
            for (int d = 0; d < ND; ++d)
                acc += wrow[d] * Wf[(size_t)d * NF + t];
        Wqkv[(size_t)bid * 160 + t] = f2bf(acc);
    }
}

// ---------------------------------------------------------------------------
// prep_c: Cqkv[s, sel*512+r] = sum_d (b_feat[d]+pe[s,d]) * W[r,d] + b[r]
// ---------------------------------------------------------------------------
__global__ __launch_bounds__(256) void prep_c_kernel(
    const float* __restrict__ Wq, const float* __restrict__ Wk, const float* __restrict__ Wv,
    const float* __restrict__ bq, const float* __restrict__ bk, const float* __restrict__ bv,
    const float* __restrict__ bfeat, const float* __restrict__ pe,
    float* __restrict__ Cqkv)
{
    int bid = blockIdx.x;           // 0..299
    int sel = bid / 100;
    int s = bid - sel * 100;
    const float* Wsrc = (sel == 0) ? Wq : (sel == 1) ? Wk : Wv;
    const float* bsrc = (sel == 0) ? bq : (sel == 1) ? bk : bv;
    __shared__ float xv[ND];
    int t = threadIdx.x;
    xv[t] = bfeat[t] + pe[(size_t)s * ND + t];
    xv[t + 256] = bfeat[t + 256] + pe[(size_t)s * ND + t + 256];
    __syncthreads();
    #pragma unroll
    for (int rr = 0; rr < 2; ++rr) {
        int r = t + (rr << 8);
        const float* wr = Wsrc + (size_t)r * ND;
        float acc = bsrc[r];
        for (int d = 0; d < ND; d += 4) {
            float4 w4 = *(const float4*)(wr + d);
            acc += w4.x * xv[d] + w4.y * xv[d+1] + w4.z * xv[d+2] + w4.w * xv[d+3];
        }
        Cqkv[(size_t)s * 1536 + (sel << 9) + r] = acc;
    }
}

// ---------------------------------------------------------------------------
__global__ __launch_bounds__(256) void pad_cast_kernel(
    const float* __restrict__ src, u16* __restrict__ dst,
    int R, int C, int Cp, int total)
{
    int idx = blockIdx.x * 256 + threadIdx.x;
    if (idx >= total) return;
    int r = idx / Cp, c = idx - r * Cp;
    float v = (r < R && c < C) ? src[(size_t)r * C + c] : 0.f;
    dst[idx] = f2bf(v);
}

__global__ __launch_bounds__(256) void pad_b1_kernel(
    const float* __restrict__ b1, float* __restrict__ b1p)
{
    int t = threadIdx.x;
    b1p[t] = (t < NF) ? b1[t] : 0.f;
}

__global__ __launch_bounds__(256) void cast_src_kernel(
    const float* __restrict__ src, u16* __restrict__ dst)
{
    int idx = blockIdx.x * 256 + threadIdx.x;   // < CMc*160
    int r = idx / 160, c = idx - r * 160;
    float v = (c < NF) ? src[(size_t)r * NF + c] : 0.f;
    dst[idx] = f2bf(v);
}

// ---------------------------------------------------------------------------
// bf16 MFMA GEMM: C[M,N] = A[M,K]@W[N,K]^T (+bias[col])(+tab[row%100,col])(relu)
// 128x128 tile, BK=32, 256 thr, m97-style global_load_lds staging.
// M%128==0, N%128==0, K%32==0. OUTMODE: 0=f32, 1=bf16.
// ---------------------------------------------------------------------------
template<int OUTMODE, bool RELU, bool ADDTAB>
__global__ __launch_bounds__(256) void gemm_bf16(
    const u16* __restrict__ A, const u16* __restrict__ W,
    const float* __restrict__ bias, const float* __restrict__ tab, int ldtab,
    void* __restrict__ Cv, int K, int ldc)
{
    __shared__ short As[128 * 32];
    __shared__ short Bs[128 * 32];
    int t = threadIdx.x;
    int lane = t & 63, wave = t >> 6;
    int quad = lane >> 4, l16 = lane & 15;
    int wr = wave >> 1, wc = wave & 1;
    int m0 = blockIdx.y << 7, n0 = blockIdx.x << 7;

    f32x4 acc[4][4];
    f32x4 z = {0.f, 0.f, 0.f, 0.f};
    #pragma unroll
    for (int mi = 0; mi < 4; ++mi)
        #pragma unroll
        for (int ni = 0; ni < 4; ++ni) acc[mi][ni] = z;

    int rowA = t >> 2;
    int cch = (t & 3) << 3;
    const u16* aSrc0 = A + (size_t)(m0 + rowA) * K + cch;
    const u16* aSrc1 = A + (size_t)(m0 + rowA + 64) * K + cch;
    const u16* bSrc0 = W + (size_t)(n0 + rowA) * K + cch;
    const u16* bSrc1 = W + (size_t)(n0 + rowA + 64) * K + cch;
    short* aDst0 = As + t * 8;
    short* aDst1 = As + (t + 256) * 8;
    short* bDst0 = Bs + t * 8;
    short* bDst1 = Bs + (t + 256) * 8;

    int nk = K >> 5;
    for (int kc = 0; kc < nk; ++kc) {
        if (kc) __syncthreads();
        gload16(aSrc0, aDst0);
        gload16(aSrc1, aDst1);
        gload16(bSrc0, bDst0);
        gload16(bSrc1, bDst1);
        aSrc0 += 32; aSrc1 += 32; bSrc0 += 32; bSrc1 += 32;
        __syncthreads();

        bf16x8 af[4], bw[4];
        #pragma unroll
        for (int mi = 0; mi < 4; ++mi)
            af[mi] = *(const bf16x8*)(As + ((size_t)((wr << 6) + (mi << 4) + l16) * 32 + (quad << 3)));
        #pragma unroll
        for (int ni = 0; ni < 4; ++ni)
            bw[ni] = *(const bf16x8*)(Bs + ((size_t)((wc << 6) + (ni << 4) + l16) * 32 + (quad << 3)));
        #pragma unroll
        for (int mi = 0; mi < 4; ++mi)
            #pragma unroll
            for (int ni = 0; ni < 4; ++ni)
                acc[mi][ni] = __builtin_amdgcn_mfma_f32_16x16x32_bf16(af[mi], bw[ni], acc[mi][ni], 0, 0, 0);
    }

    #pragma unroll
    for (int mi = 0; mi < 4; ++mi) {
        #pragma unroll
        for (int r = 0; r < 4; ++r) {
            int row = m0 + (wr << 6) + (mi << 4) + (quad << 2) + r;
            const float* trow = ADDTAB ? (tab + (size_t)(row % NS) * ldtab) : nullptr;
            #pragma unroll
            for (int ni = 0; ni < 4; ++ni) {
                int col = n0 + (wc << 6) + (ni << 4) + l16;
                float v = acc[mi][ni][r];
                if (bias) v += bias[col];
                if (ADDTAB) v += trow[col];
                if (RELU) v = fmaxf(v, 0.f);
                if (OUTMODE == 0)
                    ((float*)Cv)[(size_t)row * ldc + col] = v;
                else
                    ((u16*)Cv)[(size_t)row * ldc + col] = f2bf(v);
            }
        }
    }
}

// ---------------------------------------------------------------------------
// MFMA attention: one block per (b_local, h). QKV rows in [CM,1536] bf16:
// q at +0, k at +512, v at +1024 per row. Output bf16 [CM,512].
// QK^T: 128(padded rows)x112 tiles; softmax in registers (rows live in one
// 16-lane group of the C-layout); P bf16 into LDS (over dead Q); P@V MFMA.
// LDS 66.8 KB -> 2 blocks/CU.
// ---------------------------------------------------------------------------
#define ALDQ 72     // Q/K row stride (shorts): 2-way bank aliasing only
#define ALDP 136    // P / Vt row stride (shorts)

__global__ __launch_bounds__(256) void attn_kernel(
    const u16* __restrict__ QKV, u16* __restrict__ O)
{
    __shared__ short UN[128 * ALDP];   // Q view (stride 72) then P view (stride 136)
    __shared__ short Ks[112 * ALDQ];
    __shared__ short Vt[64 * ALDP];

    int t = threadIdx.x;
    int lane = t & 63, wave = t >> 6;
    int quad = lane >> 4, l16 = lane & 15;
    int rows0 = wave << 5;             // wave's 32 output rows
    int bh = blockIdx.x;
    int b = bh >> 3, h = bh & 7;
    const size_t rowbase = (size_t)b * NS;
    const u16* qptr = QKV + rowbase * 1536 + (h << 6);

    // stage Q,K row-major; V transposed. 100 rows x 8 segs of 8 shorts.
    for (int l = t; l < 800; l += 256) {
        int s = l >> 3, seg = (l & 7) << 3;
        const u16* g = qptr + (size_t)s * 1536 + seg;
        *(u16x8*)&UN[s * ALDQ + seg] = *(const u16x8*)g;
        *(u16x8*)&Ks[s * ALDQ + seg] = *(const u16x8*)(g + 512);
        u16x8 v8 = *(const u16x8*)(g + 1024);
        #pragma unroll
        for (int i = 0; i < 8; ++i) Vt[(seg + i) * ALDP + s] = (short)v8[i];
    }
    for (int l = t; l < 64 * 28; l += 256) {    // zero Vt k=100..127 (NaN guard)
        int c = l / 28, k = 100 + (l - c * 28);
        Vt[c * ALDP + k] = 0;
    }
    __syncthreads();

    // ---- S = Q K^T  (2 row-tiles x 7 col-tiles per wave, K=64 = 2 steps)
    f32x4 sc[2][7];
    f32x4 z = {0.f, 0.f, 0.f, 0.f};
    #pragma unroll
    for (int mi = 0; mi < 2; ++mi)
        #pragma unroll
        for (int ni = 0; ni < 7; ++ni) sc[mi][ni] = z;

    #pragma unroll
    for (int ks = 0; ks < 2; ++ks) {
        bf16x8 aq[2], bk[7];
        #pragma unroll
        for (int mi = 0; mi < 2; ++mi)
            aq[mi] = *(const bf16x8*)&UN[(rows0 + (mi << 4) + l16) * ALDQ + (ks << 5) + (quad << 3)];
        #pragma unroll
        for (int ni = 0; ni < 7; ++ni)
            bk[ni] = *(const bf16x8*)&Ks[((ni << 4) + l16) * ALDQ + (ks << 5) + (quad << 3)];
        #pragma unroll
        for (int mi = 0; mi < 2; ++mi)
            #pragma unroll
            for (int ni = 0; ni < 7; ++ni)
                sc[mi][ni] = __builtin_amdgcn_mfma_f32_16x16x32_bf16(aq[mi], bk[ni], sc[mi][ni], 0, 0, 0);
    }
    __syncthreads();   // all waves done reading Q region -> safe to write P

    // ---- softmax in registers; write P (bf16) into UN with stride 136
    #pragma unroll
    for (int mi = 0; mi < 2; ++mi) {
        #pragma unroll
        for (int r = 0; r < 4; ++r) {
            if (l16 >= 4) sc[mi][6][r] = -3.0e38f;   // cols 100..111 masked
            float mx = sc[mi][0][r];
            #pragma unroll
            for (int ni = 1; ni < 7; ++ni) mx = fmaxf(mx, sc[mi][ni][r]);
            #pragma unroll
            for (int off = 1; off < 16; off <<= 1) mx = fmaxf(mx, __shfl_xor(mx, off));
            float sum = 0.f;
            #pragma unroll
            for (int ni = 0; ni < 7; ++ni) {
                float e = expf((sc[mi][ni][r] - mx) * 0.125f);
                sc[mi][ni][r] = e; sum += e;
            }
            #pragma unroll
            for (int off = 1; off < 16; off <<= 1) sum += __shfl_xor(sum, off);
            float inv = 1.f / sum;
            int row = rows0 + (mi << 4) + (quad << 2) + r;
            #pragma unroll
            for (int ni = 0; ni < 7; ++ni)
                UN[row * ALDP + (ni << 4) + l16] = (short)f2bf(sc[mi][ni][r] * inv);
            UN[row * ALDP + 112 + l16] = 0;          // zero K-pad cols 112..127
        }
    }
    __syncthreads();

    // ---- O = P V  (2 row-tiles x 4 col-tiles, K=128 = 4 steps)
    f32x4 oa[2][4];
    #pragma unroll
    for (int mi = 0; mi < 2; ++mi)
        #pragma unroll
        for (int ni = 0; ni < 4; ++ni) oa[mi][ni] = z;

    #pragma unroll
    for (int ks = 0; ks < 4; ++ks) {
        bf16x8 ap[2], bv[4];
        #pragma unroll
        for (int mi = 0; mi < 2; ++mi)
            ap[mi] = *(const bf16x8*)&UN[(rows0 + (mi << 4) + l16) * ALDP + (ks << 5) + (quad << 3)];
        #pragma unroll
        for (int ni = 0; ni < 4; ++ni)
            bv[ni] = *(const bf16x8*)&Vt[((ni << 4) + l16) * ALDP + (ks << 5) + (quad << 3)];
        #pragma unroll
        for (int mi = 0; mi < 2; ++mi)
            #pragma unroll
            for (int ni = 0; ni < 4; ++ni)
                oa[mi][ni] = __builtin_amdgcn_mfma_f32_16x16x32_bf16(ap[mi], bv[ni], oa[mi][ni], 0, 0, 0);
    }

    #pragma unroll
    for (int mi = 0; mi < 2; ++mi) {
        #pragma unroll
        for (int r = 0; r < 4; ++r) {
            int row = rows0 + (mi << 4) + (quad << 2) + r;
            if (row < NS) {
                u16* orow = O + (rowbase + row) * 512 + (h << 6);
                #pragma unroll
                for (int ni = 0; ni < 4; ++ni)
                    orow[(ni << 4) + l16] = f2bf(oa[mi][ni][r]);
            }
        }
    }
}

// ---------------------------------------------------------------------------
// y = x + LayerNorm(x)*w + b — wave/row, 4 rows/block; out f32 or bf16
// ---------------------------------------------------------------------------
template<bool BF16OUT>
__global__ __launch_bounds__(256) void lnadd_kernel(
    const float* __restrict__ X, const float* __restrict__ lw,
    const float* __restrict__ lb, void* __restrict__ Yv)
{
    int wid = threadIdx.x >> 6, lane = threadIdx.x & 63;
    size_t row = (size_t)blockIdx.x * 4 + wid;
    const float* x = X + row * ND;
    int c0 = lane << 2;
    float4 v0 = *(const float4*)(x + c0);
    float4 v1 = *(const float4*)(x + 256 + c0);
    float s = v0.x + v0.y + v0.z + v0.w + v1.x + v1.y + v1.z + v1.w;
    float q = v0.x*v0.x + v0.y*v0.y + v0.z*v0.z + v0.w*v0.w
            + v1.x*v1.x + v1.y*v1.y + v1.z*v1.z + v1.w*v1.w;
    #pragma unroll
    for (int off = 32; off > 0; off >>= 1) {
        s += __shfl_xor(s, off);
        q += __shfl_xor(q, off);
    }
    float mean = s * (1.f / 512.f);
    float var = q * (1.f / 512.f) - mean * mean;
    float rstd = rsqrtf(var + 1e-5f);
    float4 w0 = *(const float4*)(lw + c0), w1 = *(const float4*)(lw + 256 + c0);
    float4 b0 = *(const float4*)(lb + c0), b1 = *(const float4*)(lb + 256 + c0);
    float4 r0, r1;
    r0.x = v0.x + (v0.x - mean) * rstd * w0.x + b0.x;
    r0.y = v0.y + (v0.y - mean) * rstd * w0.y + b0.y;
    r0.z = v0.z + (v0.z - mean) * rstd * w0.z + b0.z;
    r0.w = v0.w + (v0.w - mean) * rstd * w0.w + b0.w;
    r1.x = v1.x + (v1.x - mean) * rstd * w1.x + b1.x;
    r1.y = v1.y + (v1.y - mean) * rstd * w1.y + b1.y;
    r1.z = v1.z + (v1.z - mean) * rstd * w1.z + b1.z;
    r1.w = v1.w + (v1.w - mean) * rstd * w1.w + b1.w;
    if (BF16OUT) {
        u16* y = (u16*)Yv + row * ND;
        ushort4 a, bq4;
        a.x = f2bf(r0.x); a.y = f2bf(r0.y); a.z = f2bf(r0.z); a.w = f2bf(r0.w);
        bq4.x = f2bf(r1.x); bq4.y = f2bf(r1.y); bq4.z = f2bf(r1.z); bq4.w = f2bf(r1.w);
        *(ushort4*)(y + c0) = a;
        *(ushort4*)(y + 256 + c0) = bq4;
    } else {
        float* y = (float*)Yv + row * ND;
        *(float4*)(y + c0) = r0;
        *(float4*)(y + 256 + c0) = r1;
    }
}

// ---------------------------------------------------------------------------
// u_stage1: T1[b,r] = dot(Wt[r,:], Y2[b, last row, :])   grid (8, CBc/16)
// ---------------------------------------------------------------------------
__global__ __launch_bounds__(256) void u_stage1_kernel(
    const float* __restrict__ Y2, const float* __restrict__ Wt,
    float* __restrict__ T1)
{
    __shared__ float yl[16][512];
    int t = threadIdx.x;
    int r0 = blockIdx.x << 6;
    int bg = blockIdx.y << 4;
    for (int l = t; l < 2048; l += 256) {
        int bb = l >> 7, seg = (l & 127) << 2;
        *(float4*)&yl[bb][seg] =
            *(const float4*)&Y2[((size_t)(bg + bb) * NS + 99) * ND + seg];
    }
    __syncthreads();
    int r = r0 + (t & 63);
    int b0 = t >> 6;
    const float* wr = Wt + (size_t)r * ND;
    float acc[4] = {0.f, 0.f, 0.f, 0.f};
    for (int d = 0; d < ND; d += 4) {
        float4 w4 = *(const float4*)(wr + d);
        #pragma unroll
        for (int bb = 0; bb < 4; ++bb) {
            int bl = (b0 << 2) + bb;
            acc[bb] += w4.x * yl[bl][d] + w4.y * yl[bl][d+1]
                     + w4.z * yl[bl][d+2] + w4.w * yl[bl][d+3];
        }
    }
    #pragma unroll
    for (int bb = 0; bb < 4; ++bb)
        T1[(size_t)(bg + (b0 << 2) + bb) * ND + r] = acc[bb];
}

// ---------------------------------------------------------------------------
// u_stage2: U[b,c] = sum_r Wt[r,c] * T1[b,r]   grid (8, CBc/16)
// ---------------------------------------------------------------------------
__global__ __launch_bounds__(256) void u_stage2_kernel(
    const float* __restrict__ T1, const float* __restrict__ Wt,
    float* __restrict__ U)
{
    __shared__ float t1s[16][512];
    int t = threadIdx.x;
    int c0 = blockIdx.x << 6;
    int bg = blockIdx.y << 4;
    for (int l = t; l < 2048; l += 256) {
        int bb = l >> 7, seg = (l & 127) << 2;
        *(float4*)&t1s[bb][seg] = *(const float4*)&T1[(size_t)(bg + bb) * ND + seg];
    }
    __syncthreads();
    int c = c0 + (t & 63);
    int b0 = t >> 6;
    float acc[4] = {0.f, 0.f, 0.f, 0.f};
    for (int r = 0; r < ND; ++r) {
        float w = Wt[(size_t)r * ND + c];
        #pragma unroll
        for (int bb = 0; bb < 4; ++bb)
            acc[bb] += w * t1s[(b0 << 2) + bb][r];
    }
    #pragma unroll
    for (int bb = 0; bb < 4; ++bb)
        U[(size_t)(bg + (b0 << 2) + bb) * ND + c] = acc[bb];
}

// ---------------------------------------------------------------------------
// pool_finish: lam = softmax_s(y2[b,s]·u[b]); out[b] = (sum lam_s y2[b,s])·Wout + b
// ---------------------------------------------------------------------------
__global__ __launch_bounds__(256) void pool_kernel(
    const float* __restrict__ Y2, const float* __restrict__ U,
    const float* __restrict__ Wout, const float* __restrict__ bout,
    float* __restrict__ out)
{
    __shared__ float u[ND];
    __shared__ float lam[128];
    __shared__ float red[4];
    int t = threadIdx.x;
    int b = blockIdx.x;
    const float* y2b = Y2 + (size_t)b * NS * ND;
    u[t] = U[(size_t)b * ND + t];
    u[t + 256] = U[(size_t)b * ND + t + 256];
    __syncthreads();
    int wid = t >> 6, lane = t & 63;
    int c0 = lane << 2;
    for (int s = wid; s < NS; s += 4) {
        const float* yr = y2b + (size_t)s * ND;
        float4 p0 = *(const float4*)(yr + c0);
        float4 p1 = *(const float4*)(yr + 256 + c0);
        float a = p0.x*u[c0] + p0.y*u[c0+1] + p0.z*u[c0+2] + p0.w*u[c0+3]
                + p1.x*u[256+c0] + p1.y*u[256+c0+1] + p1.z*u[256+c0+2] + p1.w*u[256+c0+3];
        #pragma unroll
        for (int off = 32; off > 0; off >>= 1) a += __shfl_xor(a, off);
        if (lane == 0) lam[s] = a;
    }
    __syncthreads();
    if (t < 64) {
        float l0 = lam[t];
        float l1 = (t + 64 < NS) ? lam[t + 64] : -3.0e38f;
        float mx = fmaxf(l0, l1);
        #pragma unroll
        for (int off = 32; off > 0; off >>= 1) mx = fmaxf(mx, __shfl_xor(mx, off));
        float e0 = expf(l0 - mx);
        float e1 = (t + 64 < NS) ? expf(l1 - mx) : 0.f;
        float ssum = e0 + e1;
        #pragma unroll
        for (int off = 32; off > 0; off >>= 1) ssum += __shfl_xor(ssum, off);
        float inv = 1.f / ssum;
        lam[t] = e0 * inv;
        if (t + 64 < NS) lam[t + 64] = e1 * inv;
    }
    __syncthreads();
    float p0 = 0.f, p1 = 0.f;
    for (int s = 0; s < NS; ++s) {
        float lm = lam[s];
        const float* yr = y2b + (size_t)s * ND;
        p0 += lm * yr[t];
        p1 += lm * yr[t + 256];
    }
    float vd = p0 * Wout[t] + p1 * Wout[t + 256];
    #pragma unroll
    for (int off = 32; off > 0; off >>= 1) vd += __shfl_xor(vd, off);
    if (lane == 0) red[wid] = vd;
    __syncthreads();
    if (t == 0) out[b] = red[0] + red[1] + red[2] + red[3] + bout[0];
}

// ---------------------------------------------------------------------------
static size_t ws_need(int CBc) {
    size_t cm = (size_t)CBc * NS;
    size_t b = 0;
    b += cm * 1536 * 2;        // QKV16
    b += cm * 160 * 2;         // S16
    b += cm * 512 * 2;         // AO16
    b += cm * 512 * 4;         // G1
    b += cm * 512 * 2;         // Y116
    b += cm * 256 * 2;         // ACT16
    b += cm * 512 * 4;         // Y2
    b += (size_t)CBc * 512 * 4 * 2;  // T1, U
    b += 1536 * 160 * 2 + 512 * 512 * 2 + 256 * 512 * 2 + 512 * 256 * 2;
    b += 100 * 1536 * 4 + 256 * 4;
    b += 64 * 1024;            // alignment slack
    return b;
}

extern "C" void kernel_launch(void* const* d_in, const int* in_sizes, int n_in,
                              void* d_out, int out_size, void* d_ws, size_t ws_size,
                              hipStream_t stream)
{
    const float* src   = (const float*)d_in[0];
    const float* Wfeat = (const float*)d_in[1];
    const float* bfeat = (const float*)d_in[2];
    const float* pe    = (const float*)d_in[3];
    const float* Wq    = (const float*)d_in[4];
    const float* bq    = (const float*)d_in[5];
    const float* Wk    = (const float*)d_in[6];
    const float* bk    = (const float*)d_in[7];
    const float* Wv    = (const float*)d_in[8];
    const float* bv    = (const float*)d_in[9];
    const float* Wo    = (const float*)d_in[10];
    const float* bo    = (const float*)d_in[11];
    const float* lnw   = (const float*)d_in[12];
    const float* lnb   = (const float*)d_in[13];
    const float* W1    = (const float*)d_in[14];
    const float* b1    = (const float*)d_in[15];
    const float* W2    = (const float*)d_in[16];
    const float* b2    = (const float*)d_in[17];
    const float* Wt    = (const float*)d_in[18];
    const float* Wout  = (const float*)d_in[19];
    const float* bout  = (const float*)d_in[20];
    float* out = (float*)d_out;

    // chunk size from ws_size (deterministic across calls — graph safe)
    int CBc = (ws_size >= ws_need(256)) ? 256 : 128;
    int NCH = NB / CBc;
    size_t CMc = (size_t)CBc * NS;

    char* p = (char*)d_ws;
    auto alloc = [&](size_t bytes) { char* r = p; p += (bytes + 255) & ~(size_t)255; return r; };
    u16*   QKV16 = (u16*)  alloc(CMc * 1536 * 2);
    u16*   S16   = (u16*)  alloc(CMc * 160 * 2);
    u16*   AO16  = (u16*)  alloc(CMc * 512 * 2);
    float* G1    = (float*)alloc(CMc * 512 * 4);
    u16*   Y116  = (u16*)  alloc(CMc * 512 * 2);
    u16*   ACT16 = (u16*)  alloc(CMc * 256 * 2);
    float* Y2    = (float*)alloc(CMc * 512 * 4);
    float* T1    = (float*)alloc((size_t)CBc * 512 * 4);
    float* U     = (float*)alloc((size_t)CBc * 512 * 4);
    u16*   Wqkv16= (u16*)  alloc(1536 * 160 * 2);
    u16*   Wo16  = (u16*)  alloc(512 * 512 * 2);
    u16*   W116  = (u16*)  alloc(256 * 512 * 2);
    u16*   W216  = (u16*)  alloc(512 * 256 * 2);
    float* Cqkv  = (float*)alloc(100 * 1536 * 4);
    float* b1p   = (float*)alloc(256 * 4);

    // ---- weight prep ----
    prep_w_kernel<<<1536, 256, 0, stream>>>(Wq, Wk, Wv, Wfeat, Wqkv16);
    prep_c_kernel<<<300, 256, 0, stream>>>(Wq, Wk, Wv, bq, bk, bv, bfeat, pe, Cqkv);
    pad_cast_kernel<<<(512 * 512) / 256, 256, 0, stream>>>(Wo, Wo16, 512, 512, 512, 512 * 512);
    pad_cast_kernel<<<(256 * 512) / 256, 256, 0, stream>>>(W1, W116, NF, 512, 512, 256 * 512);
    pad_cast_kernel<<<(512 * 256) / 256, 256, 0, stream>>>(W2, W216, 512, NF, 256, 512 * 256);
    pad_b1_kernel<<<1, 256, 0, stream>>>(b1, b1p);

    dim3 gQKV(12, CMc / 128);
    dim3 g512(4, CMc / 128);
    dim3 g256(2, CMc / 128);
    dim3 gU(8, CBc / 16);

    for (int c = 0; c < NCH; ++c) {
        const float* srcC = src + (size_t)c * CMc * NF;
        float* outC = out + (size_t)c * CBc;

        cast_src_kernel<<<(CMc * 160) / 256, 256, 0, stream>>>(srcC, S16);
        // q|k|v = src16 @ Wqkv16^T + Cqkv[s]  (K=160, N=1536, bf16 out)
        gemm_bf16<1, false, true><<<gQKV, 256, 0, stream>>>(S16, Wqkv16, nullptr, Cqkv, 1536, QKV16, 160, 1536);
        // MFMA attention -> AO16
        attn_kernel<<<CBc * NH, 256, 0, stream>>>(QKV16, AO16);
        // attn_out = AO16 @ Wo16^T + bo  (f32 -> G1)
        gemm_bf16<0, false, false><<<g512, 256, 0, stream>>>(AO16, Wo16, bo, nullptr, 0, G1, 512, 512);
        // y1 = attn_out + LN(attn_out) -> bf16
        lnadd_kernel<true><<<CMc / 4, 256, 0, stream>>>(G1, lnw, lnb, Y116);
        // act = relu(y1 @ W116^T + b1p) -> bf16 [CMc,256]
        gemm_bf16<1, true, false><<<g256, 256, 0, stream>>>(Y116, W116, b1p, nullptr, 0, ACT16, 512, 256);
        // ffn = act @ W216^T + b2 (f32 -> G1)
        gemm_bf16<0, false, false><<<g512, 256, 0, stream>>>(ACT16, W216, b2, nullptr, 0, G1, 256, 512);
        // y2 = ffn + LN(ffn) -> f32
        lnadd_kernel<false><<<CMc / 4, 256, 0, stream>>>(G1, lnw, lnb, Y2);
        // pooling head
        u_stage1_kernel<<<gU, 256, 0, stream>>>(Y2, Wt, T1);
        u_stage2_kernel<<<gU, 256, 0, stream>>>(T1, Wt, U);
        pool_kernel<<<CBc, 256, 0, stream>>>(Y2, U, Wout, bout, outC);
    }

    (void)in_sizes; (void)n_in; (void)out_size; (void)ws_size;
}

// Round 6
// 2144.668 us; speedup vs baseline: 3.5352x; 1.3125x over previous
//
#include <hip/hip_runtime.h>
#include <math.h>

#define NB 2048
#define NS 100
#define NF 158
#define ND 512
#define NH 8

typedef unsigned short u16;
typedef __attribute__((ext_vector_type(8))) short bf16x8;
typedef __attribute__((ext_vector_type(8))) unsigned short u16x8;
typedef __attribute__((ext_vector_type(4))) float f32x4;

__device__ __forceinline__ u16 f2bf(float f) {
    union { float f; unsigned u; } v; v.f = f;
    unsigned u = v.u;
    return (u16)((u + 0x7fffu + ((u >> 16) & 1u)) >> 16);   // RNE
}

__device__ __forceinline__ void gload16(const void* g, void* l) {
    __builtin_amdgcn_global_load_lds(
        (const __attribute__((address_space(1))) unsigned*)g,
        (__attribute__((address_space(3))) unsigned*)l, 16, 0, 0);
}

// ---------------------------------------------------------------------------
// prep_w: Wqkv16[n,f] (n 0..1535) = bf16(sum_d W{q|k|v}[n&511,d] * Wf[d,f])
// ---------------------------------------------------------------------------
__global__ __launch_bounds__(256) void prep_w_kernel(
    const float* __restrict__ Wq, const float* __restrict__ Wk,
    const float* __restrict__ Wv, const float* __restrict__ Wf,
    u16* __restrict__ Wqkv)
{
    int bid = blockIdx.x;           // 0..1535
    int sel = bid >> 9;
    int r = bid & 511;
    const float* Wsrc = (sel == 0) ? Wq : (sel == 1) ? Wk : Wv;
    __shared__ float wrow[ND];
    int t = threadIdx.x;
    wrow[t] = Wsrc[(size_t)r * ND + t];
    wrow[t + 256] = Wsrc[(size_t)r * ND + t + 256];
    __syncthreads();
    if (t < 160) {
        float acc = 0.f;
        if (t < NF)
            for (int d = 0; d < ND; ++d)
                acc += wrow[d] * Wf[(size_t)d * NF + t];
        Wqkv[(size_t)bid * 160 + t] = f2bf(acc);
    }
}

// ---------------------------------------------------------------------------
// prep_c: Cqkv[s, sel*512+r] = sum_d (b_feat[d]+pe[s,d]) * W[r,d] + b[r]
// ---------------------------------------------------------------------------
__global__ __launch_bounds__(256) void prep_c_kernel(
    const float* __restrict__ Wq, const float* __restrict__ Wk, const float* __restrict__ Wv,
    const float* __restrict__ bq, const float* __restrict__ bk, const float* __restrict__ bv,
    const float* __restrict__ bfeat, const float* __restrict__ pe,
    float* __restrict__ Cqkv)
{
    int bid = blockIdx.x;           // 0..299
    int sel = bid / 100;
    int s = bid - sel * 100;
    const float* Wsrc = (sel == 0) ? Wq : (sel == 1) ? Wk : Wv;
    const float* bsrc = (sel == 0) ? bq : (sel == 1) ? bk : bv;
    __shared__ float xv[ND];
    int t = threadIdx.x;
    xv[t] = bfeat[t] + pe[(size_t)s * ND + t];
    xv[t + 256] = bfeat[t + 256] + pe[(size_t)s * ND + t + 256];
    __syncthreads();
    #pragma unroll
    for (int rr = 0; rr < 2; ++rr) {
        int r = t + (rr << 8);
        const float* wr = Wsrc + (size_t)r * ND;
        float acc = bsrc[r];
        for (int d = 0; d < ND; d += 4) {
            float4 w4 = *(const float4*)(wr + d);
            acc += w4.x * xv[d] + w4.y * xv[d+1] + w4.z * xv[d+2] + w4.w * xv[d+3];
        }
        Cqkv[(size_t)s * 1536 + (sel << 9) + r] = acc;
    }
}

// ---------------------------------------------------------------------------
__global__ __launch_bounds__(256) void pad_cast_kernel(
    const float* __restrict__ src, u16* __restrict__ dst,
    int R, int C, int Cp, int total)
{
    int idx = blockIdx.x * 256 + threadIdx.x;
    if (idx >= total) return;
    int r = idx / Cp, c = idx - r * Cp;
    float v = (r < R && c < C) ? src[(size_t)r * C + c] : 0.f;
    dst[idx] = f2bf(v);
}

__global__ __launch_bounds__(256) void pad_b1_kernel(
    const float* __restrict__ b1, float* __restrict__ b1p)
{
    int t = threadIdx.x;
    b1p[t] = (t < NF) ? b1[t] : 0.f;
}

__global__ __launch_bounds__(256) void cast_src_kernel(
    const float* __restrict__ src, u16* __restrict__ dst)
{
    int idx = blockIdx.x * 256 + threadIdx.x;   // < CMc*160
    int r = idx / 160, c = idx - r * 160;
    float v = (c < NF) ? src[(size_t)r * NF + c] : 0.f;
    dst[idx] = f2bf(v);
}

// ---------------------------------------------------------------------------
// QKV GEMM, K=160 staged fully in LDS (5 BK=32 panels, m97 layout per panel).
// C[M,1536] = A[M,160] @ W[1536,160]^T + tab[row%100, col], bf16 out.
// One barrier, 80 MFMAs straight. LDS 80KB -> 2 blocks/CU.
// FIX vs R5: stage BOTH 64-row halves of each 128-row panel.
// ---------------------------------------------------------------------------
__global__ __launch_bounds__(256) void gemm_qkv(
    const u16* __restrict__ A, const u16* __restrict__ W,
    const float* __restrict__ tab, u16* __restrict__ out)
{
    __shared__ short As[5 * 128 * 32];
    __shared__ short Bs[5 * 128 * 32];
    int t = threadIdx.x;
    int lane = t & 63, wave = t >> 6;
    int quad = lane >> 4, l16 = lane & 15;
    int wr = wave >> 1, wc = wave & 1;
    int m0 = blockIdx.y << 7, n0 = blockIdx.x << 7;

    int rowA = t >> 2;              // 0..63
    int koff = (t & 3) << 3;
    #pragma unroll
    for (int p = 0; p < 5; ++p) {
        gload16(A + (size_t)(m0 + rowA) * 160 + (p << 5) + koff,      As + (p << 12) + t * 8);
        gload16(A + (size_t)(m0 + rowA + 64) * 160 + (p << 5) + koff, As + (p << 12) + (t + 256) * 8);
        gload16(W + (size_t)(n0 + rowA) * 160 + (p << 5) + koff,      Bs + (p << 12) + t * 8);
        gload16(W + (size_t)(n0 + rowA + 64) * 160 + (p << 5) + koff, Bs + (p << 12) + (t + 256) * 8);
    }
    __syncthreads();

    f32x4 acc[4][4];
    f32x4 z = {0.f, 0.f, 0.f, 0.f};
    #pragma unroll
    for (int mi = 0; mi < 4; ++mi)
        #pragma unroll
        for (int ni = 0; ni < 4; ++ni) acc[mi][ni] = z;

    #pragma unroll
    for (int ks = 0; ks < 5; ++ks) {
        bf16x8 af[4], bw[4];
        #pragma unroll
        for (int mi = 0; mi < 4; ++mi)
            af[mi] = *(const bf16x8*)(As + (ks << 12) + ((wr << 6) + (mi << 4) + l16) * 32 + (quad << 3));
        #pragma unroll
        for (int ni = 0; ni < 4; ++ni)
            bw[ni] = *(const bf16x8*)(Bs + (ks << 12) + ((wc << 6) + (ni << 4) + l16) * 32 + (quad << 3));
        #pragma unroll
        for (int mi = 0; mi < 4; ++mi)
            #pragma unroll
            for (int ni = 0; ni < 4; ++ni)
                acc[mi][ni] = __builtin_amdgcn_mfma_f32_16x16x32_bf16(af[mi], bw[ni], acc[mi][ni], 0, 0, 0);
    }

    #pragma unroll
    for (int mi = 0; mi < 4; ++mi) {
        #pragma unroll
        for (int r = 0; r < 4; ++r) {
            int row = m0 + (wr << 6) + (mi << 4) + (quad << 2) + r;
            const float* trow = tab + (size_t)(row % NS) * 1536;
            u16* orow = out + (size_t)row * 1536;
            #pragma unroll
            for (int ni = 0; ni < 4; ++ni) {
                int col = n0 + (wc << 6) + (ni << 4) + l16;
                orow[col] = f2bf(acc[mi][ni][r] + trow[col]);
            }
        }
    }
}

// ---------------------------------------------------------------------------
// Generic bf16 GEMM (used for FFN1): 128x128 tile, BK=32.
// ---------------------------------------------------------------------------
template<int OUTMODE, bool RELU>
__global__ __launch_bounds__(256) void gemm_bf16(
    const u16* __restrict__ A, const u16* __restrict__ W,
    const float* __restrict__ bias, void* __restrict__ Cv, int K, int ldc)
{
    __shared__ short As[128 * 32];
    __shared__ short Bs[128 * 32];
    int t = threadIdx.x;
    int lane = t & 63, wave = t >> 6;
    int quad = lane >> 4, l16 = lane & 15;
    int wr = wave >> 1, wc = wave & 1;
    int m0 = blockIdx.y << 7, n0 = blockIdx.x << 7;

    f32x4 acc[4][4];
    f32x4 z = {0.f, 0.f, 0.f, 0.f};
    #pragma unroll
    for (int mi = 0; mi < 4; ++mi)
        #pragma unroll
        for (int ni = 0; ni < 4; ++ni) acc[mi][ni] = z;

    int rowA = t >> 2;
    int cch = (t & 3) << 3;
    const u16* aSrc0 = A + (size_t)(m0 + rowA) * K + cch;
    const u16* aSrc1 = A + (size_t)(m0 + rowA + 64) * K + cch;
    const u16* bSrc0 = W + (size_t)(n0 + rowA) * K + cch;
    const u16* bSrc1 = W + (size_t)(n0 + rowA + 64) * K + cch;
    short* aDst0 = As + t * 8;
    short* aDst1 = As + (t + 256) * 8;
    short* bDst0 = Bs + t * 8;
    short* bDst1 = Bs + (t + 256) * 8;

    int nk = K >> 5;
    for (int kc = 0; kc < nk; ++kc) {
        if (kc) __syncthreads();
        gload16(aSrc0, aDst0);
        gload16(aSrc1, aDst1);
        gload16(bSrc0, bDst0);
        gload16(bSrc1, bDst1);
        aSrc0 += 32; aSrc1 += 32; bSrc0 += 32; bSrc1 += 32;
        __syncthreads();

        bf16x8 af[4], bw[4];
        #pragma unroll
        for (int mi = 0; mi < 4; ++mi)
            af[mi] = *(const bf16x8*)(As + ((size_t)((wr << 6) + (mi << 4) + l16) * 32 + (quad << 3)));
        #pragma unroll
        for (int ni = 0; ni < 4; ++ni)
            bw[ni] = *(const bf16x8*)(Bs + ((size_t)((wc << 6) + (ni << 4) + l16) * 32 + (quad << 3)));
        #pragma unroll
        for (int mi = 0; mi < 4; ++mi)
            #pragma unroll
            for (int ni = 0; ni < 4; ++ni)
                acc[mi][ni] = __builtin_amdgcn_mfma_f32_16x16x32_bf16(af[mi], bw[ni], acc[mi][ni], 0, 0, 0);
    }

    #pragma unroll
    for (int mi = 0; mi < 4; ++mi) {
        #pragma unroll
        for (int r = 0; r < 4; ++r) {
            int row = m0 + (wr << 6) + (mi << 4) + (quad << 2) + r;
            #pragma unroll
            for (int ni = 0; ni < 4; ++ni) {
                int col = n0 + (wc << 6) + (ni << 4) + l16;
                float v = acc[mi][ni][r];
                if (bias) v += bias[col];
                if (RELU) v = fmaxf(v, 0.f);
                if (OUTMODE == 0)
                    ((float*)Cv)[(size_t)row * ldc + col] = v;
                else
                    ((u16*)Cv)[(size_t)row * ldc + col] = f2bf(v);
            }
        }
    }
}

// ---------------------------------------------------------------------------
// Fused GEMM + add-LayerNorm epilogue:
//   X = A@W^T + bias  (row x 512);  out = X + LN(X)*lnw + lnb
// Block = 64 rows x full N=512, 512 threads (8 waves, each 64 rows x 64 cols).
// K%32==0. OUTMODE: 0=f32 out, 1=bf16 out.
// FIX vs R5: A-tile staging guard t<256 (was t<128 -> rows 32..63 garbage).
// ---------------------------------------------------------------------------
template<int OUTMODE>
__global__ __launch_bounds__(512, 2) void gemm_ln(
    const u16* __restrict__ A, const u16* __restrict__ W,
    const float* __restrict__ bias, const float* __restrict__ lnw,
    const float* __restrict__ lnb, void* __restrict__ outv, int K)
{
    __shared__ short As[64 * 32];      // 4 KB
    __shared__ short Bs[512 * 32];     // 32 KB
    __shared__ float red_s[64][9];
    __shared__ float red_q[64][9];
    __shared__ float mrow[64], rrow[64];

    int t = threadIdx.x;
    int lane = t & 63, wave = t >> 6;
    int quad = lane >> 4, l16 = lane & 15;
    int m0 = blockIdx.x << 6;

    f32x4 acc[4][4];
    f32x4 z = {0.f, 0.f, 0.f, 0.f};
    #pragma unroll
    for (int mi = 0; mi < 4; ++mi)
        #pragma unroll
        for (int ni = 0; ni < 4; ++ni) acc[mi][ni] = z;

    int koff = (t & 3) << 3;
    const u16* aSrc = A + (size_t)(m0 + (t >> 2)) * K + koff;   // t<256 -> rows 0..63
    const u16* bSrc0 = W + (size_t)(t >> 2) * K + koff;
    const u16* bSrc1 = W + (size_t)((t >> 2) + 128) * K + koff;
    const u16* bSrc2 = W + (size_t)((t >> 2) + 256) * K + koff;
    const u16* bSrc3 = W + (size_t)((t >> 2) + 384) * K + koff;
    short* aDst = As + t * 8;
    short* bDst0 = Bs + t * 8;
    short* bDst1 = Bs + (t + 512) * 8;
    short* bDst2 = Bs + (t + 1024) * 8;
    short* bDst3 = Bs + (t + 1536) * 8;

    int nk = K >> 5;
    for (int kc = 0; kc < nk; ++kc) {
        if (kc) __syncthreads();
        if (t < 256) gload16(aSrc, aDst);
        gload16(bSrc0, bDst0);
        gload16(bSrc1, bDst1);
        gload16(bSrc2, bDst2);
        gload16(bSrc3, bDst3);
        aSrc += 32; bSrc0 += 32; bSrc1 += 32; bSrc2 += 32; bSrc3 += 32;
        __syncthreads();

        bf16x8 af[4], bw[4];
        #pragma unroll
        for (int mi = 0; mi < 4; ++mi)
            af[mi] = *(const bf16x8*)(As + ((mi << 4) + l16) * 32 + (quad << 3));
        #pragma unroll
        for (int ni = 0; ni < 4; ++ni)
            bw[ni] = *(const bf16x8*)(Bs + ((wave << 6) + (ni << 4) + l16) * 32 + (quad << 3));
        #pragma unroll
        for (int mi = 0; mi < 4; ++mi)
            #pragma unroll
            for (int ni = 0; ni < 4; ++ni)
                acc[mi][ni] = __builtin_amdgcn_mfma_f32_16x16x32_bf16(af[mi], bw[ni], acc[mi][ni], 0, 0, 0);
    }

    // epilogue: bias add, per-row stats (512 cols), add-LN, store
    float lwv[4], lbv[4];
    #pragma unroll
    for (int ni = 0; ni < 4; ++ni) {
        int col = (wave << 6) + (ni << 4) + l16;
        float bv = bias[col];
        lwv[ni] = lnw[col];
        lbv[ni] = lnb[col];
        #pragma unroll
        for (int mi = 0; mi < 4; ++mi)
            #pragma unroll
            for (int r = 0; r < 4; ++r) acc[mi][ni][r] += bv;
    }
    #pragma unroll
    for (int mi = 0; mi < 4; ++mi) {
        #pragma unroll
        for (int r = 0; r < 4; ++r) {
            float s = acc[mi][0][r] + acc[mi][1][r] + acc[mi][2][r] + acc[mi][3][r];
            float q = acc[mi][0][r]*acc[mi][0][r] + acc[mi][1][r]*acc[mi][1][r]
                    + acc[mi][2][r]*acc[mi][2][r] + acc[mi][3][r]*acc[mi][3][r];
            #pragma unroll
            for (int off = 1; off < 16; off <<= 1) {
                s += __shfl_xor(s, off);
                q += __shfl_xor(q, off);
            }
            if (l16 == 0) {
                int row = (mi << 4) + (quad << 2) + r;
                red_s[row][wave] = s;
                red_q[row][wave] = q;
            }
        }
    }
    __syncthreads();
    if (t < 64) {
        float s = 0.f, q = 0.f;
        #pragma unroll
        for (int w8 = 0; w8 < 8; ++w8) { s += red_s[t][w8]; q += red_q[t][w8]; }
        float mean = s * (1.f / 512.f);
        float var = q * (1.f / 512.f) - mean * mean;
        mrow[t] = mean;
        rrow[t] = rsqrtf(var + 1e-5f);
    }
    __syncthreads();
    #pragma unroll
    for (int mi = 0; mi < 4; ++mi) {
        #pragma unroll
        for (int r = 0; r < 4; ++r) {
            int lrow = (mi << 4) + (quad << 2) + r;
            float mean = mrow[lrow], rstd = rrow[lrow];
            size_t grow = (size_t)(m0 + lrow) * 512;
            #pragma unroll
            for (int ni = 0; ni < 4; ++ni) {
                int col = (wave << 6) + (ni << 4) + l16;
                float v = acc[mi][ni][r];
                float y = v + (v - mean) * rstd * lwv[ni] + lbv[ni];
                if (OUTMODE == 0) ((float*)outv)[grow + col] = y;
                else ((u16*)outv)[grow + col] = f2bf(y);
            }
        }
    }
}

// ---------------------------------------------------------------------------
// MFMA attention (R4-proven, unchanged): one block per (b_local, h).
// ---------------------------------------------------------------------------
#define ALDQ 72
#define ALDP 136

__global__ __launch_bounds__(256) void attn_kernel(
    const u16* __restrict__ QKV, u16* __restrict__ O)
{
    __shared__ short UN[128 * ALDP];
    __shared__ short Ks[112 * ALDQ];
    __shared__ short Vt[64 * ALDP];

    int t = threadIdx.x;
    int lane = t & 63, wave = t >> 6;
    int quad = lane >> 4, l16 = lane & 15;
    int rows0 = wave << 5;
    int bh = blockIdx.x;
    int b = bh >> 3, h = bh & 7;
    const size_t rowbase = (size_t)b * NS;
    const u16* qptr = QKV + rowbase * 1536 + (h << 6);

    for (int l = t; l < 800; l += 256) {
        int s = l >> 3, seg = (l & 7) << 3;
        const u16* g = qptr + (size_t)s * 1536 + seg;
        *(u16x8*)&UN[s * ALDQ + seg] = *(const u16x8*)g;
        *(u16x8*)&Ks[s * ALDQ + seg] = *(const u16x8*)(g + 512);
        u16x8 v8 = *(const u16x8*)(g + 1024);
        #pragma unroll
        for (int i = 0; i < 8; ++i) Vt[(seg + i) * ALDP + s] = (short)v8[i];
    }
    for (int l = t; l < 64 * 28; l += 256) {
        int c = l / 28, k = 100 + (l - c * 28);
        Vt[c * ALDP + k] = 0;
    }
    __syncthreads();

    f32x4 sc[2][7];
    f32x4 z = {0.f, 0.f, 0.f, 0.f};
    #pragma unroll
    for (int mi = 0; mi < 2; ++mi)
        #pragma unroll
        for (int ni = 0; ni < 7; ++ni) sc[mi][ni] = z;

    #pragma unroll
    for (int ks = 0; ks < 2; ++ks) {
        bf16x8 aq[2], bk[7];
        #pragma unroll
        for (int mi = 0; mi < 2; ++mi)
            aq[mi] = *(const bf16x8*)&UN[(rows0 + (mi << 4) + l16) * ALDQ + (ks << 5) + (quad << 3)];
        #pragma unroll
        for (int ni = 0; ni < 7; ++ni)
            bk[ni] = *(const bf16x8*)&Ks[((ni << 4) + l16) * ALDQ + (ks << 5) + (quad << 3)];
        #pragma unroll
        for (int mi = 0; mi < 2; ++mi)
            #pragma unroll
            for (int ni = 0; ni < 7; ++ni)
                sc[mi][ni] = __builtin_amdgcn_mfma_f32_16x16x32_bf16(aq[mi], bk[ni], sc[mi][ni], 0, 0, 0);
    }
    __syncthreads();

    #pragma unroll
    for (int mi = 0; mi < 2; ++mi) {
        #pragma unroll
        for (int r = 0; r < 4; ++r) {
            if (l16 >= 4) sc[mi][6][r] = -3.0e38f;
            float mx = sc[mi][0][r];
            #pragma unroll
            for (int ni = 1; ni < 7; ++ni) mx = fmaxf(mx, sc[mi][ni][r]);
            #pragma unroll
            for (int off = 1; off < 16; off <<= 1) mx = fmaxf(mx, __shfl_xor(mx, off));
            float sum = 0.f;
            #pragma unroll
            for (int ni = 0; ni < 7; ++ni) {
                float e = expf((sc[mi][ni][r] - mx) * 0.125f);
                sc[mi][ni][r] = e; sum += e;
            }
            #pragma unroll
            for (int off = 1; off < 16; off <<= 1) sum += __shfl_xor(sum, off);
            float inv = 1.f / sum;
            int row = rows0 + (mi << 4) + (quad << 2) + r;
            #pragma unroll
            for (int ni = 0; ni < 7; ++ni)
                UN[row * ALDP + (ni << 4) + l16] = (short)f2bf(sc[mi][ni][r] * inv);
            UN[row * ALDP + 112 + l16] = 0;
        }
    }
    __syncthreads();

    f32x4 oa[2][4];
    #pragma unroll
    for (int mi = 0; mi < 2; ++mi)
        #pragma unroll
        for (int ni = 0; ni < 4; ++ni) oa[mi][ni] = z;

    #pragma unroll
    for (int ks = 0; ks < 4; ++ks) {
        bf16x8 ap[2], bv[4];
        #pragma unroll
        for (int mi = 0; mi < 2; ++mi)
            ap[mi] = *(const bf16x8*)&UN[(rows0 + (mi << 4) + l16) * ALDP + (ks << 5) + (quad << 3)];
        #pragma unroll
        for (int ni = 0; ni < 4; ++ni)
            bv[ni] = *(const bf16x8*)&Vt[((ni << 4) + l16) * ALDP + (ks << 5) + (quad << 3)];
        #pragma unroll
        for (int mi = 0; mi < 2; ++mi)
            #pragma unroll
            for (int ni = 0; ni < 4; ++ni)
                oa[mi][ni] = __builtin_amdgcn_mfma_f32_16x16x32_bf16(ap[mi], bv[ni], oa[mi][ni], 0, 0, 0);
    }

    #pragma unroll
    for (int mi = 0; mi < 2; ++mi) {
        #pragma unroll
        for (int r = 0; r < 4; ++r) {
            int row = rows0 + (mi << 4) + (quad << 2) + r;
            if (row < NS) {
                u16* orow = O + (rowbase + row) * 512 + (h << 6);
                #pragma unroll
                for (int ni = 0; ni < 4; ++ni)
                    orow[(ni << 4) + l16] = f2bf(oa[mi][ni][r]);
            }
        }
    }
}

// ---------------------------------------------------------------------------
// u_stage1: T1[b,r] = dot(Wt[r,:], Y2[b, last, :])
// ---------------------------------------------------------------------------
__global__ __launch_bounds__(256) void u_stage1_kernel(
    const float* __restrict__ Y2, const float* __restrict__ Wt,
    float* __restrict__ T1)
{
    __shared__ float yl[16][512];
    int t = threadIdx.x;
    int r0 = blockIdx.x << 6;
    int bg = blockIdx.y << 4;
    for (int l = t; l < 2048; l += 256) {
        int bb = l >> 7, seg = (l & 127) << 2;
        *(float4*)&yl[bb][seg] =
            *(const float4*)&Y2[((size_t)(bg + bb) * NS + 99) * ND + seg];
    }
    __syncthreads();
    int r = r0 + (t & 63);
    int b0 = t >> 6;
    const float* wr = Wt + (size_t)r * ND;
    float acc[4] = {0.f, 0.f, 0.f, 0.f};
    for (int d = 0; d < ND; d += 4) {
        float4 w4 = *(const float4*)(wr + d);
        #pragma unroll
        for (int bb = 0; bb < 4; ++bb) {
            int bl = (b0 << 2) + bb;
            acc[bb] += w4.x * yl[bl][d] + w4.y * yl[bl][d+1]
                     + w4.z * yl[bl][d+2] + w4.w * yl[bl][d+3];
        }
    }
    #pragma unroll
    for (int bb = 0; bb < 4; ++bb)
        T1[(size_t)(bg + (b0 << 2) + bb) * ND + r] = acc[bb];
}

__global__ __launch_bounds__(256) void u_stage2_kernel(
    const float* __restrict__ T1, const float* __restrict__ Wt,
    float* __restrict__ U)
{
    __shared__ float t1s[16][512];
    int t = threadIdx.x;
    int c0 = blockIdx.x << 6;
    int bg = blockIdx.y << 4;
    for (int l = t; l < 2048; l += 256) {
        int bb = l >> 7, seg = (l & 127) << 2;
        *(float4*)&t1s[bb][seg] = *(const float4*)&T1[(size_t)(bg + bb) * ND + seg];
    }
    __syncthreads();
    int c = c0 + (t & 63);
    int b0 = t >> 6;
    float acc[4] = {0.f, 0.f, 0.f, 0.f};
    for (int r = 0; r < ND; ++r) {
        float w = Wt[(size_t)r * ND + c];
        #pragma unroll
        for (int bb = 0; bb < 4; ++bb)
            acc[bb] += w * t1s[(b0 << 2) + bb][r];
    }
    #pragma unroll
    for (int bb = 0; bb < 4; ++bb)
        U[(size_t)(bg + (b0 << 2) + bb) * ND + c] = acc[bb];
}

// ---------------------------------------------------------------------------
__global__ __launch_bounds__(256) void pool_kernel(
    const float* __restrict__ Y2, const float* __restrict__ U,
    const float* __restrict__ Wout, const float* __restrict__ bout,
    float* __restrict__ out)
{
    __shared__ float u[ND];
    __shared__ float lam[128];
    __shared__ float red[4];
    int t = threadIdx.x;
    int b = blockIdx.x;
    const float* y2b = Y2 + (size_t)b * NS * ND;
    u[t] = U[(size_t)b * ND + t];
    u[t + 256] = U[(size_t)b * ND + t + 256];
    __syncthreads();
    int wid = t >> 6, lane = t & 63;
    int c0 = lane << 2;
    for (int s = wid; s < NS; s += 4) {
        const float* yr = y2b + (size_t)s * ND;
        float4 p0 = *(const float4*)(yr + c0);
        float4 p1 = *(const float4*)(yr + 256 + c0);
        float a = p0.x*u[c0] + p0.y*u[c0+1] + p0.z*u[c0+2] + p0.w*u[c0+3]
                + p1.x*u[256+c0] + p1.y*u[256+c0+1] + p1.z*u[256+c0+2] + p1.w*u[256+c0+3];
        #pragma unroll
        for (int off = 32; off > 0; off >>= 1) a += __shfl_xor(a, off);
        if (lane == 0) lam[s] = a;
    }
    __syncthreads();
    if (t < 64) {
        float l0 = lam[t];
        float l1 = (t + 64 < NS) ? lam[t + 64] : -3.0e38f;
        float mx = fmaxf(l0, l1);
        #pragma unroll
        for (int off = 32; off > 0; off >>= 1) mx = fmaxf(mx, __shfl_xor(mx, off));
        float e0 = expf(l0 - mx);
        float e1 = (t + 64 < NS) ? expf(l1 - mx) : 0.f;
        float ssum = e0 + e1;
        #pragma unroll
        for (int off = 32; off > 0; off >>= 1) ssum += __shfl_xor(ssum, off);
        float inv = 1.f / ssum;
        lam[t] = e0 * inv;
        if (t + 64 < NS) lam[t + 64] = e1 * inv;
    }
    __syncthreads();
    float p0 = 0.f, p1 = 0.f;
    for (int s = 0; s < NS; ++s) {
        float lm = lam[s];
        const float* yr = y2b + (size_t)s * ND;
        p0 += lm * yr[t];
        p1 += lm * yr[t + 256];
    }
    float vd = p0 * Wout[t] + p1 * Wout[t + 256];
    #pragma unroll
    for (int off = 32; off > 0; off >>= 1) vd += __shfl_xor(vd, off);
    if (lane == 0) red[wid] = vd;
    __syncthreads();
    if (t == 0) out[b] = red[0] + red[1] + red[2] + red[3] + bout[0];
}

// ---------------------------------------------------------------------------
static size_t ws_need(int CBc) {
    size_t cm = (size_t)CBc * NS;
    size_t b = 0;
    b += cm * 1536 * 2;        // QKV16
    b += cm * 160 * 2;         // S16
    b += cm * 512 * 2;         // AO16
    b += cm * 512 * 2;         // Y116
    b += cm * 256 * 2;         // ACT16
    b += cm * 512 * 4;         // Y2
    b += (size_t)CBc * 512 * 4 * 2;  // T1, U
    b += 1536 * 160 * 2 + 512 * 512 * 2 + 256 * 512 * 2 + 512 * 256 * 2;
    b += 100 * 1536 * 4 + 256 * 4;
    b += 64 * 1024;
    return b;
}

extern "C" void kernel_launch(void* const* d_in, const int* in_sizes, int n_in,
                              void* d_out, int out_size, void* d_ws, size_t ws_size,
                              hipStream_t stream)
{
    const float* src   = (const float*)d_in[0];
    const float* Wfeat = (const float*)d_in[1];
    const float* bfeat = (const float*)d_in[2];
    const float* pe    = (const float*)d_in[3];
    const float* Wq    = (const float*)d_in[4];
    const float* bq    = (const float*)d_in[5];
    const float* Wk    = (const float*)d_in[6];
    const float* bk    = (const float*)d_in[7];
    const float* Wv    = (const float*)d_in[8];
    const float* bv    = (const float*)d_in[9];
    const float* Wo    = (const float*)d_in[10];
    const float* bo    = (const float*)d_in[11];
    const float* lnw   = (const float*)d_in[12];
    const float* lnb   = (const float*)d_in[13];
    const float* W1    = (const float*)d_in[14];
    const float* b1    = (const float*)d_in[15];
    const float* W2    = (const float*)d_in[16];
    const float* b2    = (const float*)d_in[17];
    const float* Wt    = (const float*)d_in[18];
    const float* Wout  = (const float*)d_in[19];
    const float* bout  = (const float*)d_in[20];
    float* out = (float*)d_out;

    int CBc = (ws_size >= ws_need(256)) ? 256 : 128;
    int NCH = NB / CBc;
    size_t CMc = (size_t)CBc * NS;

    char* p = (char*)d_ws;
    auto alloc = [&](size_t bytes) { char* r = p; p += (bytes + 255) & ~(size_t)255; return r; };
    u16*   QKV16 = (u16*)  alloc(CMc * 1536 * 2);
    u16*   S16   = (u16*)  alloc(CMc * 160 * 2);
    u16*   AO16  = (u16*)  alloc(CMc * 512 * 2);
    u16*   Y116  = (u16*)  alloc(CMc * 512 * 2);
    u16*   ACT16 = (u16*)  alloc(CMc * 256 * 2);
    float* Y2    = (float*)alloc(CMc * 512 * 4);
    float* T1    = (float*)alloc((size_t)CBc * 512 * 4);
    float* U     = (float*)alloc((size_t)CBc * 512 * 4);
    u16*   Wqkv16= (u16*)  alloc(1536 * 160 * 2);
    u16*   Wo16  = (u16*)  alloc(512 * 512 * 2);
    u16*   W116  = (u16*)  alloc(256 * 512 * 2);
    u16*   W216  = (u16*)  alloc(512 * 256 * 2);
    float* Cqkv  = (float*)alloc(100 * 1536 * 4);
    float* b1p   = (float*)alloc(256 * 4);

    prep_w_kernel<<<1536, 256, 0, stream>>>(Wq, Wk, Wv, Wfeat, Wqkv16);
    prep_c_kernel<<<300, 256, 0, stream>>>(Wq, Wk, Wv, bq, bk, bv, bfeat, pe, Cqkv);
    pad_cast_kernel<<<(512 * 512) / 256, 256, 0, stream>>>(Wo, Wo16, 512, 512, 512, 512 * 512);
    pad_cast_kernel<<<(256 * 512) / 256, 256, 0, stream>>>(W1, W116, NF, 512, 512, 256 * 512);
    pad_cast_kernel<<<(512 * 256) / 256, 256, 0, stream>>>(W2, W216, 512, NF, 256, 512 * 256);
    pad_b1_kernel<<<1, 256, 0, stream>>>(b1, b1p);

    dim3 gQKV(12, CMc / 128);
    dim3 g256(2, CMc / 128);
    dim3 gU(8, CBc / 16);
    int gLN = CMc / 64;

    for (int c = 0; c < NCH; ++c) {
        const float* srcC = src + (size_t)c * CMc * NF;
        float* outC = out + (size_t)c * CBc;

        cast_src_kernel<<<(CMc * 160) / 256, 256, 0, stream>>>(srcC, S16);
        // q|k|v = src16 @ Wqkv16^T + Cqkv[s]  (K=160 fully staged, bf16 out)
        gemm_qkv<<<gQKV, 256, 0, stream>>>(S16, Wqkv16, Cqkv, QKV16);
        // MFMA attention -> AO16
        attn_kernel<<<CBc * NH, 256, 0, stream>>>(QKV16, AO16);
        // y1 = (AO16@Wo^T + bo) + LN(...) -> bf16 (fused)
        gemm_ln<1><<<gLN, 512, 0, stream>>>(AO16, Wo16, bo, lnw, lnb, Y116, 512);
        // act = relu(y1 @ W116^T + b1p) -> bf16 [CMc,256]
        gemm_bf16<1, true><<<g256, 256, 0, stream>>>(Y116, W116, b1p, ACT16, 512, 256);
        // y2 = (act@W2^T + b2) + LN(...) -> f32 (fused)
        gemm_ln<0><<<gLN, 512, 0, stream>>>(ACT16, W216, b2, lnw, lnb, Y2, 256);
        // pooling head
        u_stage1_kernel<<<gU, 256, 0, stream>>>(Y2, Wt, T1);
        u_stage2_kernel<<<gU, 256, 0, stream>>>(T1, Wt, U);
        pool_kernel<<<CBc, 256, 0, stream>>>(Y2, U, Wout, bout, outC);
    }

    (void)in_sizes; (void)n_in; (void)out_size; (void)ws_size;
}

// Round 7
// 1987.353 us; speedup vs baseline: 3.8150x; 1.0792x over previous
//
#include <hip/hip_runtime.h>
#include <math.h>

#define NB 2048
#define NS 100
#define NF 158
#define ND 512
#define NH 8

typedef unsigned short u16;
typedef __attribute__((ext_vector_type(8))) short bf16x8;
typedef __attribute__((ext_vector_type(8))) unsigned short u16x8;
typedef __attribute__((ext_vector_type(4))) float f32x4;

__device__ __forceinline__ u16 f2bf(float f) {
    union { float f; unsigned u; } v; v.f = f;
    unsigned u = v.u;
    return (u16)((u + 0x7fffu + ((u >> 16) & 1u)) >> 16);   // RNE
}

__device__ __forceinline__ void gload16(const void* g, void* l) {
    __builtin_amdgcn_global_load_lds(
        (const __attribute__((address_space(1))) unsigned*)g,
        (__attribute__((address_space(3))) unsigned*)l, 16, 0, 0);
}

// ---------------------------------------------------------------------------
// prep_w: Wqkv16[n,f] (n 0..1535) = bf16(sum_d W{q|k|v}[n&511,d] * Wf[d,f])
// ---------------------------------------------------------------------------
__global__ __launch_bounds__(256) void prep_w_kernel(
    const float* __restrict__ Wq, const float* __restrict__ Wk,
    const float* __restrict__ Wv, const float* __restrict__ Wf,
    u16* __restrict__ Wqkv)
{
    int bid = blockIdx.x;           // 0..1535
    int sel = bid >> 9;
    int r = bid & 511;
    const float* Wsrc = (sel == 0) ? Wq : (sel == 1) ? Wk : Wv;
    __shared__ float wrow[ND];
    int t = threadIdx.x;
    wrow[t] = Wsrc[(size_t)r * ND + t];
    wrow[t + 256] = Wsrc[(size_t)r * ND + t + 256];
    __syncthreads();
    if (t < 160) {
        float acc = 0.f;
        if (t < NF)
            for (int d = 0; d < ND; ++d)
                acc += wrow[d] * Wf[(size_t)d * NF + t];
        Wqkv[(size_t)bid * 160 + t] = f2bf(acc);
    }
}

// ---------------------------------------------------------------------------
// prep_c: Cqkv[s, sel*512+r] = sum_d (b_feat[d]+pe[s,d]) * W[r,d] + b[r]
// ---------------------------------------------------------------------------
__global__ __launch_bounds__(256) void prep_c_kernel(
    const float* __restrict__ Wq, const float* __restrict__ Wk, const float* __restrict__ Wv,
    const float* __restrict__ bq, const float* __restrict__ bk, const float* __restrict__ bv,
    const float* __restrict__ bfeat, const float* __restrict__ pe,
    float* __restrict__ Cqkv)
{
    int bid = blockIdx.x;           // 0..299
    int sel = bid / 100;
    int s = bid - sel * 100;
    const float* Wsrc = (sel == 0) ? Wq : (sel == 1) ? Wk : Wv;
    const float* bsrc = (sel == 0) ? bq : (sel == 1) ? bk : bv;
    __shared__ float xv[ND];
    int t = threadIdx.x;
    xv[t] = bfeat[t] + pe[(size_t)s * ND + t];
    xv[t + 256] = bfeat[t + 256] + pe[(size_t)s * ND + t + 256];
    __syncthreads();
    #pragma unroll
    for (int rr = 0; rr < 2; ++rr) {
        int r = t + (rr << 8);
        const float* wr = Wsrc + (size_t)r * ND;
        float acc = bsrc[r];
        for (int d = 0; d < ND; d += 4) {
            float4 w4 = *(const float4*)(wr + d);
            acc += w4.x * xv[d] + w4.y * xv[d+1] + w4.z * xv[d+2] + w4.w * xv[d+3];
        }
        Cqkv[(size_t)s * 1536 + (sel << 9) + r] = acc;
    }
}

// ---------------------------------------------------------------------------
__global__ __launch_bounds__(256) void pad_cast_kernel(
    const float* __restrict__ src, u16* __restrict__ dst,
    int R, int C, int Cp, int total)
{
    int idx = blockIdx.x * 256 + threadIdx.x;
    if (idx >= total) return;
    int r = idx / Cp, c = idx - r * Cp;
    float v = (r < R && c < C) ? src[(size_t)r * C + c] : 0.f;
    dst[idx] = f2bf(v);
}

__global__ __launch_bounds__(256) void pad_b1_kernel(
    const float* __restrict__ b1, float* __restrict__ b1p)
{
    int t = threadIdx.x;
    b1p[t] = (t < NF) ? b1[t] : 0.f;
}

// ---------------------------------------------------------------------------
// 8 f32 -> 8 bf16 with tail guard at NF (src rows are 8B aligned -> float2)
// ---------------------------------------------------------------------------
__device__ __forceinline__ u16x8 load8_cvt(const float* __restrict__ base, int c0) {
    u16x8 r;
    if (c0 + 8 <= NF) {
        #pragma unroll
        for (int j = 0; j < 8; j += 2) {
            float2 v = *(const float2*)(base + c0 + j);
            r[j] = f2bf(v.x); r[j + 1] = f2bf(v.y);
        }
    } else {
        #pragma unroll
        for (int j = 0; j < 8; ++j)
            r[j] = (c0 + j < NF) ? f2bf(base[c0 + j]) : (u16)0;
    }
    return r;
}

// ---------------------------------------------------------------------------
// QKV GEMM with inline f32->bf16 A conversion. K=160 staged fully in LDS
// (5 BK=32 panels). C[M,1536] = bf16(src)[M,158pad160] @ W[1536,160]^T + tab.
// One barrier, 80 MFMAs. LDS 80KB -> 2 blocks/CU.
// ---------------------------------------------------------------------------
__global__ __launch_bounds__(256) void gemm_qkv(
    const float* __restrict__ Asrc, const u16* __restrict__ W,
    const float* __restrict__ tab, u16* __restrict__ out)
{
    __shared__ short As[5 * 128 * 32];
    __shared__ short Bs[5 * 128 * 32];
    int t = threadIdx.x;
    int lane = t & 63, wave = t >> 6;
    int quad = lane >> 4, l16 = lane & 15;
    int wr = wave >> 1, wc = wave & 1;
    int m0 = blockIdx.y << 7, n0 = blockIdx.x << 7;

    int rowA = t >> 2;              // 0..63
    int koff = (t & 3) << 3;
    const float* a0 = Asrc + (size_t)(m0 + rowA) * NF;
    const float* a1 = Asrc + (size_t)(m0 + rowA + 64) * NF;
    #pragma unroll
    for (int p = 0; p < 5; ++p) {
        int c0 = (p << 5) + koff;
        *(u16x8*)(As + (p << 12) + t * 8)         = load8_cvt(a0, c0);
        *(u16x8*)(As + (p << 12) + (t + 256) * 8) = load8_cvt(a1, c0);
        gload16(W + (size_t)(n0 + rowA) * 160 + c0,      Bs + (p << 12) + t * 8);
        gload16(W + (size_t)(n0 + rowA + 64) * 160 + c0, Bs + (p << 12) + (t + 256) * 8);
    }
    __syncthreads();

    f32x4 acc[4][4];
    f32x4 z = {0.f, 0.f, 0.f, 0.f};
    #pragma unroll
    for (int mi = 0; mi < 4; ++mi)
        #pragma unroll
        for (int ni = 0; ni < 4; ++ni) acc[mi][ni] = z;

    #pragma unroll
    for (int ks = 0; ks < 5; ++ks) {
        bf16x8 af[4], bw[4];
        #pragma unroll
        for (int mi = 0; mi < 4; ++mi)
            af[mi] = *(const bf16x8*)(As + (ks << 12) + ((wr << 6) + (mi << 4) + l16) * 32 + (quad << 3));
        #pragma unroll
        for (int ni = 0; ni < 4; ++ni)
            bw[ni] = *(const bf16x8*)(Bs + (ks << 12) + ((wc << 6) + (ni << 4) + l16) * 32 + (quad << 3));
        #pragma unroll
        for (int mi = 0; mi < 4; ++mi)
            #pragma unroll
            for (int ni = 0; ni < 4; ++ni)
                acc[mi][ni] = __builtin_amdgcn_mfma_f32_16x16x32_bf16(af[mi], bw[ni], acc[mi][ni], 0, 0, 0);
    }

    #pragma unroll
    for (int mi = 0; mi < 4; ++mi) {
        #pragma unroll
        for (int r = 0; r < 4; ++r) {
            int row = m0 + (wr << 6) + (mi << 4) + (quad << 2) + r;
            const float* trow = tab + (size_t)(row % NS) * 1536;
            u16* orow = out + (size_t)row * 1536;
            #pragma unroll
            for (int ni = 0; ni < 4; ++ni) {
                int col = n0 + (wc << 6) + (ni << 4) + l16;
                orow[col] = f2bf(acc[mi][ni][r] + trow[col]);
            }
        }
    }
}

// ---------------------------------------------------------------------------
// Generic bf16 GEMM (used for FFN1): 128x128 tile, BK=32.
// ---------------------------------------------------------------------------
template<int OUTMODE, bool RELU>
__global__ __launch_bounds__(256) void gemm_bf16(
    const u16* __restrict__ A, const u16* __restrict__ W,
    const float* __restrict__ bias, void* __restrict__ Cv, int K, int ldc)
{
    __shared__ short As[128 * 32];
    __shared__ short Bs[128 * 32];
    int t = threadIdx.x;
    int lane = t & 63, wave = t >> 6;
    int quad = lane >> 4, l16 = lane & 15;
    int wr = wave >> 1, wc = wave & 1;
    int m0 = blockIdx.y << 7, n0 = blockIdx.x << 7;

    f32x4 acc[4][4];
    f32x4 z = {0.f, 0.f, 0.f, 0.f};
    #pragma unroll
    for (int mi = 0; mi < 4; ++mi)
        #pragma unroll
        for (int ni = 0; ni < 4; ++ni) acc[mi][ni] = z;

    int rowA = t >> 2;
    int cch = (t & 3) << 3;
    const u16* aSrc0 = A + (size_t)(m0 + rowA) * K + cch;
    const u16* aSrc1 = A + (size_t)(m0 + rowA + 64) * K + cch;
    const u16* bSrc0 = W + (size_t)(n0 + rowA) * K + cch;
    const u16* bSrc1 = W + (size_t)(n0 + rowA + 64) * K + cch;
    short* aDst0 = As + t * 8;
    short* aDst1 = As + (t + 256) * 8;
    short* bDst0 = Bs + t * 8;
    short* bDst1 = Bs + (t + 256) * 8;

    int nk = K >> 5;
    for (int kc = 0; kc < nk; ++kc) {
        if (kc) __syncthreads();
        gload16(aSrc0, aDst0);
        gload16(aSrc1, aDst1);
        gload16(bSrc0, bDst0);
        gload16(bSrc1, bDst1);
        aSrc0 += 32; aSrc1 += 32; bSrc0 += 32; bSrc1 += 32;
        __syncthreads();

        bf16x8 af[4], bw[4];
        #pragma unroll
        for (int mi = 0; mi < 4; ++mi)
            af[mi] = *(const bf16x8*)(As + ((size_t)((wr << 6) + (mi << 4) + l16) * 32 + (quad << 3)));
        #pragma unroll
        for (int ni = 0; ni < 4; ++ni)
            bw[ni] = *(const bf16x8*)(Bs + ((size_t)((wc << 6) + (ni << 4) + l16) * 32 + (quad << 3)));
        #pragma unroll
        for (int mi = 0; mi < 4; ++mi)
            #pragma unroll
            for (int ni = 0; ni < 4; ++ni)
                acc[mi][ni] = __builtin_amdgcn_mfma_f32_16x16x32_bf16(af[mi], bw[ni], acc[mi][ni], 0, 0, 0);
    }

    #pragma unroll
    for (int mi = 0; mi < 4; ++mi) {
        #pragma unroll
        for (int r = 0; r < 4; ++r) {
            int row = m0 + (wr << 6) + (mi << 4) + (quad << 2) + r;
            #pragma unroll
            for (int ni = 0; ni < 4; ++ni) {
                int col = n0 + (wc << 6) + (ni << 4) + l16;
                float v = acc[mi][ni][r];
                if (bias) v += bias[col];
                if (RELU) v = fmaxf(v, 0.f);
                if (OUTMODE == 0)
                    ((float*)Cv)[(size_t)row * ldc + col] = v;
                else
                    ((u16*)Cv)[(size_t)row * ldc + col] = f2bf(v);
            }
        }
    }
}

// ---------------------------------------------------------------------------
// Fused GEMM + add-LayerNorm epilogue:
//   X = A@W^T + bias  (row x 512);  out = X + LN(X)*lnw + lnb
// Block = 64 rows x full N=512, 512 threads (8 waves).
// ---------------------------------------------------------------------------
template<int OUTMODE>
__global__ __launch_bounds__(512, 2) void gemm_ln(
    const u16* __restrict__ A, const u16* __restrict__ W,
    const float* __restrict__ bias, const float* __restrict__ lnw,
    const float* __restrict__ lnb, void* __restrict__ outv, int K)
{
    __shared__ short As[64 * 32];      // 4 KB
    __shared__ short Bs[512 * 32];     // 32 KB
    __shared__ float red_s[64][9];
    __shared__ float red_q[64][9];
    __shared__ float mrow[64], rrow[64];

    int t = threadIdx.x;
    int lane = t & 63, wave = t >> 6;
    int quad = lane >> 4, l16 = lane & 15;
    int m0 = blockIdx.x << 6;

    f32x4 acc[4][4];
    f32x4 z = {0.f, 0.f, 0.f, 0.f};
    #pragma unroll
    for (int mi = 0; mi < 4; ++mi)
        #pragma unroll
        for (int ni = 0; ni < 4; ++ni) acc[mi][ni] = z;

    int koff = (t & 3) << 3;
    const u16* aSrc = A + (size_t)(m0 + (t >> 2)) * K + koff;   // t<256 -> rows 0..63
    const u16* bSrc0 = W + (size_t)(t >> 2) * K + koff;
    const u16* bSrc1 = W + (size_t)((t >> 2) + 128) * K + koff;
    const u16* bSrc2 = W + (size_t)((t >> 2) + 256) * K + koff;
    const u16* bSrc3 = W + (size_t)((t >> 2) + 384) * K + koff;
    short* aDst = As + t * 8;
    short* bDst0 = Bs + t * 8;
    short* bDst1 = Bs + (t + 512) * 8;
    short* bDst2 = Bs + (t + 1024) * 8;
    short* bDst3 = Bs + (t + 1536) * 8;

    int nk = K >> 5;
    for (int kc = 0; kc < nk; ++kc) {
        if (kc) __syncthreads();
        if (t < 256) gload16(aSrc, aDst);
        gload16(bSrc0, bDst0);
        gload16(bSrc1, bDst1);
        gload16(bSrc2, bDst2);
        gload16(bSrc3, bDst3);
        aSrc += 32; bSrc0 += 32; bSrc1 += 32; bSrc2 += 32; bSrc3 += 32;
        __syncthreads();

        bf16x8 af[4], bw[4];
        #pragma unroll
        for (int mi = 0; mi < 4; ++mi)
            af[mi] = *(const bf16x8*)(As + ((mi << 4) + l16) * 32 + (quad << 3));
        #pragma unroll
        for (int ni = 0; ni < 4; ++ni)
            bw[ni] = *(const bf16x8*)(Bs + ((wave << 6) + (ni << 4) + l16) * 32 + (quad << 3));
        #pragma unroll
        for (int mi = 0; mi < 4; ++mi)
            #pragma unroll
            for (int ni = 0; ni < 4; ++ni)
                acc[mi][ni] = __builtin_amdgcn_mfma_f32_16x16x32_bf16(af[mi], bw[ni], acc[mi][ni], 0, 0, 0);
    }

    // epilogue: bias add, per-row stats (512 cols), add-LN, store
    float lwv[4], lbv[4];
    #pragma unroll
    for (int ni = 0; ni < 4; ++ni) {
        int col = (wave << 6) + (ni << 4) + l16;
        float bv = bias[col];
        lwv[ni] = lnw[col];
        lbv[ni] = lnb[col];
        #pragma unroll
        for (int mi = 0; mi < 4; ++mi)
            #pragma unroll
            for (int r = 0; r < 4; ++r) acc[mi][ni][r] += bv;
    }
    #pragma unroll
    for (int mi = 0; mi < 4; ++mi) {
        #pragma unroll
        for (int r = 0; r < 4; ++r) {
            float s = acc[mi][0][r] + acc[mi][1][r] + acc[mi][2][r] + acc[mi][3][r];
            float q = acc[mi][0][r]*acc[mi][0][r] + acc[mi][1][r]*acc[mi][1][r]
                    + acc[mi][2][r]*acc[mi][2][r] + acc[mi][3][r]*acc[mi][3][r];
            #pragma unroll
            for (int off = 1; off < 16; off <<= 1) {
                s += __shfl_xor(s, off);
                q += __shfl_xor(q, off);
            }
            if (l16 == 0) {
                int row = (mi << 4) + (quad << 2) + r;
                red_s[row][wave] = s;
                red_q[row][wave] = q;
            }
        }
    }
    __syncthreads();
    if (t < 64) {
        float s = 0.f, q = 0.f;
        #pragma unroll
        for (int w8 = 0; w8 < 8; ++w8) { s += red_s[t][w8]; q += red_q[t][w8]; }
        float mean = s * (1.f / 512.f);
        float var = q * (1.f / 512.f) - mean * mean;
        mrow[t] = mean;
        rrow[t] = rsqrtf(var + 1e-5f);
    }
    __syncthreads();
    #pragma unroll
    for (int mi = 0; mi < 4; ++mi) {
        #pragma unroll
        for (int r = 0; r < 4; ++r) {
            int lrow = (mi << 4) + (quad << 2) + r;
            float mean = mrow[lrow], rstd = rrow[lrow];
            size_t grow = (size_t)(m0 + lrow) * 512;
            #pragma unroll
            for (int ni = 0; ni < 4; ++ni) {
                int col = (wave << 6) + (ni << 4) + l16;
                float v = acc[mi][ni][r];
                float y = v + (v - mean) * rstd * lwv[ni] + lbv[ni];
                if (OUTMODE == 0) ((float*)outv)[grow + col] = y;
                else ((u16*)outv)[grow + col] = f2bf(y);
            }
        }
    }
}

// ---------------------------------------------------------------------------
// MFMA attention (R4-proven, unchanged): one block per (b_local, h).
// ---------------------------------------------------------------------------
#define ALDQ 72
#define ALDP 136

__global__ __launch_bounds__(256) void attn_kernel(
    const u16* __restrict__ QKV, u16* __restrict__ O)
{
    __shared__ short UN[128 * ALDP];
    __shared__ short Ks[112 * ALDQ];
    __shared__ short Vt[64 * ALDP];

    int t = threadIdx.x;
    int lane = t & 63, wave = t >> 6;
    int quad = lane >> 4, l16 = lane & 15;
    int rows0 = wave << 5;
    int bh = blockIdx.x;
    int b = bh >> 3, h = bh & 7;
    const size_t rowbase = (size_t)b * NS;
    const u16* qptr = QKV + rowbase * 1536 + (h << 6);

    for (int l = t; l < 800; l += 256) {
        int s = l >> 3, seg = (l & 7) << 3;
        const u16* g = qptr + (size_t)s * 1536 + seg;
        *(u16x8*)&UN[s * ALDQ + seg] = *(const u16x8*)g;
        *(u16x8*)&Ks[s * ALDQ + seg] = *(const u16x8*)(g + 512);
        u16x8 v8 = *(const u16x8*)(g + 1024);
        #pragma unroll
        for (int i = 0; i < 8; ++i) Vt[(seg + i) * ALDP + s] = (short)v8[i];
    }
    for (int l = t; l < 64 * 28; l += 256) {
        int c = l / 28, k = 100 + (l - c * 28);
        Vt[c * ALDP + k] = 0;
    }
    __syncthreads();

    f32x4 sc[2][7];
    f32x4 z = {0.f, 0.f, 0.f, 0.f};
    #pragma unroll
    for (int mi = 0; mi < 2; ++mi)
        #pragma unroll
        for (int ni = 0; ni < 7; ++ni) sc[mi][ni] = z;

    #pragma unroll
    for (int ks = 0; ks < 2; ++ks) {
        bf16x8 aq[2], bk[7];
        #pragma unroll
        for (int mi = 0; mi < 2; ++mi)
            aq[mi] = *(const bf16x8*)&UN[(rows0 + (mi << 4) + l16) * ALDQ + (ks << 5) + (quad << 3)];
        #pragma unroll
        for (int ni = 0; ni < 7; ++ni)
            bk[ni] = *(const bf16x8*)&Ks[((ni << 4) + l16) * ALDQ + (ks << 5) + (quad << 3)];
        #pragma unroll
        for (int mi = 0; mi < 2; ++mi)
            #pragma unroll
            for (int ni = 0; ni < 7; ++ni)
                sc[mi][ni] = __builtin_amdgcn_mfma_f32_16x16x32_bf16(aq[mi], bk[ni], sc[mi][ni], 0, 0, 0);
    }
    __syncthreads();

    #pragma unroll
    for (int mi = 0; mi < 2; ++mi) {
        #pragma unroll
        for (int r = 0; r < 4; ++r) {
            if (l16 >= 4) sc[mi][6][r] = -3.0e38f;
            float mx = sc[mi][0][r];
            #pragma unroll
            for (int ni = 1; ni < 7; ++ni) mx = fmaxf(mx, sc[mi][ni][r]);
            #pragma unroll
            for (int off = 1; off < 16; off <<= 1) mx = fmaxf(mx, __shfl_xor(mx, off));
            float sum = 0.f;
            #pragma unroll
            for (int ni = 0; ni < 7; ++ni) {
                float e = expf((sc[mi][ni][r] - mx) * 0.125f);
                sc[mi][ni][r] = e; sum += e;
            }
            #pragma unroll
            for (int off = 1; off < 16; off <<= 1) sum += __shfl_xor(sum, off);
            float inv = 1.f / sum;
            int row = rows0 + (mi << 4) + (quad << 2) + r;
            #pragma unroll
            for (int ni = 0; ni < 7; ++ni)
                UN[row * ALDP + (ni << 4) + l16] = (short)f2bf(sc[mi][ni][r] * inv);
            UN[row * ALDP + 112 + l16] = 0;
        }
    }
    __syncthreads();

    f32x4 oa[2][4];
    #pragma unroll
    for (int mi = 0; mi < 2; ++mi)
        #pragma unroll
        for (int ni = 0; ni < 4; ++ni) oa[mi][ni] = z;

    #pragma unroll
    for (int ks = 0; ks < 4; ++ks) {
        bf16x8 ap[2], bv[4];
        #pragma unroll
        for (int mi = 0; mi < 2; ++mi)
            ap[mi] = *(const bf16x8*)&UN[(rows0 + (mi << 4) + l16) * ALDP + (ks << 5) + (quad << 3)];
        #pragma unroll
        for (int ni = 0; ni < 4; ++ni)
            bv[ni] = *(const bf16x8*)&Vt[((ni << 4) + l16) * ALDP + (ks << 5) + (quad << 3)];
        #pragma unroll
        for (int mi = 0; mi < 2; ++mi)
            #pragma unroll
            for (int ni = 0; ni < 4; ++ni)
                oa[mi][ni] = __builtin_amdgcn_mfma_f32_16x16x32_bf16(ap[mi], bv[ni], oa[mi][ni], 0, 0, 0);
    }

    #pragma unroll
    for (int mi = 0; mi < 2; ++mi) {
        #pragma unroll
        for (int r = 0; r < 4; ++r) {
            int row = rows0 + (mi << 4) + (quad << 2) + r;
            if (row < NS) {
                u16* orow = O + (rowbase + row) * 512 + (h << 6);
                #pragma unroll
                for (int ni = 0; ni < 4; ++ni)
                    orow[(ni << 4) + l16] = f2bf(oa[mi][ni][r]);
            }
        }
    }
}

// ---------------------------------------------------------------------------
// u_stage1: T1[b,r] = dot(Wt[r,:], Y2[b, last, :])
// ---------------------------------------------------------------------------
__global__ __launch_bounds__(256) void u_stage1_kernel(
    const float* __restrict__ Y2, const float* __restrict__ Wt,
    float* __restrict__ T1)
{
    __shared__ float yl[16][512];
    int t = threadIdx.x;
    int r0 = blockIdx.x << 6;
    int bg = blockIdx.y << 4;
    for (int l = t; l < 2048; l += 256) {
        int bb = l >> 7, seg = (l & 127) << 2;
        *(float4*)&yl[bb][seg] =
            *(const float4*)&Y2[((size_t)(bg + bb) * NS + 99) * ND + seg];
    }
    __syncthreads();
    int r = r0 + (t & 63);
    int b0 = t >> 6;
    const float* wr = Wt + (size_t)r * ND;
    float acc[4] = {0.f, 0.f, 0.f, 0.f};
    for (int d = 0; d < ND; d += 4) {
        float4 w4 = *(const float4*)(wr + d);
        #pragma unroll
        for (int bb = 0; bb < 4; ++bb) {
            int bl = (b0 << 2) + bb;
            acc[bb] += w4.x * yl[bl][d] + w4.y * yl[bl][d+1]
                     + w4.z * yl[bl][d+2] + w4.w * yl[bl][d+3];
        }
    }
    #pragma unroll
    for (int bb = 0; bb < 4; ++bb)
        T1[(size_t)(bg + (b0 << 2) + bb) * ND + r] = acc[bb];
}

__global__ __launch_bounds__(256) void u_stage2_kernel(
    const float* __restrict__ T1, const float* __restrict__ Wt,
    float* __restrict__ U)
{
    __shared__ float t1s[16][512];
    int t = threadIdx.x;
    int c0 = blockIdx.x << 6;
    int bg = blockIdx.y << 4;
    for (int l = t; l < 2048; l += 256) {
        int bb = l >> 7, seg = (l & 127) << 2;
        *(float4*)&t1s[bb][seg] = *(const float4*)&T1[(size_t)(bg + bb) * ND + seg];
    }
    __syncthreads();
    int c = c0 + (t & 63);
    int b0 = t >> 6;
    float acc[4] = {0.f, 0.f, 0.f, 0.f};
    for (int r = 0; r < ND; ++r) {
        float w = Wt[(size_t)r * ND + c];
        #pragma unroll
        for (int bb = 0; bb < 4; ++bb)
            acc[bb] += w * t1s[(b0 << 2) + bb][r];
    }
    #pragma unroll
    for (int bb = 0; bb < 4; ++bb)
        U[(size_t)(bg + (b0 << 2) + bb) * ND + c] = acc[bb];
}

// ---------------------------------------------------------------------------
__global__ __launch_bounds__(256) void pool_kernel(
    const float* __restrict__ Y2, const float* __restrict__ U,
    const float* __restrict__ Wout, const float* __restrict__ bout,
    float* __restrict__ out)
{
    __shared__ float u[ND];
    __shared__ float lam[128];
    __shared__ float red[4];
    int t = threadIdx.x;
    int b = blockIdx.x;
    const float* y2b = Y2 + (size_t)b * NS * ND;
    u[t] = U[(size_t)b * ND + t];
    u[t + 256] = U[(size_t)b * ND + t + 256];
    __syncthreads();
    int wid = t >> 6, lane = t & 63;
    int c0 = lane << 2;
    for (int s = wid; s < NS; s += 4) {
        const float* yr = y2b + (size_t)s * ND;
        float4 p0 = *(const float4*)(yr + c0);
        float4 p1 = *(const float4*)(yr + 256 + c0);
        float a = p0.x*u[c0] + p0.y*u[c0+1] + p0.z*u[c0+2] + p0.w*u[c0+3]
                + p1.x*u[256+c0] + p1.y*u[256+c0+1] + p1.z*u[256+c0+2] + p1.w*u[256+c0+3];
        #pragma unroll
        for (int off = 32; off > 0; off >>= 1) a += __shfl_xor(a, off);
        if (lane == 0) lam[s] = a;
    }
    __syncthreads();
    if (t < 64) {
        float l0 = lam[t];
        float l1 = (t + 64 < NS) ? lam[t + 64] : -3.0e38f;
        float mx = fmaxf(l0, l1);
        #pragma unroll
        for (int off = 32; off > 0; off >>= 1) mx = fmaxf(mx, __shfl_xor(mx, off));
        float e0 = expf(l0 - mx);
        float e1 = (t + 64 < NS) ? expf(l1 - mx) : 0.f;
        float ssum = e0 + e1;
        #pragma unroll
        for (int off = 32; off > 0; off >>= 1) ssum += __shfl_xor(ssum, off);
        float inv = 1.f / ssum;
        lam[t] = e0 * inv;
        if (t + 64 < NS) lam[t + 64] = e1 * inv;
    }
    __syncthreads();
    float p0 = 0.f, p1 = 0.f;
    for (int s = 0; s < NS; ++s) {
        float lm = lam[s];
        const float* yr = y2b + (size_t)s * ND;
        p0 += lm * yr[t];
        p1 += lm * yr[t + 256];
    }
    float vd = p0 * Wout[t] + p1 * Wout[t + 256];
    #pragma unroll
    for (int off = 32; off > 0; off >>= 1) vd += __shfl_xor(vd, off);
    if (lane == 0) red[wid] = vd;
    __syncthreads();
    if (t == 0) out[b] = red[0] + red[1] + red[2] + red[3] + bout[0];
}

// ---------------------------------------------------------------------------
static size_t ws_need(int CBc) {
    size_t cm = (size_t)CBc * NS;
    size_t b = 0;
    b += cm * 1536 * 2;        // QKV16
    b += cm * 512 * 2;         // AO16
    b += cm * 512 * 2;         // Y116
    b += cm * 256 * 2;         // ACT16
    b += cm * 512 * 4;         // Y2
    b += (size_t)CBc * 512 * 4 * 2;  // T1, U
    b += 1536 * 160 * 2 + 512 * 512 * 2 + 256 * 512 * 2 + 512 * 256 * 2;
    b += 100 * 1536 * 4 + 256 * 4;
    b += 64 * 1024;
    return b;
}

extern "C" void kernel_launch(void* const* d_in, const int* in_sizes, int n_in,
                              void* d_out, int out_size, void* d_ws, size_t ws_size,
                              hipStream_t stream)
{
    const float* src   = (const float*)d_in[0];
    const float* Wfeat = (const float*)d_in[1];
    const float* bfeat = (const float*)d_in[2];
    const float* pe    = (const float*)d_in[3];
    const float* Wq    = (const float*)d_in[4];
    const float* bq    = (const float*)d_in[5];
    const float* Wk    = (const float*)d_in[6];
    const float* bk    = (const float*)d_in[7];
    const float* Wv    = (const float*)d_in[8];
    const float* bv    = (const float*)d_in[9];
    const float* Wo    = (const float*)d_in[10];
    const float* bo    = (const float*)d_in[11];
    const float* lnw   = (const float*)d_in[12];
    const float* lnb   = (const float*)d_in[13];
    const float* W1    = (const float*)d_in[14];
    const float* b1    = (const float*)d_in[15];
    const float* W2    = (const float*)d_in[16];
    const float* b2    = (const float*)d_in[17];
    const float* Wt    = (const float*)d_in[18];
    const float* Wout  = (const float*)d_in[19];
    const float* bout  = (const float*)d_in[20];
    float* out = (float*)d_out;

    // chunk size: largest of {512,256,128} that fits d_ws (deterministic)
    int CBc = (ws_size >= ws_need(512)) ? 512
            : (ws_size >= ws_need(256)) ? 256 : 128;
    int NCH = NB / CBc;
    size_t CMc = (size_t)CBc * NS;

    char* p = (char*)d_ws;
    auto alloc = [&](size_t bytes) { char* r = p; p += (bytes + 255) & ~(size_t)255; return r; };
    u16*   QKV16 = (u16*)  alloc(CMc * 1536 * 2);
    u16*   AO16  = (u16*)  alloc(CMc * 512 * 2);
    u16*   Y116  = (u16*)  alloc(CMc * 512 * 2);
    u16*   ACT16 = (u16*)  alloc(CMc * 256 * 2);
    float* Y2    = (float*)alloc(CMc * 512 * 4);
    float* T1    = (float*)alloc((size_t)CBc * 512 * 4);
    float* U     = (float*)alloc((size_t)CBc * 512 * 4);
    u16*   Wqkv16= (u16*)  alloc(1536 * 160 * 2);
    u16*   Wo16  = (u16*)  alloc(512 * 512 * 2);
    u16*   W116  = (u16*)  alloc(256 * 512 * 2);
    u16*   W216  = (u16*)  alloc(512 * 256 * 2);
    float* Cqkv  = (float*)alloc(100 * 1536 * 4);
    float* b1p   = (float*)alloc(256 * 4);

    prep_w_kernel<<<1536, 256, 0, stream>>>(Wq, Wk, Wv, Wfeat, Wqkv16);
    prep_c_kernel<<<300, 256, 0, stream>>>(Wq, Wk, Wv, bq, bk, bv, bfeat, pe, Cqkv);
    pad_cast_kernel<<<(512 * 512) / 256, 256, 0, stream>>>(Wo, Wo16, 512, 512, 512, 512 * 512);
    pad_cast_kernel<<<(256 * 512) / 256, 256, 0, stream>>>(W1, W116, NF, 512, 512, 256 * 512);
    pad_cast_kernel<<<(512 * 256) / 256, 256, 0, stream>>>(W2, W216, 512, NF, 256, 512 * 256);
    pad_b1_kernel<<<1, 256, 0, stream>>>(b1, b1p);

    dim3 gQKV(12, CMc / 128);
    dim3 g256(2, CMc / 128);
    dim3 gU(8, CBc / 16);
    int gLN = CMc / 64;

    for (int c = 0; c < NCH; ++c) {
        const float* srcC = src + (size_t)c * CMc * NF;
        float* outC = out + (size_t)c * CBc;

        // q|k|v = bf16(srcC) @ Wqkv16^T + Cqkv[s]  (K=160, inline cast, bf16 out)
        gemm_qkv<<<gQKV, 256, 0, stream>>>(srcC, Wqkv16, Cqkv, QKV16);
        // MFMA attention -> AO16
        attn_kernel<<<CBc * NH, 256, 0, stream>>>(QKV16, AO16);
        // y1 = (AO16@Wo^T + bo) + LN(...) -> bf16 (fused)
        gemm_ln<1><<<gLN, 512, 0, stream>>>(AO16, Wo16, bo, lnw, lnb, Y116, 512);
        // act = relu(y1 @ W116^T + b1p) -> bf16 [CMc,256]
        gemm_bf16<1, true><<<g256, 256, 0, stream>>>(Y116, W116, b1p, ACT16, 512, 256);
        // y2 = (act@W2^T + b2) + LN(...) -> f32 (fused)
        gemm_ln<0><<<gLN, 512, 0, stream>>>(ACT16, W216, b2, lnw, lnb, Y2, 256);
        // pooling head
        u_stage1_kernel<<<gU, 256, 0, stream>>>(Y2, Wt, T1);
        u_stage2_kernel<<<gU, 256, 0, stream>>>(T1, Wt, U);
        pool_kernel<<<CBc, 256, 0, stream>>>(Y2, U, Wout, bout, outC);
    }

    (void)in_sizes; (void)n_in; (void)out_size; (void)ws_size;
}

// Round 8
// 1832.960 us; speedup vs baseline: 4.1364x; 1.0842x over previous
//
#include <hip/hip_runtime.h>
#include <math.h>

#define NB 2048
#define NS 100
#define NF 158
#define ND 512
#define NH 8

typedef unsigned short u16;
typedef __attribute__((ext_vector_type(8))) short bf16x8;
typedef __attribute__((ext_vector_type(8))) unsigned short u16x8;
typedef __attribute__((ext_vector_type(4))) float f32x4;

__device__ __forceinline__ u16 f2bf(float f) {
    union { float f; unsigned u; } v; v.f = f;
    unsigned u = v.u;
    return (u16)((u + 0x7fffu + ((u >> 16) & 1u)) >> 16);   // RNE
}

__device__ __forceinline__ void gload16(const void* g, void* l) {
    __builtin_amdgcn_global_load_lds(
        (const __attribute__((address_space(1))) unsigned*)g,
        (__attribute__((address_space(3))) unsigned*)l, 16, 0, 0);
}

// 8 f32 -> bf16x8 with tail guard at NF (src rows 8B aligned -> float2)
__device__ __forceinline__ bf16x8 load8_cvt(const float* __restrict__ base, int c0) {
    bf16x8 r;
    if (c0 + 8 <= NF) {
        #pragma unroll
        for (int j = 0; j < 8; j += 2) {
            float2 v = *(const float2*)(base + c0 + j);
            r[j] = (short)f2bf(v.x); r[j + 1] = (short)f2bf(v.y);
        }
    } else {
        #pragma unroll
        for (int j = 0; j < 8; ++j)
            r[j] = (c0 + j < NF) ? (short)f2bf(base[c0 + j]) : (short)0;
    }
    return r;
}

// ---------------------------------------------------------------------------
// prep_w: folded QKV weights -> MFMA-B-fragment layout
// Wf[((((sel*8+h)*4+ni)*5+ks)*64 + quad*16+l16)*8 + j] = bf16(Wsel[n,:]@Wfeat[:,f])
//   n = h*64+ni*16+l16 (bid&511), f = ks*32+quad*8+j (thread t<160)
// ---------------------------------------------------------------------------
__global__ __launch_bounds__(256) void prep_w_kernel(
    const float* __restrict__ Wq, const float* __restrict__ Wk,
    const float* __restrict__ Wv, const float* __restrict__ Wfeat,
    u16* __restrict__ Wf)
{
    int bid = blockIdx.x;           // 0..1535
    int sel = bid >> 9;
    int n = bid & 511;
    const float* Wsrc = (sel == 0) ? Wq : (sel == 1) ? Wk : Wv;
    __shared__ float wrow[ND];
    int t = threadIdx.x;
    wrow[t] = Wsrc[(size_t)n * ND + t];
    wrow[t + 256] = Wsrc[(size_t)n * ND + t + 256];
    __syncthreads();
    if (t < 160) {
        float acc = 0.f;
        if (t < NF)
            for (int d = 0; d < ND; ++d)
                acc += wrow[d] * Wfeat[(size_t)d * NF + t];
        int h = n >> 6, ni = (n >> 4) & 3, l16 = n & 15;
        int ks = t >> 5, quad = (t >> 3) & 3, j = t & 7;
        size_t idx = (((((size_t)sel * 8 + h) * 4 + ni) * 5 + ks) * 64
                      + (quad << 4) + l16) * 8 + j;
        Wf[idx] = f2bf(acc);
    }
}

// ---------------------------------------------------------------------------
// prep_c: Cqkv[s, sel*512+n] = (b_feat+pe[s]) @ W[n,:] + b[n]   (f32 [100,1536])
// ---------------------------------------------------------------------------
__global__ __launch_bounds__(256) void prep_c_kernel(
    const float* __restrict__ Wq, const float* __restrict__ Wk, const float* __restrict__ Wv,
    const float* __restrict__ bq, const float* __restrict__ bk, const float* __restrict__ bv,
    const float* __restrict__ bfeat, const float* __restrict__ pe,
    float* __restrict__ Cqkv)
{
    int bid = blockIdx.x;           // 0..299
    int sel = bid / 100;
    int s = bid - sel * 100;
    const float* Wsrc = (sel == 0) ? Wq : (sel == 1) ? Wk : Wv;
    const float* bsrc = (sel == 0) ? bq : (sel == 1) ? bk : bv;
    __shared__ float xv[ND];
    int t = threadIdx.x;
    xv[t] = bfeat[t] + pe[(size_t)s * ND + t];
    xv[t + 256] = bfeat[t + 256] + pe[(size_t)s * ND + t + 256];
    __syncthreads();
    #pragma unroll
    for (int rr = 0; rr < 2; ++rr) {
        int r = t + (rr << 8);
        const float* wr = Wsrc + (size_t)r * ND;
        float acc = bsrc[r];
        for (int d = 0; d < ND; d += 4) {
            float4 w4 = *(const float4*)(wr + d);
            acc += w4.x * xv[d] + w4.y * xv[d+1] + w4.z * xv[d+2] + w4.w * xv[d+3];
        }
        Cqkv[(size_t)s * 1536 + (sel << 9) + r] = acc;
    }
}

// ---------------------------------------------------------------------------
__global__ __launch_bounds__(256) void pad_cast_kernel(
    const float* __restrict__ src, u16* __restrict__ dst,
    int R, int C, int Cp, int total)
{
    int idx = blockIdx.x * 256 + threadIdx.x;
    if (idx >= total) return;
    int r = idx / Cp, c = idx - r * Cp;
    float v = (r < R && c < C) ? src[(size_t)r * C + c] : 0.f;
    dst[idx] = f2bf(v);
}

__global__ __launch_bounds__(256) void pad_b1_kernel(
    const float* __restrict__ b1, float* __restrict__ b1p)
{
    int t = threadIdx.x;
    b1p[t] = (t < NF) ? b1[t] : 0.f;
}

// ---------------------------------------------------------------------------
// FUSED QKV + attention. One block per batch b, 256 threads.
//  - X A-frags (2 m-tiles/wave, K=160) from f32 src -> registers (bf16)
//  - per head: q/k/v via MFMA (B-frags streamed from Wf, L2-resident),
//    +Cqkv tab, bf16 -> LDS (Q->UN, K->Ks, V->Vt transposed)
//  - then R4-proven S/softmax/PV, O -> global bf16.
// LDS 66.8 KB -> 2 blocks/CU. Rounding chain identical to R7 path.
// ---------------------------------------------------------------------------
#define ALDQ 72     // Ks row stride (shorts)
#define ALDP 136    // UN (Q/P) and Vt row stride (shorts)

__global__ __launch_bounds__(256) void qkv_attn_kernel(
    const float* __restrict__ src, const u16* __restrict__ Wf,
    const float* __restrict__ tab, u16* __restrict__ O)
{
    __shared__ short UN[128 * ALDP];   // Q (cols 0..63), later P (cols 0..127)
    __shared__ short Ks[112 * ALDQ];
    __shared__ short Vt[64 * ALDP];

    int t = threadIdx.x;
    int lane = t & 63, wave = t >> 6;
    int quad = lane >> 4, l16 = lane & 15;
    int rows0 = wave << 5;             // this wave's 32 rows
    int b = blockIdx.x;
    const float* xb = src + (size_t)b * NS * NF;
    const size_t rowbase = (size_t)b * NS;
    f32x4 z = {0.f, 0.f, 0.f, 0.f};

    // static zero pads (persist across heads; per-head writes never touch them)
    for (int l = t; l < 12 * ALDQ; l += 256)
        Ks[(100 + l / ALDQ) * ALDQ + (l % ALDQ)] = 0;
    for (int l = t; l < 64 * 28; l += 256) {
        int d = l / 28, s = 100 + (l - d * 28);
        Vt[d * ALDP + s] = 0;
    }

    // X A-fragments for this wave's rows (rows >= 100 -> zero), kept in VGPRs
    bf16x8 AF[2][5];
    #pragma unroll
    for (int mt = 0; mt < 2; ++mt) {
        int row = rows0 + (mt << 4) + l16;
        const float* xr = xb + (size_t)row * NF;
        #pragma unroll
        for (int ks = 0; ks < 5; ++ks) {
            if (row < NS) AF[mt][ks] = load8_cvt(xr, (ks << 5) + (quad << 3));
            else { bf16x8 zz = {0,0,0,0,0,0,0,0}; AF[mt][ks] = zz; }
        }
    }

    for (int h = 0; h < NH; ++h) {
        // ---- q/k/v for head h (each wave: rows rows0..rows0+31, all 64 head-dims)
        #pragma unroll
        for (int sel = 0; sel < 3; ++sel) {
            f32x4 acc[2][4];
            #pragma unroll
            for (int mt = 0; mt < 2; ++mt)
                #pragma unroll
                for (int ni = 0; ni < 4; ++ni) acc[mt][ni] = z;
            #pragma unroll
            for (int ks = 0; ks < 5; ++ks) {
                bf16x8 wfr[4];
                #pragma unroll
                for (int ni = 0; ni < 4; ++ni)
                    wfr[ni] = *(const bf16x8*)(Wf +
                        (((((size_t)sel * 8 + h) * 4 + ni) * 5 + ks) * 64 + lane) * 8);
                #pragma unroll
                for (int mt = 0; mt < 2; ++mt)
                    #pragma unroll
                    for (int ni = 0; ni < 4; ++ni)
                        acc[mt][ni] = __builtin_amdgcn_mfma_f32_16x16x32_bf16(
                            AF[mt][ks], wfr[ni], acc[mt][ni], 0, 0, 0);
            }
            // epilogue: +tab, bf16 -> LDS
            #pragma unroll
            for (int mt = 0; mt < 2; ++mt) {
                int rbase = rows0 + (mt << 4) + (quad << 2);
                #pragma unroll
                for (int r = 0; r < 4; ++r) {
                    int row_s = rbase + r;
                    bool real = row_s < NS;
                    const float* trow = tab + (size_t)(real ? row_s : 0) * 1536
                                        + (sel << 9) + (h << 6);
                    #pragma unroll
                    for (int ni = 0; ni < 4; ++ni) {
                        int nloc = (ni << 4) + l16;
                        float v = acc[mt][ni][r] + (real ? trow[nloc] : 0.f);
                        u16 bv = f2bf(v);
                        if (sel == 0) UN[row_s * ALDP + nloc] = (short)bv;          // Q all rows (pad rows = 0)
                        else if (sel == 1) { if (real) Ks[row_s * ALDQ + nloc] = (short)bv; }
                        else               { if (real) Vt[nloc * ALDP + row_s] = (short)bv; }
                    }
                }
            }
        }
        __syncthreads();

        // ---- S = Q K^T  (2 row-tiles x 7 col-tiles per wave, K=64)
        f32x4 sc[2][7];
        #pragma unroll
        for (int mi = 0; mi < 2; ++mi)
            #pragma unroll
            for (int ni = 0; ni < 7; ++ni) sc[mi][ni] = z;
        #pragma unroll
        for (int ks = 0; ks < 2; ++ks) {
            bf16x8 aq[2], bk[7];
            #pragma unroll
            for (int mi = 0; mi < 2; ++mi)
                aq[mi] = *(const bf16x8*)&UN[(rows0 + (mi << 4) + l16) * ALDP + (ks << 5) + (quad << 3)];
            #pragma unroll
            for (int ni = 0; ni < 7; ++ni)
                bk[ni] = *(const bf16x8*)&Ks[((ni << 4) + l16) * ALDQ + (ks << 5) + (quad << 3)];
            #pragma unroll
            for (int mi = 0; mi < 2; ++mi)
                #pragma unroll
                for (int ni = 0; ni < 7; ++ni)
                    sc[mi][ni] = __builtin_amdgcn_mfma_f32_16x16x32_bf16(aq[mi], bk[ni], sc[mi][ni], 0, 0, 0);
        }
        __syncthreads();   // all waves done reading Q before P overwrites UN

        // ---- softmax in registers; P (bf16) into UN stride 136
        #pragma unroll
        for (int mi = 0; mi < 2; ++mi) {
            #pragma unroll
            for (int r = 0; r < 4; ++r) {
                if (l16 >= 4) sc[mi][6][r] = -3.0e38f;   // cols 100..111 masked
                float mx = sc[mi][0][r];
                #pragma unroll
                for (int ni = 1; ni < 7; ++ni) mx = fmaxf(mx, sc[mi][ni][r]);
                #pragma unroll
                for (int off = 1; off < 16; off <<= 1) mx = fmaxf(mx, __shfl_xor(mx, off));
                float sum = 0.f;
                #pragma unroll
                for (int ni = 0; ni < 7; ++ni) {
                    float e = expf((sc[mi][ni][r] - mx) * 0.125f);
                    sc[mi][ni][r] = e; sum += e;
                }
                #pragma unroll
                for (int off = 1; off < 16; off <<= 1) sum += __shfl_xor(sum, off);
                float inv = 1.f / sum;
                int row = rows0 + (mi << 4) + (quad << 2) + r;
                #pragma unroll
                for (int ni = 0; ni < 7; ++ni)
                    UN[row * ALDP + (ni << 4) + l16] = (short)f2bf(sc[mi][ni][r] * inv);
                UN[row * ALDP + 112 + l16] = 0;          // zero K-pad cols
            }
        }
        __syncthreads();

        // ---- O = P V  (K=128)
        f32x4 oa[2][4];
        #pragma unroll
        for (int mi = 0; mi < 2; ++mi)
            #pragma unroll
            for (int ni = 0; ni < 4; ++ni) oa[mi][ni] = z;
        #pragma unroll
        for (int ks = 0; ks < 4; ++ks) {
            bf16x8 ap[2], bv[4];
            #pragma unroll
            for (int mi = 0; mi < 2; ++mi)
                ap[mi] = *(const bf16x8*)&UN[(rows0 + (mi << 4) + l16) * ALDP + (ks << 5) + (quad << 3)];
            #pragma unroll
            for (int ni = 0; ni < 4; ++ni)
                bv[ni] = *(const bf16x8*)&Vt[((ni << 4) + l16) * ALDP + (ks << 5) + (quad << 3)];
            #pragma unroll
            for (int mi = 0; mi < 2; ++mi)
                #pragma unroll
                for (int ni = 0; ni < 4; ++ni)
                    oa[mi][ni] = __builtin_amdgcn_mfma_f32_16x16x32_bf16(ap[mi], bv[ni], oa[mi][ni], 0, 0, 0);
        }
        #pragma unroll
        for (int mi = 0; mi < 2; ++mi) {
            #pragma unroll
            for (int r = 0; r < 4; ++r) {
                int row = rows0 + (mi << 4) + (quad << 2) + r;
                if (row < NS) {
                    u16* orow = O + (rowbase + row) * 512 + (h << 6);
                    #pragma unroll
                    for (int ni = 0; ni < 4; ++ni)
                        orow[(ni << 4) + l16] = f2bf(oa[mi][ni][r]);
                }
            }
        }
        __syncthreads();   // before next head rewrites UN/Ks/Vt
    }
}

// ---------------------------------------------------------------------------
// Generic bf16 GEMM (used for FFN1): 128x128 tile, BK=32.
// ---------------------------------------------------------------------------
template<int OUTMODE, bool RELU>
__global__ __launch_bounds__(256) void gemm_bf16(
    const u16* __restrict__ A, const u16* __restrict__ W,
    const float* __restrict__ bias, void* __restrict__ Cv, int K, int ldc)
{
    __shared__ short As[128 * 32];
    __shared__ short Bs[128 * 32];
    int t = threadIdx.x;
    int lane = t & 63, wave = t >> 6;
    int quad = lane >> 4, l16 = lane & 15;
    int wr = wave >> 1, wc = wave & 1;
    int m0 = blockIdx.y << 7, n0 = blockIdx.x << 7;

    f32x4 acc[4][4];
    f32x4 z = {0.f, 0.f, 0.f, 0.f};
    #pragma unroll
    for (int mi = 0; mi < 4; ++mi)
        #pragma unroll
        for (int ni = 0; ni < 4; ++ni) acc[mi][ni] = z;

    int rowA = t >> 2;
    int cch = (t & 3) << 3;
    const u16* aSrc0 = A + (size_t)(m0 + rowA) * K + cch;
    const u16* aSrc1 = A + (size_t)(m0 + rowA + 64) * K + cch;
    const u16* bSrc0 = W + (size_t)(n0 + rowA) * K + cch;
    const u16* bSrc1 = W + (size_t)(n0 + rowA + 64) * K + cch;
    short* aDst0 = As + t * 8;
    short* aDst1 = As + (t + 256) * 8;
    short* bDst0 = Bs + t * 8;
    short* bDst1 = Bs + (t + 256) * 8;

    int nk = K >> 5;
    for (int kc = 0; kc < nk; ++kc) {
        if (kc) __syncthreads();
        gload16(aSrc0, aDst0);
        gload16(aSrc1, aDst1);
        gload16(bSrc0, bDst0);
        gload16(bSrc1, bDst1);
        aSrc0 += 32; aSrc1 += 32; bSrc0 += 32; bSrc1 += 32;
        __syncthreads();

        bf16x8 af[4], bw[4];
        #pragma unroll
        for (int mi = 0; mi < 4; ++mi)
            af[mi] = *(const bf16x8*)(As + ((size_t)((wr << 6) + (mi << 4) + l16) * 32 + (quad << 3)));
        #pragma unroll
        for (int ni = 0; ni < 4; ++ni)
            bw[ni] = *(const bf16x8*)(Bs + ((size_t)((wc << 6) + (ni << 4) + l16) * 32 + (quad << 3)));
        #pragma unroll
        for (int mi = 0; mi < 4; ++mi)
            #pragma unroll
            for (int ni = 0; ni < 4; ++ni)
                acc[mi][ni] = __builtin_amdgcn_mfma_f32_16x16x32_bf16(af[mi], bw[ni], acc[mi][ni], 0, 0, 0);
    }

    #pragma unroll
    for (int mi = 0; mi < 4; ++mi) {
        #pragma unroll
        for (int r = 0; r < 4; ++r) {
            int row = m0 + (wr << 6) + (mi << 4) + (quad << 2) + r;
            #pragma unroll
            for (int ni = 0; ni < 4; ++ni) {
                int col = n0 + (wc << 6) + (ni << 4) + l16;
                float v = acc[mi][ni][r];
                if (bias) v += bias[col];
                if (RELU) v = fmaxf(v, 0.f);
                if (OUTMODE == 0)
                    ((float*)Cv)[(size_t)row * ldc + col] = v;
                else
                    ((u16*)Cv)[(size_t)row * ldc + col] = f2bf(v);
            }
        }
    }
}

// ---------------------------------------------------------------------------
// Fused GEMM + add-LayerNorm epilogue (proven in R6/R7).
// ---------------------------------------------------------------------------
template<int OUTMODE>
__global__ __launch_bounds__(512, 2) void gemm_ln(
    const u16* __restrict__ A, const u16* __restrict__ W,
    const float* __restrict__ bias, const float* __restrict__ lnw,
    const float* __restrict__ lnb, void* __restrict__ outv, int K)
{
    __shared__ short As[64 * 32];
    __shared__ short Bs[512 * 32];
    __shared__ float red_s[64][9];
    __shared__ float red_q[64][9];
    __shared__ float mrow[64], rrow[64];

    int t = threadIdx.x;
    int lane = t & 63, wave = t >> 6;
    int quad = lane >> 4, l16 = lane & 15;
    int m0 = blockIdx.x << 6;

    f32x4 acc[4][4];
    f32x4 z = {0.f, 0.f, 0.f, 0.f};
    #pragma unroll
    for (int mi = 0; mi < 4; ++mi)
        #pragma unroll
        for (int ni = 0; ni < 4; ++ni) acc[mi][ni] = z;

    int koff = (t & 3) << 3;
    const u16* aSrc = A + (size_t)(m0 + (t >> 2)) * K + koff;
    const u16* bSrc0 = W + (size_t)(t >> 2) * K + koff;
    const u16* bSrc1 = W + (size_t)((t >> 2) + 128) * K + koff;
    const u16* bSrc2 = W + (size_t)((t >> 2) + 256) * K + koff;
    const u16* bSrc3 = W + (size_t)((t >> 2) + 384) * K + koff;
    short* aDst = As + t * 8;
    short* bDst0 = Bs + t * 8;
    short* bDst1 = Bs + (t + 512) * 8;
    short* bDst2 = Bs + (t + 1024) * 8;
    short* bDst3 = Bs + (t + 1536) * 8;

    int nk = K >> 5;
    for (int kc = 0; kc < nk; ++kc) {
        if (kc) __syncthreads();
        if (t < 256) gload16(aSrc, aDst);
        gload16(bSrc0, bDst0);
        gload16(bSrc1, bDst1);
        gload16(bSrc2, bDst2);
        gload16(bSrc3, bDst3);
        aSrc += 32; bSrc0 += 32; bSrc1 += 32; bSrc2 += 32; bSrc3 += 32;
        __syncthreads();

        bf16x8 af[4], bw[4];
        #pragma unroll
        for (int mi = 0; mi < 4; ++mi)
            af[mi] = *(const bf16x8*)(As + ((mi << 4) + l16) * 32 + (quad << 3));
        #pragma unroll
        for (int ni = 0; ni < 4; ++ni)
            bw[ni] = *(const bf16x8*)(Bs + ((wave << 6) + (ni << 4) + l16) * 32 + (quad << 3));
        #pragma unroll
        for (int mi = 0; mi < 4; ++mi)
            #pragma unroll
            for (int ni = 0; ni < 4; ++ni)
                acc[mi][ni] = __builtin_amdgcn_mfma_f32_16x16x32_bf16(af[mi], bw[ni], acc[mi][ni], 0, 0, 0);
    }

    float lwv[4], lbv[4];
    #pragma unroll
    for (int ni = 0; ni < 4; ++ni) {
        int col = (wave << 6) + (ni << 4) + l16;
        float bv = bias[col];
        lwv[ni] = lnw[col];
        lbv[ni] = lnb[col];
        #pragma unroll
        for (int mi = 0; mi < 4; ++mi)
            #pragma unroll
            for (int r = 0; r < 4; ++r) acc[mi][ni][r] += bv;
    }
    #pragma unroll
    for (int mi = 0; mi < 4; ++mi) {
        #pragma unroll
        for (int r = 0; r < 4; ++r) {
            float s = acc[mi][0][r] + acc[mi][1][r] + acc[mi][2][r] + acc[mi][3][r];
            float q = acc[mi][0][r]*acc[mi][0][r] + acc[mi][1][r]*acc[mi][1][r]
                    + acc[mi][2][r]*acc[mi][2][r] + acc[mi][3][r]*acc[mi][3][r];
            #pragma unroll
            for (int off = 1; off < 16; off <<= 1) {
                s += __shfl_xor(s, off);
                q += __shfl_xor(q, off);
            }
            if (l16 == 0) {
                int row = (mi << 4) + (quad << 2) + r;
                red_s[row][wave] = s;
                red_q[row][wave] = q;
            }
        }
    }
    __syncthreads();
    if (t < 64) {
        float s = 0.f, q = 0.f;
        #pragma unroll
        for (int w8 = 0; w8 < 8; ++w8) { s += red_s[t][w8]; q += red_q[t][w8]; }
        float mean = s * (1.f / 512.f);
        float var = q * (1.f / 512.f) - mean * mean;
        mrow[t] = mean;
        rrow[t] = rsqrtf(var + 1e-5f);
    }
    __syncthreads();
    #pragma unroll
    for (int mi = 0; mi < 4; ++mi) {
        #pragma unroll
        for (int r = 0; r < 4; ++r) {
            int lrow = (mi << 4) + (quad << 2) + r;
            float mean = mrow[lrow], rstd = rrow[lrow];
            size_t grow = (size_t)(m0 + lrow) * 512;
            #pragma unroll
            for (int ni = 0; ni < 4; ++ni) {
                int col = (wave << 6) + (ni << 4) + l16;
                float v = acc[mi][ni][r];
                float y = v + (v - mean) * rstd * lwv[ni] + lbv[ni];
                if (OUTMODE == 0) ((float*)outv)[grow + col] = y;
                else ((u16*)outv)[grow + col] = f2bf(y);
            }
        }
    }
}

// ---------------------------------------------------------------------------
__global__ __launch_bounds__(256) void u_stage1_kernel(
    const float* __restrict__ Y2, const float* __restrict__ Wt,
    float* __restrict__ T1)
{
    __shared__ float yl[16][512];
    int t = threadIdx.x;
    int r0 = blockIdx.x << 6;
    int bg = blockIdx.y << 4;
    for (int l = t; l < 2048; l += 256) {
        int bb = l >> 7, seg = (l & 127) << 2;
        *(float4*)&yl[bb][seg] =
            *(const float4*)&Y2[((size_t)(bg + bb) * NS + 99) * ND + seg];
    }
    __syncthreads();
    int r = r0 + (t & 63);
    int b0 = t >> 6;
    const float* wr = Wt + (size_t)r * ND;
    float acc[4] = {0.f, 0.f, 0.f, 0.f};
    for (int d = 0; d < ND; d += 4) {
        float4 w4 = *(const float4*)(wr + d);
        #pragma unroll
        for (int bb = 0; bb < 4; ++bb) {
            int bl = (b0 << 2) + bb;
            acc[bb] += w4.x * yl[bl][d] + w4.y * yl[bl][d+1]
                     + w4.z * yl[bl][d+2] + w4.w * yl[bl][d+3];
        }
    }
    #pragma unroll
    for (int bb = 0; bb < 4; ++bb)
        T1[(size_t)(bg + (b0 << 2) + bb) * ND + r] = acc[bb];
}

__global__ __launch_bounds__(256) void u_stage2_kernel(
    const float* __restrict__ T1, const float* __restrict__ Wt,
    float* __restrict__ U)
{
    __shared__ float t1s[16][512];
    int t = threadIdx.x;
    int c0 = blockIdx.x << 6;
    int bg = blockIdx.y << 4;
    for (int l = t; l < 2048; l += 256) {
        int bb = l >> 7, seg = (l & 127) << 2;
        *(float4*)&t1s[bb][seg] = *(const float4*)&T1[(size_t)(bg + bb) * ND + seg];
    }
    __syncthreads();
    int c = c0 + (t & 63);
    int b0 = t >> 6;
    float acc[4] = {0.f, 0.f, 0.f, 0.f};
    for (int r = 0; r < ND; ++r) {
        float w = Wt[(size_t)r * ND + c];
        #pragma unroll
        for (int bb = 0; bb < 4; ++bb)
            acc[bb] += w * t1s[(b0 << 2) + bb][r];
    }
    #pragma unroll
    for (int bb = 0; bb < 4; ++bb)
        U[(size_t)(bg + (b0 << 2) + bb) * ND + c] = acc[bb];
}

// ---------------------------------------------------------------------------
__global__ __launch_bounds__(256) void pool_kernel(
    const float* __restrict__ Y2, const float* __restrict__ U,
    const float* __restrict__ Wout, const float* __restrict__ bout,
    float* __restrict__ out)
{
    __shared__ float u[ND];
    __shared__ float lam[128];
    __shared__ float red[4];
    int t = threadIdx.x;
    int b = blockIdx.x;
    const float* y2b = Y2 + (size_t)b * NS * ND;
    u[t] = U[(size_t)b * ND + t];
    u[t + 256] = U[(size_t)b * ND + t + 256];
    __syncthreads();
    int wid = t >> 6, lane = t & 63;
    int c0 = lane << 2;
    for (int s = wid; s < NS; s += 4) {
        const float* yr = y2b + (size_t)s * ND;
        float4 p0 = *(const float4*)(yr + c0);
        float4 p1 = *(const float4*)(yr + 256 + c0);
        float a = p0.x*u[c0] + p0.y*u[c0+1] + p0.z*u[c0+2] + p0.w*u[c0+3]
                + p1.x*u[256+c0] + p1.y*u[256+c0+1] + p1.z*u[256+c0+2] + p1.w*u[256+c0+3];
        #pragma unroll
        for (int off = 32; off > 0; off >>= 1) a += __shfl_xor(a, off);
        if (lane == 0) lam[s] = a;
    }
    __syncthreads();
    if (t < 64) {
        float l0 = lam[t];
        float l1 = (t + 64 < NS) ? lam[t + 64] : -3.0e38f;
        float mx = fmaxf(l0, l1);
        #pragma unroll
        for (int off = 32; off > 0; off >>= 1) mx = fmaxf(mx, __shfl_xor(mx, off));
        float e0 = expf(l0 - mx);
        float e1 = (t + 64 < NS) ? expf(l1 - mx) : 0.f;
        float ssum = e0 + e1;
        #pragma unroll
        for (int off = 32; off > 0; off >>= 1) ssum += __shfl_xor(ssum, off);
        float inv = 1.f / ssum;
        lam[t] = e0 * inv;
        if (t + 64 < NS) lam[t + 64] = e1 * inv;
    }
    __syncthreads();
    float p0 = 0.f, p1 = 0.f;
    for (int s = 0; s < NS; ++s) {
        float lm = lam[s];
        const float* yr = y2b + (size_t)s * ND;
        p0 += lm * yr[t];
        p1 += lm * yr[t + 256];
    }
    float vd = p0 * Wout[t] + p1 * Wout[t + 256];
    #pragma unroll
    for (int off = 32; off > 0; off >>= 1) vd += __shfl_xor(vd, off);
    if (lane == 0) red[wid] = vd;
    __syncthreads();
    if (t == 0) out[b] = red[0] + red[1] + red[2] + red[3] + bout[0];
}

// ---------------------------------------------------------------------------
static size_t ws_need(int CBc) {
    size_t cm = (size_t)CBc * NS;
    size_t b = 0;
    b += cm * 512 * 2;         // AO16
    b += cm * 512 * 2;         // Y116
    b += cm * 256 * 2;         // ACT16
    b += cm * 512 * 4;         // Y2
    b += (size_t)CBc * 512 * 4 * 2;  // T1, U
    b += 1536 * 160 * 2;       // Wf (frag layout)
    b += 512 * 512 * 2 + 256 * 512 * 2 + 512 * 256 * 2;
    b += 100 * 1536 * 4 + 256 * 4;
    b += 64 * 1024;
    return b;
}

extern "C" void kernel_launch(void* const* d_in, const int* in_sizes, int n_in,
                              void* d_out, int out_size, void* d_ws, size_t ws_size,
                              hipStream_t stream)
{
    const float* src   = (const float*)d_in[0];
    const float* Wfeat = (const float*)d_in[1];
    const float* bfeat = (const float*)d_in[2];
    const float* pe    = (const float*)d_in[3];
    const float* Wq    = (const float*)d_in[4];
    const float* bq    = (const float*)d_in[5];
    const float* Wk    = (const float*)d_in[6];
    const float* bk    = (const float*)d_in[7];
    const float* Wv    = (const float*)d_in[8];
    const float* bv    = (const float*)d_in[9];
    const float* Wo    = (const float*)d_in[10];
    const float* bo    = (const float*)d_in[11];
    const float* lnw   = (const float*)d_in[12];
    const float* lnb   = (const float*)d_in[13];
    const float* W1    = (const float*)d_in[14];
    const float* b1    = (const float*)d_in[15];
    const float* W2    = (const float*)d_in[16];
    const float* b2    = (const float*)d_in[17];
    const float* Wt    = (const float*)d_in[18];
    const float* Wout  = (const float*)d_in[19];
    const float* bout  = (const float*)d_in[20];
    float* out = (float*)d_out;

    // chunk size: largest tier that fits d_ws (deterministic across calls)
    int CBc = (ws_size >= ws_need(1024)) ? 1024
            : (ws_size >= ws_need(512))  ? 512
            : (ws_size >= ws_need(256))  ? 256 : 128;
    int NCH = NB / CBc;
    size_t CMc = (size_t)CBc * NS;

    char* p = (char*)d_ws;
    auto alloc = [&](size_t bytes) { char* r = p; p += (bytes + 255) & ~(size_t)255; return r; };
    u16*   AO16  = (u16*)  alloc(CMc * 512 * 2);
    u16*   Y116  = (u16*)  alloc(CMc * 512 * 2);
    u16*   ACT16 = (u16*)  alloc(CMc * 256 * 2);
    float* Y2    = (float*)alloc(CMc * 512 * 4);
    float* T1    = (float*)alloc((size_t)CBc * 512 * 4);
    float* U     = (float*)alloc((size_t)CBc * 512 * 4);
    u16*   Wf    = (u16*)  alloc(1536 * 160 * 2);
    u16*   Wo16  = (u16*)  alloc(512 * 512 * 2);
    u16*   W116  = (u16*)  alloc(256 * 512 * 2);
    u16*   W216  = (u16*)  alloc(512 * 256 * 2);
    float* Cqkv  = (float*)alloc(100 * 1536 * 4);
    float* b1p   = (float*)alloc(256 * 4);

    prep_w_kernel<<<1536, 256, 0, stream>>>(Wq, Wk, Wv, Wfeat, Wf);
    prep_c_kernel<<<300, 256, 0, stream>>>(Wq, Wk, Wv, bq, bk, bv, bfeat, pe, Cqkv);
    pad_cast_kernel<<<(512 * 512) / 256, 256, 0, stream>>>(Wo, Wo16, 512, 512, 512, 512 * 512);
    pad_cast_kernel<<<(256 * 512) / 256, 256, 0, stream>>>(W1, W116, NF, 512, 512, 256 * 512);
    pad_cast_kernel<<<(512 * 256) / 256, 256, 0, stream>>>(W2, W216, 512, NF, 256, 512 * 256);
    pad_b1_kernel<<<1, 256, 0, stream>>>(b1, b1p);

    dim3 g256(2, CMc / 128);
    dim3 gU(8, CBc / 16);
    int gLN = CMc / 64;

    for (int c = 0; c < NCH; ++c) {
        const float* srcC = src + (size_t)c * CMc * NF;
        float* outC = out + (size_t)c * CBc;

        // fused QKV + attention -> AO16 (bf16)
        qkv_attn_kernel<<<CBc, 256, 0, stream>>>(srcC, Wf, Cqkv, AO16);
        // y1 = (AO16@Wo^T + bo) + LN(...) -> bf16 (fused)
        gemm_ln<1><<<gLN, 512, 0, stream>>>(AO16, Wo16, bo, lnw, lnb, Y116, 512);
        // act = relu(y1 @ W116^T + b1p) -> bf16 [CMc,256]
        gemm_bf16<1, true><<<g256, 256, 0, stream>>>(Y116, W116, b1p, ACT16, 512, 256);
        // y2 = (act@W2^T + b2) + LN(...) -> f32 (fused)
        gemm_ln<0><<<gLN, 512, 0, stream>>>(ACT16, W216, b2, lnw, lnb, Y2, 256);
        // pooling head
        u_stage1_kernel<<<gU, 256, 0, stream>>>(Y2, Wt, T1);
        u_stage2_kernel<<<gU, 256, 0, stream>>>(T1, Wt, U);
        pool_kernel<<<CBc, 256, 0, stream>>>(Y2, U, Wout, bout, outC);
    }

    (void)in_sizes; (void)n_in; (void)out_size; (void)ws_size;
}

// Round 9
// 1551.869 us; speedup vs baseline: 4.8856x; 1.1811x over previous
//
#include <hip/hip_runtime.h>
#include <math.h>

#define NB 2048
#define NS 100
#define NF 158
#define ND 512
#define NH 8

typedef unsigned short u16;
typedef __attribute__((ext_vector_type(8))) short bf16x8;
typedef __attribute__((ext_vector_type(8))) unsigned short u16x8;
typedef __attribute__((ext_vector_type(4))) float f32x4;

__device__ __forceinline__ u16 f2bf(float f) {
    union { float f; unsigned u; } v; v.f = f;
    unsigned u = v.u;
    return (u16)((u + 0x7fffu + ((u >> 16) & 1u)) >> 16);   // RNE
}

__device__ __forceinline__ void gload16(const void* g, void* l) {
    __builtin_amdgcn_global_load_lds(
        (const __attribute__((address_space(1))) unsigned*)g,
        (__attribute__((address_space(3))) unsigned*)l, 16, 0, 0);
}

// 8 f32 -> bf16x8 with tail guard at NF (src rows 8B aligned -> float2)
__device__ __forceinline__ bf16x8 load8_cvt(const float* __restrict__ base, int c0) {
    bf16x8 r;
    if (c0 + 8 <= NF) {
        #pragma unroll
        for (int j = 0; j < 8; j += 2) {
            float2 v = *(const float2*)(base + c0 + j);
            r[j] = (short)f2bf(v.x); r[j + 1] = (short)f2bf(v.y);
        }
    } else {
        #pragma unroll
        for (int j = 0; j < 8; ++j)
            r[j] = (c0 + j < NF) ? (short)f2bf(base[c0 + j]) : (short)0;
    }
    return r;
}

// ---------------------------------------------------------------------------
// prep_w: folded QKV weights -> MFMA-B-fragment layout (unchanged from R8)
// ---------------------------------------------------------------------------
__global__ __launch_bounds__(256) void prep_w_kernel(
    const float* __restrict__ Wq, const float* __restrict__ Wk,
    const float* __restrict__ Wv, const float* __restrict__ Wfeat,
    u16* __restrict__ Wf)
{
    int bid = blockIdx.x;           // 0..1535
    int sel = bid >> 9;
    int n = bid & 511;
    const float* Wsrc = (sel == 0) ? Wq : (sel == 1) ? Wk : Wv;
    __shared__ float wrow[ND];
    int t = threadIdx.x;
    wrow[t] = Wsrc[(size_t)n * ND + t];
    wrow[t + 256] = Wsrc[(size_t)n * ND + t + 256];
    __syncthreads();
    if (t < 160) {
        float acc = 0.f;
        if (t < NF)
            for (int d = 0; d < ND; ++d)
                acc += wrow[d] * Wfeat[(size_t)d * NF + t];
        int h = n >> 6, ni = (n >> 4) & 3, l16 = n & 15;
        int ks = t >> 5, quad = (t >> 3) & 3, j = t & 7;
        size_t idx = (((((size_t)sel * 8 + h) * 4 + ni) * 5 + ks) * 64
                      + (quad << 4) + l16) * 8 + j;
        Wf[idx] = f2bf(acc);
    }
}

// ---------------------------------------------------------------------------
// prep_c: T4[((sel*8+h)*100+s)*64 + l16*4 + ni] = (b_feat+pe[s])@W[n,:]+b[n]
//   n = h*64+ni*16+l16  (per-lane float4 layout for the fused kernel)
// ---------------------------------------------------------------------------
__global__ __launch_bounds__(256) void prep_c_kernel(
    const float* __restrict__ Wq, const float* __restrict__ Wk, const float* __restrict__ Wv,
    const float* __restrict__ bq, const float* __restrict__ bk, const float* __restrict__ bv,
    const float* __restrict__ bfeat, const float* __restrict__ pe,
    float* __restrict__ T4)
{
    int bid = blockIdx.x;           // 0..299
    int sel = bid / 100;
    int s = bid - sel * 100;
    const float* Wsrc = (sel == 0) ? Wq : (sel == 1) ? Wk : Wv;
    const float* bsrc = (sel == 0) ? bq : (sel == 1) ? bk : bv;
    __shared__ float xv[ND];
    int t = threadIdx.x;
    xv[t] = bfeat[t] + pe[(size_t)s * ND + t];
    xv[t + 256] = bfeat[t + 256] + pe[(size_t)s * ND + t + 256];
    __syncthreads();
    #pragma unroll
    for (int rr = 0; rr < 2; ++rr) {
        int r = t + (rr << 8);
        const float* wr = Wsrc + (size_t)r * ND;
        float acc = bsrc[r];
        for (int d = 0; d < ND; d += 4) {
            float4 w4 = *(const float4*)(wr + d);
            acc += w4.x * xv[d] + w4.y * xv[d+1] + w4.z * xv[d+2] + w4.w * xv[d+3];
        }
        int h = r >> 6, ni = (r >> 4) & 3, l16 = r & 15;
        T4[(((size_t)(sel * 8 + h)) * 100 + s) * 64 + (l16 << 2) + ni] = acc;
    }
}

// ---------------------------------------------------------------------------
__global__ __launch_bounds__(256) void pad_cast_kernel(
    const float* __restrict__ src, u16* __restrict__ dst,
    int R, int C, int Cp, int total)
{
    int idx = blockIdx.x * 256 + threadIdx.x;
    if (idx >= total) return;
    int r = idx / Cp, c = idx - r * Cp;
    float v = (r < R && c < C) ? src[(size_t)r * C + c] : 0.f;
    dst[idx] = f2bf(v);
}

__global__ __launch_bounds__(256) void pad_b1_kernel(
    const float* __restrict__ b1, float* __restrict__ b1p)
{
    int t = threadIdx.x;
    b1p[t] = (t < NF) ? b1[t] : 0.f;
}

// ---------------------------------------------------------------------------
// FUSED QKV + attention, 512 threads (8 waves x 16 rows) for 2x latency hiding.
// Same LDS layout / rounding chain as R8 (2 blocks/CU, 16 waves/CU).
// ---------------------------------------------------------------------------
#define ALDQ 72     // Ks row stride (shorts)
#define ALDP 136    // UN (Q/P) and Vt row stride (shorts)

__global__ __launch_bounds__(512, 4) void qkv_attn_kernel(
    const float* __restrict__ src, const u16* __restrict__ Wf,
    const float* __restrict__ T4, u16* __restrict__ O)
{
    __shared__ short UN[128 * ALDP];   // Q (cols 0..63), later P (cols 0..127)
    __shared__ short Ks[112 * ALDQ];
    __shared__ short Vt[64 * ALDP];

    int t = threadIdx.x;
    int lane = t & 63, wave = t >> 6;       // wave 0..7
    int quad = lane >> 4, l16 = lane & 15;
    int rows0 = wave << 4;                  // this wave's 16 rows
    int b = blockIdx.x;
    const float* xb = src + (size_t)b * NS * NF;
    const size_t rowbase = (size_t)b * NS;
    f32x4 z = {0.f, 0.f, 0.f, 0.f};

    // static zero pads (persist across heads)
    for (int l = t; l < 12 * ALDQ; l += 512)
        Ks[(100 + l / ALDQ) * ALDQ + (l % ALDQ)] = 0;
    for (int l = t; l < 64 * 28; l += 512) {
        int d = l / 28, s = 100 + (l - d * 28);
        Vt[d * ALDP + s] = 0;
    }

    // X A-fragments for this wave's 16 rows (rows >= 100 -> zero), in VGPRs
    int arow = rows0 + l16;
    bf16x8 AF[5];
    {
        const float* xr = xb + (size_t)arow * NF;
        #pragma unroll
        for (int ks = 0; ks < 5; ++ks) {
            if (arow < NS) AF[ks] = load8_cvt(xr, (ks << 5) + (quad << 3));
            else { bf16x8 zz = {0,0,0,0,0,0,0,0}; AF[ks] = zz; }
        }
    }

    for (int h = 0; h < NH; ++h) {
        // ---- q/k/v for head h (this wave: 16 rows x 64 head-dims)
        #pragma unroll
        for (int sel = 0; sel < 3; ++sel) {
            f32x4 acc[4];
            #pragma unroll
            for (int ni = 0; ni < 4; ++ni) acc[ni] = z;
            #pragma unroll
            for (int ks = 0; ks < 5; ++ks) {
                bf16x8 wfr[4];
                #pragma unroll
                for (int ni = 0; ni < 4; ++ni)
                    wfr[ni] = *(const bf16x8*)(Wf +
                        (((((size_t)sel * 8 + h) * 4 + ni) * 5 + ks) * 64 + lane) * 8);
                #pragma unroll
                for (int ni = 0; ni < 4; ++ni)
                    acc[ni] = __builtin_amdgcn_mfma_f32_16x16x32_bf16(
                        AF[ks], wfr[ni], acc[ni], 0, 0, 0);
            }
            // epilogue: +T4 (float4 per row), bf16 -> LDS
            #pragma unroll
            for (int r = 0; r < 4; ++r) {
                int row_s = rows0 + (quad << 2) + r;
                bool real = row_s < NS;
                float4 tv = make_float4(0.f, 0.f, 0.f, 0.f);
                if (real)
                    tv = *(const float4*)(T4 +
                        (((size_t)(sel * 8 + h)) * 100 + row_s) * 64 + (l16 << 2));
                float tvs[4] = {tv.x, tv.y, tv.z, tv.w};
                #pragma unroll
                for (int ni = 0; ni < 4; ++ni) {
                    int nloc = (ni << 4) + l16;
                    float v = acc[ni][r] + tvs[ni];
                    u16 bv = f2bf(v);
                    if (sel == 0) UN[row_s * ALDP + nloc] = (short)bv;           // Q (pad rows = 0)
                    else if (sel == 1) { if (real) Ks[row_s * ALDQ + nloc] = (short)bv; }
                    else               { if (real) Vt[nloc * ALDP + row_s] = (short)bv; }
                }
            }
        }
        __syncthreads();

        // ---- S = Q K^T  (1 row-tile x 7 col-tiles per wave, K=64)
        f32x4 sc[7];
        #pragma unroll
        for (int ni = 0; ni < 7; ++ni) sc[ni] = z;
        #pragma unroll
        for (int ks = 0; ks < 2; ++ks) {
            bf16x8 aq = *(const bf16x8*)&UN[(rows0 + l16) * ALDP + (ks << 5) + (quad << 3)];
            bf16x8 bk[7];
            #pragma unroll
            for (int ni = 0; ni < 7; ++ni)
                bk[ni] = *(const bf16x8*)&Ks[((ni << 4) + l16) * ALDQ + (ks << 5) + (quad << 3)];
            #pragma unroll
            for (int ni = 0; ni < 7; ++ni)
                sc[ni] = __builtin_amdgcn_mfma_f32_16x16x32_bf16(aq, bk[ni], sc[ni], 0, 0, 0);
        }
        __syncthreads();   // all waves done reading Q before P overwrites UN

        // ---- softmax in registers; P (bf16) into UN stride 136
        #pragma unroll
        for (int r = 0; r < 4; ++r) {
            if (l16 >= 4) sc[6][r] = -3.0e38f;   // cols 100..111 masked
            float mx = sc[0][r];
            #pragma unroll
            for (int ni = 1; ni < 7; ++ni) mx = fmaxf(mx, sc[ni][r]);
            #pragma unroll
            for (int off = 1; off < 16; off <<= 1) mx = fmaxf(mx, __shfl_xor(mx, off));
            float sum = 0.f;
            #pragma unroll
            for (int ni = 0; ni < 7; ++ni) {
                float e = expf((sc[ni][r] - mx) * 0.125f);
                sc[ni][r] = e; sum += e;
            }
            #pragma unroll
            for (int off = 1; off < 16; off <<= 1) sum += __shfl_xor(sum, off);
            float inv = 1.f / sum;
            int row = rows0 + (quad << 2) + r;
            #pragma unroll
            for (int ni = 0; ni < 7; ++ni)
                UN[row * ALDP + (ni << 4) + l16] = (short)f2bf(sc[ni][r] * inv);
            UN[row * ALDP + 112 + l16] = 0;      // zero K-pad cols
        }
        __syncthreads();

        // ---- O = P V  (K=128)
        f32x4 oa[4];
        #pragma unroll
        for (int ni = 0; ni < 4; ++ni) oa[ni] = z;
        #pragma unroll
        for (int ks = 0; ks < 4; ++ks) {
            bf16x8 ap = *(const bf16x8*)&UN[(rows0 + l16) * ALDP + (ks << 5) + (quad << 3)];
            bf16x8 bv[4];
            #pragma unroll
            for (int ni = 0; ni < 4; ++ni)
                bv[ni] = *(const bf16x8*)&Vt[((ni << 4) + l16) * ALDP + (ks << 5) + (quad << 3)];
            #pragma unroll
            for (int ni = 0; ni < 4; ++ni)
                oa[ni] = __builtin_amdgcn_mfma_f32_16x16x32_bf16(ap, bv[ni], oa[ni], 0, 0, 0);
        }
        #pragma unroll
        for (int r = 0; r < 4; ++r) {
            int row = rows0 + (quad << 2) + r;
            if (row < NS) {
                u16* orow = O + (rowbase + row) * 512 + (h << 6);
                #pragma unroll
                for (int ni = 0; ni < 4; ++ni)
                    orow[(ni << 4) + l16] = f2bf(oa[ni][r]);
            }
        }
        __syncthreads();   // before next head rewrites UN/Ks/Vt
    }
}

// ---------------------------------------------------------------------------
// Generic bf16 GEMM (used for FFN1): 128x128 tile, BK=32.
// ---------------------------------------------------------------------------
template<int OUTMODE, bool RELU>
__global__ __launch_bounds__(256) void gemm_bf16(
    const u16* __restrict__ A, const u16* __restrict__ W,
    const float* __restrict__ bias, void* __restrict__ Cv, int K, int ldc)
{
    __shared__ short As[128 * 32];
    __shared__ short Bs[128 * 32];
    int t = threadIdx.x;
    int lane = t & 63, wave = t >> 6;
    int quad = lane >> 4, l16 = lane & 15;
    int wr = wave >> 1, wc = wave & 1;
    int m0 = blockIdx.y << 7, n0 = blockIdx.x << 7;

    f32x4 acc[4][4];
    f32x4 z = {0.f, 0.f, 0.f, 0.f};
    #pragma unroll
    for (int mi = 0; mi < 4; ++mi)
        #pragma unroll
        for (int ni = 0; ni < 4; ++ni) acc[mi][ni] = z;

    int rowA = t >> 2;
    int cch = (t & 3) << 3;
    const u16* aSrc0 = A + (size_t)(m0 + rowA) * K + cch;
    const u16* aSrc1 = A + (size_t)(m0 + rowA + 64) * K + cch;
    const u16* bSrc0 = W + (size_t)(n0 + rowA) * K + cch;
    const u16* bSrc1 = W + (size_t)(n0 + rowA + 64) * K + cch;
    short* aDst0 = As + t * 8;
    short* aDst1 = As + (t + 256) * 8;
    short* bDst0 = Bs + t * 8;
    short* bDst1 = Bs + (t + 256) * 8;

    int nk = K >> 5;
    for (int kc = 0; kc < nk; ++kc) {
        if (kc) __syncthreads();
        gload16(aSrc0, aDst0);
        gload16(aSrc1, aDst1);
        gload16(bSrc0, bDst0);
        gload16(bSrc1, bDst1);
        aSrc0 += 32; aSrc1 += 32; bSrc0 += 32; bSrc1 += 32;
        __syncthreads();

        bf16x8 af[4], bw[4];
        #pragma unroll
        for (int mi = 0; mi < 4; ++mi)
            af[mi] = *(const bf16x8*)(As + ((size_t)((wr << 6) + (mi << 4) + l16) * 32 + (quad << 3)));
        #pragma unroll
        for (int ni = 0; ni < 4; ++ni)
            bw[ni] = *(const bf16x8*)(Bs + ((size_t)((wc << 6) + (ni << 4) + l16) * 32 + (quad << 3)));
        #pragma unroll
        for (int mi = 0; mi < 4; ++mi)
            #pragma unroll
            for (int ni = 0; ni < 4; ++ni)
                acc[mi][ni] = __builtin_amdgcn_mfma_f32_16x16x32_bf16(af[mi], bw[ni], acc[mi][ni], 0, 0, 0);
    }

    #pragma unroll
    for (int mi = 0; mi < 4; ++mi) {
        #pragma unroll
        for (int r = 0; r < 4; ++r) {
            int row = m0 + (wr << 6) + (mi << 4) + (quad << 2) + r;
            #pragma unroll
            for (int ni = 0; ni < 4; ++ni) {
                int col = n0 + (wc << 6) + (ni << 4) + l16;
                float v = acc[mi][ni][r];
                if (bias) v += bias[col];
                if (RELU) v = fmaxf(v, 0.f);
                if (OUTMODE == 0)
                    ((float*)Cv)[(size_t)row * ldc + col] = v;
                else
                    ((u16*)Cv)[(size_t)row * ldc + col] = f2bf(v);
            }
        }
    }
}

// ---------------------------------------------------------------------------
// Fused GEMM + add-LayerNorm epilogue (proven in R6/R7/R8).
// ---------------------------------------------------------------------------
template<int OUTMODE>
__global__ __launch_bounds__(512, 2) void gemm_ln(
    const u16* __restrict__ A, const u16* __restrict__ W,
    const float* __restrict__ bias, const float* __restrict__ lnw,
    const float* __restrict__ lnb, void* __restrict__ outv, int K)
{
    __shared__ short As[64 * 32];
    __shared__ short Bs[512 * 32];
    __shared__ float red_s[64][9];
    __shared__ float red_q[64][9];
    __shared__ float mrow[64], rrow[64];

    int t = threadIdx.x;
    int lane = t & 63, wave = t >> 6;
    int quad = lane >> 4, l16 = lane & 15;
    int m0 = blockIdx.x << 6;

    f32x4 acc[4][4];
    f32x4 z = {0.f, 0.f, 0.f, 0.f};
    #pragma unroll
    for (int mi = 0; mi < 4; ++mi)
        #pragma unroll
        for (int ni = 0; ni < 4; ++ni) acc[mi][ni] = z;

    int koff = (t & 3) << 3;
    const u16* aSrc = A + (size_t)(m0 + (t >> 2)) * K + koff;
    const u16* bSrc0 = W + (size_t)(t >> 2) * K + koff;
    const u16* bSrc1 = W + (size_t)((t >> 2) + 128) * K + koff;
    const u16* bSrc2 = W + (size_t)((t >> 2) + 256) * K + koff;
    const u16* bSrc3 = W + (size_t)((t >> 2) + 384) * K + koff;
    short* aDst = As + t * 8;
    short* bDst0 = Bs + t * 8;
    short* bDst1 = Bs + (t + 512) * 8;
    short* bDst2 = Bs + (t + 1024) * 8;
    short* bDst3 = Bs + (t + 1536) * 8;

    int nk = K >> 5;
    for (int kc = 0; kc < nk; ++kc) {
        if (kc) __syncthreads();
        if (t < 256) gload16(aSrc, aDst);
        gload16(bSrc0, bDst0);
        gload16(bSrc1, bDst1);
        gload16(bSrc2, bDst2);
        gload16(bSrc3, bDst3);
        aSrc += 32; bSrc0 += 32; bSrc1 += 32; bSrc2 += 32; bSrc3 += 32;
        __syncthreads();

        bf16x8 af[4], bw[4];
        #pragma unroll
        for (int mi = 0; mi < 4; ++mi)
            af[mi] = *(const bf16x8*)(As + ((mi << 4) + l16) * 32 + (quad << 3));
        #pragma unroll
        for (int ni = 0; ni < 4; ++ni)
            bw[ni] = *(const bf16x8*)(Bs + ((wave << 6) + (ni << 4) + l16) * 32 + (quad << 3));
        #pragma unroll
        for (int mi = 0; mi < 4; ++mi)
            #pragma unroll
            for (int ni = 0; ni < 4; ++ni)
                acc[mi][ni] = __builtin_amdgcn_mfma_f32_16x16x32_bf16(af[mi], bw[ni], acc[mi][ni], 0, 0, 0);
    }

    float lwv[4], lbv[4];
    #pragma unroll
    for (int ni = 0; ni < 4; ++ni) {
        int col = (wave << 6) + (ni << 4) + l16;
        float bv = bias[col];
        lwv[ni] = lnw[col];
        lbv[ni] = lnb[col];
        #pragma unroll
        for (int mi = 0; mi < 4; ++mi)
            #pragma unroll
            for (int r = 0; r < 4; ++r) acc[mi][ni][r] += bv;
    }
    #pragma unroll
    for (int mi = 0; mi < 4; ++mi) {
        #pragma unroll
        for (int r = 0; r < 4; ++r) {
            float s = acc[mi][0][r] + acc[mi][1][r] + acc[mi][2][r] + acc[mi][3][r];
            float q = acc[mi][0][r]*acc[mi][0][r] + acc[mi][1][r]*acc[mi][1][r]
                    + acc[mi][2][r]*acc[mi][2][r] + acc[mi][3][r]*acc[mi][3][r];
            #pragma unroll
            for (int off = 1; off < 16; off <<= 1) {
                s += __shfl_xor(s, off);
                q += __shfl_xor(q, off);
            }
            if (l16 == 0) {
                int row = (mi << 4) + (quad << 2) + r;
                red_s[row][wave] = s;
                red_q[row][wave] = q;
            }
        }
    }
    __syncthreads();
    if (t < 64) {
        float s = 0.f, q = 0.f;
        #pragma unroll
        for (int w8 = 0; w8 < 8; ++w8) { s += red_s[t][w8]; q += red_q[t][w8]; }
        float mean = s * (1.f / 512.f);
        float var = q * (1.f / 512.f) - mean * mean;
        mrow[t] = mean;
        rrow[t] = rsqrtf(var + 1e-5f);
    }
    __syncthreads();
    #pragma unroll
    for (int mi = 0; mi < 4; ++mi) {
        #pragma unroll
        for (int r = 0; r < 4; ++r) {
            int lrow = (mi << 4) + (quad << 2) + r;
            float mean = mrow[lrow], rstd = rrow[lrow];
            size_t grow = (size_t)(m0 + lrow) * 512;
            #pragma unroll
            for (int ni = 0; ni < 4; ++ni) {
                int col = (wave << 6) + (ni << 4) + l16;
                float v = acc[mi][ni][r];
                float y = v + (v - mean) * rstd * lwv[ni] + lbv[ni];
                if (OUTMODE == 0) ((float*)outv)[grow + col] = y;
                else ((u16*)outv)[grow + col] = f2bf(y);
            }
        }
    }
}

// ---------------------------------------------------------------------------
__global__ __launch_bounds__(256) void u_stage1_kernel(
    const float* __restrict__ Y2, const float* __restrict__ Wt,
    float* __restrict__ T1)
{
    __shared__ float yl[16][512];
    int t = threadIdx.x;
    int r0 = blockIdx.x << 6;
    int bg = blockIdx.y << 4;
    for (int l = t; l < 2048; l += 256) {
        int bb = l >> 7, seg = (l & 127) << 2;
        *(float4*)&yl[bb][seg] =
            *(const float4*)&Y2[((size_t)(bg + bb) * NS + 99) * ND + seg];
    }
    __syncthreads();
    int r = r0 + (t & 63);
    int b0 = t >> 6;
    const float* wr = Wt + (size_t)r * ND;
    float acc[4] = {0.f, 0.f, 0.f, 0.f};
    for (int d = 0; d < ND; d += 4) {
        float4 w4 = *(const float4*)(wr + d);
        #pragma unroll
        for (int bb = 0; bb < 4; ++bb) {
            int bl = (b0 << 2) + bb;
            acc[bb] += w4.x * yl[bl][d] + w4.y * yl[bl][d+1]
                     + w4.z * yl[bl][d+2] + w4.w * yl[bl][d+3];
        }
    }
    #pragma unroll
    for (int bb = 0; bb < 4; ++bb)
        T1[(size_t)(bg + (b0 << 2) + bb) * ND + r] = acc[bb];
}

__global__ __launch_bounds__(256) void u_stage2_kernel(
    const float* __restrict__ T1, const float* __restrict__ Wt,
    float* __restrict__ U)
{
    __shared__ float t1s[16][512];
    int t = threadIdx.x;
    int c0 = blockIdx.x << 6;
    int bg = blockIdx.y << 4;
    for (int l = t; l < 2048; l += 256) {
        int bb = l >> 7, seg = (l & 127) << 2;
        *(float4*)&t1s[bb][seg] = *(const float4*)&T1[(size_t)(bg + bb) * ND + seg];
    }
    __syncthreads();
    int c = c0 + (t & 63);
    int b0 = t >> 6;
    float acc[4] = {0.f, 0.f, 0.f, 0.f};
    for (int r = 0; r < ND; ++r) {
        float w = Wt[(size_t)r * ND + c];
        #pragma unroll
        for (int bb = 0; bb < 4; ++bb)
            acc[bb] += w * t1s[(b0 << 2) + bb][r];
    }
    #pragma unroll
    for (int bb = 0; bb < 4; ++bb)
        U[(size_t)(bg + (b0 << 2) + bb) * ND + c] = acc[bb];
}

// ---------------------------------------------------------------------------
__global__ __launch_bounds__(256) void pool_kernel(
    const float* __restrict__ Y2, const float* __restrict__ U,
    const float* __restrict__ Wout, const float* __restrict__ bout,
    float* __restrict__ out)
{
    __shared__ float u[ND];
    __shared__ float lam[128];
    __shared__ float red[4];
    int t = threadIdx.x;
    int b = blockIdx.x;
    const float* y2b = Y2 + (size_t)b * NS * ND;
    u[t] = U[(size_t)b * ND + t];
    u[t + 256] = U[(size_t)b * ND + t + 256];
    __syncthreads();
    int wid = t >> 6, lane = t & 63;
    int c0 = lane << 2;
    for (int s = wid; s < NS; s += 4) {
        const float* yr = y2b + (size_t)s * ND;
        float4 p0 = *(const float4*)(yr + c0);
        float4 p1 = *(const float4*)(yr + 256 + c0);
        float a = p0.x*u[c0] + p0.y*u[c0+1] + p0.z*u[c0+2] + p0.w*u[c0+3]
                + p1.x*u[256+c0] + p1.y*u[256+c0+1] + p1.z*u[256+c0+2] + p1.w*u[256+c0+3];
        #pragma unroll
        for (int off = 32; off > 0; off >>= 1) a += __shfl_xor(a, off);
        if (lane == 0) lam[s] = a;
    }
    __syncthreads();
    if (t < 64) {
        float l0 = lam[t];
        float l1 = (t + 64 < NS) ? lam[t + 64] : -3.0e38f;
        float mx = fmaxf(l0, l1);
        #pragma unroll
        for (int off = 32; off > 0; off >>= 1) mx = fmaxf(mx, __shfl_xor(mx, off));
        float e0 = expf(l0 - mx);
        float e1 = (t + 64 < NS) ? expf(l1 - mx) : 0.f;
        float ssum = e0 + e1;
        #pragma unroll
        for (int off = 32; off > 0; off >>= 1) ssum += __shfl_xor(ssum, off);
        float inv = 1.f / ssum;
        lam[t] = e0 * inv;
        if (t + 64 < NS) lam[t + 64] = e1 * inv;
    }
    __syncthreads();
    float p0 = 0.f, p1 = 0.f;
    for (int s = 0; s < NS; ++s) {
        float lm = lam[s];
        const float* yr = y2b + (size_t)s * ND;
        p0 += lm * yr[t];
        p1 += lm * yr[t + 256];
    }
    float vd = p0 * Wout[t] + p1 * Wout[t + 256];
    #pragma unroll
    for (int off = 32; off > 0; off >>= 1) vd += __shfl_xor(vd, off);
    if (lane == 0) red[wid] = vd;
    __syncthreads();
    if (t == 0) out[b] = red[0] + red[1] + red[2] + red[3] + bout[0];
}

// ---------------------------------------------------------------------------
static size_t ws_need(int CBc) {
    size_t cm = (size_t)CBc * NS;
    size_t b = 0;
    b += cm * 512 * 2;         // AO16
    b += cm * 512 * 2;         // Y116
    b += cm * 256 * 2;         // ACT16
    b += cm * 512 * 4;         // Y2
    b += (size_t)CBc * 512 * 4 * 2;  // T1, U
    b += 1536 * 160 * 2;       // Wf
    b += 512 * 512 * 2 + 256 * 512 * 2 + 512 * 256 * 2;
    b += 3 * 8 * 100 * 64 * 4; // T4
    b += 256 * 4;
    b += 64 * 1024;
    return b;
}

extern "C" void kernel_launch(void* const* d_in, const int* in_sizes, int n_in,
                              void* d_out, int out_size, void* d_ws, size_t ws_size,
                              hipStream_t stream)
{
    const float* src   = (const float*)d_in[0];
    const float* Wfeat = (const float*)d_in[1];
    const float* bfeat = (const float*)d_in[2];
    const float* pe    = (const float*)d_in[3];
    const float* Wq    = (const float*)d_in[4];
    const float* bq    = (const float*)d_in[5];
    const float* Wk    = (const float*)d_in[6];
    const float* bk    = (const float*)d_in[7];
    const float* Wv    = (const float*)d_in[8];
    const float* bv    = (const float*)d_in[9];
    const float* Wo    = (const float*)d_in[10];
    const float* bo    = (const float*)d_in[11];
    const float* lnw   = (const float*)d_in[12];
    const float* lnb   = (const float*)d_in[13];
    const float* W1    = (const float*)d_in[14];
    const float* b1    = (const float*)d_in[15];
    const float* W2    = (const float*)d_in[16];
    const float* b2    = (const float*)d_in[17];
    const float* Wt    = (const float*)d_in[18];
    const float* Wout  = (const float*)d_in[19];
    const float* bout  = (const float*)d_in[20];
    float* out = (float*)d_out;

    int CBc = (ws_size >= ws_need(1024)) ? 1024
            : (ws_size >= ws_need(512))  ? 512
            : (ws_size >= ws_need(256))  ? 256 : 128;
    int NCH = NB / CBc;
    size_t CMc = (size_t)CBc * NS;

    char* p = (char*)d_ws;
    auto alloc = [&](size_t bytes) { char* r = p; p += (bytes + 255) & ~(size_t)255; return r; };
    u16*   AO16  = (u16*)  alloc(CMc * 512 * 2);
    u16*   Y116  = (u16*)  alloc(CMc * 512 * 2);
    u16*   ACT16 = (u16*)  alloc(CMc * 256 * 2);
    float* Y2    = (float*)alloc(CMc * 512 * 4);
    float* T1    = (float*)alloc((size_t)CBc * 512 * 4);
    float* U     = (float*)alloc((size_t)CBc * 512 * 4);
    u16*   Wf    = (u16*)  alloc(1536 * 160 * 2);
    u16*   Wo16  = (u16*)  alloc(512 * 512 * 2);
    u16*   W116  = (u16*)  alloc(256 * 512 * 2);
    u16*   W216  = (u16*)  alloc(512 * 256 * 2);
    float* T4    = (float*)alloc(3 * 8 * 100 * 64 * 4);
    float* b1p   = (float*)alloc(256 * 4);

    prep_w_kernel<<<1536, 256, 0, stream>>>(Wq, Wk, Wv, Wfeat, Wf);
    prep_c_kernel<<<300, 256, 0, stream>>>(Wq, Wk, Wv, bq, bk, bv, bfeat, pe, T4);
    pad_cast_kernel<<<(512 * 512) / 256, 256, 0, stream>>>(Wo, Wo16, 512, 512, 512, 512 * 512);
    pad_cast_kernel<<<(256 * 512) / 256, 256, 0, stream>>>(W1, W116, NF, 512, 512, 256 * 512);
    pad_cast_kernel<<<(512 * 256) / 256, 256, 0, stream>>>(W2, W216, 512, NF, 256, 512 * 256);
    pad_b1_kernel<<<1, 256, 0, stream>>>(b1, b1p);

    dim3 g256(2, CMc / 128);
    dim3 gU(8, CBc / 16);
    int gLN = CMc / 64;

    for (int c = 0; c < NCH; ++c) {
        const float* srcC = src + (size_t)c * CMc * NF;
        float* outC = out + (size_t)c * CBc;

        // fused QKV + attention -> AO16 (bf16), 512 threads / 8 waves
        qkv_attn_kernel<<<CBc, 512, 0, stream>>>(srcC, Wf, T4, AO16);
        // y1 = (AO16@Wo^T + bo) + LN(...) -> bf16 (fused)
        gemm_ln<1><<<gLN, 512, 0, stream>>>(AO16, Wo16, bo, lnw, lnb, Y116, 512);
        // act = relu(y1 @ W116^T + b1p) -> bf16 [CMc,256]
        gemm_bf16<1, true><<<g256, 256, 0, stream>>>(Y116, W116, b1p, ACT16, 512, 256);
        // y2 = (act@W2^T + b2) + LN(...) -> f32 (fused)
        gemm_ln<0><<<gLN, 512, 0, stream>>>(ACT16, W216, b2, lnw, lnb, Y2, 256);
        // pooling head
        u_stage1_kernel<<<gU, 256, 0, stream>>>(Y2, Wt, T1);
        u_stage2_kernel<<<gU, 256, 0, stream>>>(T1, Wt, U);
        pool_kernel<<<CBc, 256, 0, stream>>>(Y2, U, Wout, bout, outC);
    }

    (void)in_sizes; (void)n_in; (void)out_size; (void)ws_size;
}

// Round 10
// 1484.036 us; speedup vs baseline: 5.1089x; 1.0457x over previous
//
#include <hip/hip_runtime.h>
#include <math.h>

#define NB 2048
#define NS 100
#define NF 158
#define ND 512
#define NH 8

typedef unsigned short u16;
typedef __attribute__((ext_vector_type(8))) short bf16x8;
typedef __attribute__((ext_vector_type(8))) unsigned short u16x8;
typedef __attribute__((ext_vector_type(4))) float f32x4;

__device__ __forceinline__ u16 f2bf(float f) {
    union { float f; unsigned u; } v; v.f = f;
    unsigned u = v.u;
    return (u16)((u + 0x7fffu + ((u >> 16) & 1u)) >> 16);   // RNE
}

__device__ __forceinline__ float bf2f(u16 v) {
    union { unsigned u; float f; } x; x.u = ((unsigned)v) << 16; return x.f;
}

__device__ __forceinline__ void gload16(const void* g, void* l) {
    __builtin_amdgcn_global_load_lds(
        (const __attribute__((address_space(1))) unsigned*)g,
        (__attribute__((address_space(3))) unsigned*)l, 16, 0, 0);
}

// 8 f32 -> bf16x8 with tail guard at NF (src rows 8B aligned -> float2)
__device__ __forceinline__ bf16x8 load8_cvt(const float* __restrict__ base, int c0) {
    bf16x8 r;
    if (c0 + 8 <= NF) {
        #pragma unroll
        for (int j = 0; j < 8; j += 2) {
            float2 v = *(const float2*)(base + c0 + j);
            r[j] = (short)f2bf(v.x); r[j + 1] = (short)f2bf(v.y);
        }
    } else {
        #pragma unroll
        for (int j = 0; j < 8; ++j)
            r[j] = (c0 + j < NF) ? (short)f2bf(base[c0 + j]) : (short)0;
    }
    return r;
}

// ---------------------------------------------------------------------------
// prep_w: folded QKV weights -> MFMA-B-fragment layout.
// For sel in {0(q),1(k)}: head-dim PERMUTED mapping  d = 4*l16 + ni
//   (S = QK^T is invariant under identical d-permutation of Q and K; this
//    makes each lane hold 4 consecutive dims -> b64 LDS writes in the fused
//    kernel). For sel==2(v): natural mapping (PV/O-store unchanged).
// ---------------------------------------------------------------------------
__global__ __launch_bounds__(256) void prep_w_kernel(
    const float* __restrict__ Wq, const float* __restrict__ Wk,
    const float* __restrict__ Wv, const float* __restrict__ Wfeat,
    u16* __restrict__ Wf)
{
    int bid = blockIdx.x;           // 0..1535
    int sel = bid >> 9;
    int n = bid & 511;
    const float* Wsrc = (sel == 0) ? Wq : (sel == 1) ? Wk : Wv;
    __shared__ float wrow[ND];
    int t = threadIdx.x;
    wrow[t] = Wsrc[(size_t)n * ND + t];
    wrow[t + 256] = Wsrc[(size_t)n * ND + t + 256];
    __syncthreads();
    if (t < 160) {
        float acc = 0.f;
        if (t < NF)
            for (int d = 0; d < ND; ++d)
                acc += wrow[d] * Wfeat[(size_t)d * NF + t];
        int h = n >> 6, local = n & 63;
        int ni, l16;
        if (sel < 2) { ni = local & 3; l16 = local >> 2; }       // permuted
        else         { ni = (local >> 4) & 3; l16 = local & 15; } // natural
        int ks = t >> 5, quad = (t >> 3) & 3, j = t & 7;
        size_t idx = (((((size_t)sel * 8 + h) * 4 + ni) * 5 + ks) * 64
                      + (quad << 4) + l16) * 8 + j;
        Wf[idx] = f2bf(acc);
    }
}

// ---------------------------------------------------------------------------
// prep_c: T4[(sel*8+h)*100+s][idx64] = (b_feat+pe[s])@W[n,:]+b[n]
//   sel<2: idx64 = local dim d (natural order; lane l16 reads float4 at 4*l16)
//   sel==2: idx64 = (l16<<2)|ni  (old per-lane layout)
// ---------------------------------------------------------------------------
__global__ __launch_bounds__(256) void prep_c_kernel(
    const float* __restrict__ Wq, const float* __restrict__ Wk, const float* __restrict__ Wv,
    const float* __restrict__ bq, const float* __restrict__ bk, const float* __restrict__ bv,
    const float* __restrict__ bfeat, const float* __restrict__ pe,
    float* __restrict__ T4)
{
    int bid = blockIdx.x;           // 0..299
    int sel = bid / 100;
    int s = bid - sel * 100;
    const float* Wsrc = (sel == 0) ? Wq : (sel == 1) ? Wk : Wv;
    const float* bsrc = (sel == 0) ? bq : (sel == 1) ? bk : bv;
    __shared__ float xv[ND];
    int t = threadIdx.x;
    xv[t] = bfeat[t] + pe[(size_t)s * ND + t];
    xv[t + 256] = bfeat[t + 256] + pe[(size_t)s * ND + t + 256];
    __syncthreads();
    #pragma unroll
    for (int rr = 0; rr < 2; ++rr) {
        int r = t + (rr << 8);
        const float* wr = Wsrc + (size_t)r * ND;
        float acc = bsrc[r];
        for (int d = 0; d < ND; d += 4) {
            float4 w4 = *(const float4*)(wr + d);
            acc += w4.x * xv[d] + w4.y * xv[d+1] + w4.z * xv[d+2] + w4.w * xv[d+3];
        }
        int h = r >> 6, local = r & 63;
        int idx64 = (sel < 2) ? local : (((local & 15) << 2) | (local >> 4));
        T4[(((size_t)(sel * 8 + h)) * 100 + s) * 64 + idx64] = acc;
    }
}

// ---------------------------------------------------------------------------
__global__ __launch_bounds__(256) void pad_cast_kernel(
    const float* __restrict__ src, u16* __restrict__ dst,
    int R, int C, int Cp, int total)
{
    int idx = blockIdx.x * 256 + threadIdx.x;
    if (idx >= total) return;
    int r = idx / Cp, c = idx - r * Cp;
    float v = (r < R && c < C) ? src[(size_t)r * C + c] : 0.f;
    dst[idx] = f2bf(v);
}

__global__ __launch_bounds__(256) void pad_b1_kernel(
    const float* __restrict__ b1, float* __restrict__ b1p)
{
    int t = threadIdx.x;
    b1p[t] = (t < NF) ? b1[t] : 0.f;
}

// ---------------------------------------------------------------------------
// FUSED QKV + attention, 512 threads (8 waves x 16 rows).
// Q/K head-dims permuted (see prep_w) -> b64 LDS writes; V natural.
// ---------------------------------------------------------------------------
#define ALDQ 72     // Ks row stride (shorts)
#define ALDP 136    // UN (Q/P) and Vt row stride (shorts)

__global__ __launch_bounds__(512, 4) void qkv_attn_kernel(
    const float* __restrict__ src, const u16* __restrict__ Wf,
    const float* __restrict__ T4, u16* __restrict__ O)
{
    __shared__ short UN[128 * ALDP];   // Q (cols 0..63), later P (cols 0..127)
    __shared__ short Ks[112 * ALDQ];
    __shared__ short Vt[64 * ALDP];

    int t = threadIdx.x;
    int lane = t & 63, wave = t >> 6;       // wave 0..7
    int quad = lane >> 4, l16 = lane & 15;
    int rows0 = wave << 4;                  // this wave's 16 rows
    int b = blockIdx.x;
    const float* xb = src + (size_t)b * NS * NF;
    const size_t rowbase = (size_t)b * NS;
    f32x4 z = {0.f, 0.f, 0.f, 0.f};

    // static zero pads (persist across heads)
    for (int l = t; l < 12 * ALDQ; l += 512)
        Ks[(100 + l / ALDQ) * ALDQ + (l % ALDQ)] = 0;
    for (int l = t; l < 64 * 28; l += 512) {
        int d = l / 28, s = 100 + (l - d * 28);
        Vt[d * ALDP + s] = 0;
    }

    // X A-fragments for this wave's 16 rows (rows >= 100 -> zero), in VGPRs
    int arow = rows0 + l16;
    bf16x8 AF[5];
    {
        const float* xr = xb + (size_t)arow * NF;
        #pragma unroll
        for (int ks = 0; ks < 5; ++ks) {
            if (arow < NS) AF[ks] = load8_cvt(xr, (ks << 5) + (quad << 3));
            else { bf16x8 zz = {0,0,0,0,0,0,0,0}; AF[ks] = zz; }
        }
    }

    for (int h = 0; h < NH; ++h) {
        // ---- q/k/v for head h (this wave: 16 rows x 64 head-dims)
        #pragma unroll
        for (int sel = 0; sel < 3; ++sel) {
            f32x4 acc[4];
            #pragma unroll
            for (int ni = 0; ni < 4; ++ni) acc[ni] = z;
            #pragma unroll
            for (int ks = 0; ks < 5; ++ks) {
                bf16x8 wfr[4];
                #pragma unroll
                for (int ni = 0; ni < 4; ++ni)
                    wfr[ni] = *(const bf16x8*)(Wf +
                        (((((size_t)sel * 8 + h) * 4 + ni) * 5 + ks) * 64 + lane) * 8);
                #pragma unroll
                for (int ni = 0; ni < 4; ++ni)
                    acc[ni] = __builtin_amdgcn_mfma_f32_16x16x32_bf16(
                        AF[ks], wfr[ni], acc[ni], 0, 0, 0);
            }
            // epilogue: +T4, bf16 -> LDS
            #pragma unroll
            for (int r = 0; r < 4; ++r) {
                int row_s = rows0 + (quad << 2) + r;
                bool real = row_s < NS;
                float4 tv = make_float4(0.f, 0.f, 0.f, 0.f);
                if (real)
                    tv = *(const float4*)(T4 +
                        (((size_t)(sel * 8 + h)) * 100 + row_s) * 64 + (l16 << 2));
                if (sel < 2) {
                    // permuted: lane holds dims 4*l16..4*l16+3 -> one b64 write
                    ushort4 pk;
                    pk.x = f2bf(acc[0][r] + tv.x);
                    pk.y = f2bf(acc[1][r] + tv.y);
                    pk.z = f2bf(acc[2][r] + tv.z);
                    pk.w = f2bf(acc[3][r] + tv.w);
                    if (sel == 0) *(ushort4*)&UN[row_s * ALDP + (l16 << 2)] = pk;  // Q (pad rows = 0)
                    else if (real) *(ushort4*)&Ks[row_s * ALDQ + (l16 << 2)] = pk;
                } else {
                    float tvs[4] = {tv.x, tv.y, tv.z, tv.w};
                    #pragma unroll
                    for (int ni = 0; ni < 4; ++ni) {
                        int nloc = (ni << 4) + l16;
                        float v = acc[ni][r] + tvs[ni];
                        if (real) Vt[nloc * ALDP + row_s] = (short)f2bf(v);
                    }
                }
            }
        }
        __syncthreads();

        // ---- S = Q K^T  (1 row-tile x 7 col-tiles per wave, K=64 permuted dims)
        f32x4 sc[7];
        #pragma unroll
        for (int ni = 0; ni < 7; ++ni) sc[ni] = z;
        #pragma unroll
        for (int ks = 0; ks < 2; ++ks) {
            bf16x8 aq = *(const bf16x8*)&UN[(rows0 + l16) * ALDP + (ks << 5) + (quad << 3)];
            bf16x8 bk[7];
            #pragma unroll
            for (int ni = 0; ni < 7; ++ni)
                bk[ni] = *(const bf16x8*)&Ks[((ni << 4) + l16) * ALDQ + (ks << 5) + (quad << 3)];
            #pragma unroll
            for (int ni = 0; ni < 7; ++ni)
                sc[ni] = __builtin_amdgcn_mfma_f32_16x16x32_bf16(aq, bk[ni], sc[ni], 0, 0, 0);
        }
        __syncthreads();   // all waves done reading Q before P overwrites UN

        // ---- softmax in registers; P (bf16) into UN stride 136
        #pragma unroll
        for (int r = 0; r < 4; ++r) {
            if (l16 >= 4) sc[6][r] = -3.0e38f;   // cols 100..111 masked
            float mx = sc[0][r];
            #pragma unroll
            for (int ni = 1; ni < 7; ++ni) mx = fmaxf(mx, sc[ni][r]);
            #pragma unroll
            for (int off = 1; off < 16; off <<= 1) mx = fmaxf(mx, __shfl_xor(mx, off));
            float sum = 0.f;
            #pragma unroll
            for (int ni = 0; ni < 7; ++ni) {
                float e = expf((sc[ni][r] - mx) * 0.125f);
                sc[ni][r] = e; sum += e;
            }
            #pragma unroll
            for (int off = 1; off < 16; off <<= 1) sum += __shfl_xor(sum, off);
            float inv = 1.f / sum;
            int row = rows0 + (quad << 2) + r;
            #pragma unroll
            for (int ni = 0; ni < 7; ++ni)
                UN[row * ALDP + (ni << 4) + l16] = (short)f2bf(sc[ni][r] * inv);
            UN[row * ALDP + 112 + l16] = 0;      // zero K-pad cols
        }
        __syncthreads();

        // ---- O = P V  (K=128)
        f32x4 oa[4];
        #pragma unroll
        for (int ni = 0; ni < 4; ++ni) oa[ni] = z;
        #pragma unroll
        for (int ks = 0; ks < 4; ++ks) {
            bf16x8 ap = *(const bf16x8*)&UN[(rows0 + l16) * ALDP + (ks << 5) + (quad << 3)];
            bf16x8 bv[4];
            #pragma unroll
            for (int ni = 0; ni < 4; ++ni)
                bv[ni] = *(const bf16x8*)&Vt[((ni << 4) + l16) * ALDP + (ks << 5) + (quad << 3)];
            #pragma unroll
            for (int ni = 0; ni < 4; ++ni)
                oa[ni] = __builtin_amdgcn_mfma_f32_16x16x32_bf16(ap, bv[ni], oa[ni], 0, 0, 0);
        }
        #pragma unroll
        for (int r = 0; r < 4; ++r) {
            int row = rows0 + (quad << 2) + r;
            if (row < NS) {
                u16* orow = O + (rowbase + row) * 512 + (h << 6);
                #pragma unroll
                for (int ni = 0; ni < 4; ++ni)
                    orow[(ni << 4) + l16] = f2bf(oa[ni][r]);
            }
        }
        __syncthreads();   // before next head rewrites UN/Ks/Vt
    }
}

// ---------------------------------------------------------------------------
// Generic bf16 GEMM (used for FFN1): 128x128 tile, BK=32.
// ---------------------------------------------------------------------------
template<int OUTMODE, bool RELU>
__global__ __launch_bounds__(256) void gemm_bf16(
    const u16* __restrict__ A, const u16* __restrict__ W,
    const float* __restrict__ bias, void* __restrict__ Cv, int K, int ldc)
{
    __shared__ short As[128 * 32];
    __shared__ short Bs[128 * 32];
    int t = threadIdx.x;
    int lane = t & 63, wave = t >> 6;
    int quad = lane >> 4, l16 = lane & 15;
    int wr = wave >> 1, wc = wave & 1;
    int m0 = blockIdx.y << 7, n0 = blockIdx.x << 7;

    f32x4 acc[4][4];
    f32x4 z = {0.f, 0.f, 0.f, 0.f};
    #pragma unroll
    for (int mi = 0; mi < 4; ++mi)
        #pragma unroll
        for (int ni = 0; ni < 4; ++ni) acc[mi][ni] = z;

    int rowA = t >> 2;
    int cch = (t & 3) << 3;
    const u16* aSrc0 = A + (size_t)(m0 + rowA) * K + cch;
    const u16* aSrc1 = A + (size_t)(m0 + rowA + 64) * K + cch;
    const u16* bSrc0 = W + (size_t)(n0 + rowA) * K + cch;
    const u16* bSrc1 = W + (size_t)(n0 + rowA + 64) * K + cch;
    short* aDst0 = As + t * 8;
    short* aDst1 = As + (t + 256) * 8;
    short* bDst0 = Bs + t * 8;
    short* bDst1 = Bs + (t + 256) * 8;

    int nk = K >> 5;
    for (int kc = 0; kc < nk; ++kc) {
        if (kc) __syncthreads();
        gload16(aSrc0, aDst0);
        gload16(aSrc1, aDst1);
        gload16(bSrc0, bDst0);
        gload16(bSrc1, bDst1);
        aSrc0 += 32; aSrc1 += 32; bSrc0 += 32; bSrc1 += 32;
        __syncthreads();

        bf16x8 af[4], bw[4];
        #pragma unroll
        for (int mi = 0; mi < 4; ++mi)
            af[mi] = *(const bf16x8*)(As + ((size_t)((wr << 6) + (mi << 4) + l16) * 32 + (quad << 3)));
        #pragma unroll
        for (int ni = 0; ni < 4; ++ni)
            bw[ni] = *(const bf16x8*)(Bs + ((size_t)((wc << 6) + (ni << 4) + l16) * 32 + (quad << 3)));
        #pragma unroll
        for (int mi = 0; mi < 4; ++mi)
            #pragma unroll
            for (int ni = 0; ni < 4; ++ni)
                acc[mi][ni] = __builtin_amdgcn_mfma_f32_16x16x32_bf16(af[mi], bw[ni], acc[mi][ni], 0, 0, 0);
    }

    #pragma unroll
    for (int mi = 0; mi < 4; ++mi) {
        #pragma unroll
        for (int r = 0; r < 4; ++r) {
            int row = m0 + (wr << 6) + (mi << 4) + (quad << 2) + r;
            #pragma unroll
            for (int ni = 0; ni < 4; ++ni) {
                int col = n0 + (wc << 6) + (ni << 4) + l16;
                float v = acc[mi][ni][r];
                if (bias) v += bias[col];
                if (RELU) v = fmaxf(v, 0.f);
                if (OUTMODE == 0)
                    ((float*)Cv)[(size_t)row * ldc + col] = v;
                else
                    ((u16*)Cv)[(size_t)row * ldc + col] = f2bf(v);
            }
        }
    }
}

// ---------------------------------------------------------------------------
// Fused GEMM + add-LayerNorm epilogue (proven R6-R9).
// ---------------------------------------------------------------------------
template<int OUTMODE>
__global__ __launch_bounds__(512, 2) void gemm_ln(
    const u16* __restrict__ A, const u16* __restrict__ W,
    const float* __restrict__ bias, const float* __restrict__ lnw,
    const float* __restrict__ lnb, void* __restrict__ outv, int K)
{
    __shared__ short As[64 * 32];
    __shared__ short Bs[512 * 32];
    __shared__ float red_s[64][9];
    __shared__ float red_q[64][9];
    __shared__ float mrow[64], rrow[64];

    int t = threadIdx.x;
    int lane = t & 63, wave = t >> 6;
    int quad = lane >> 4, l16 = lane & 15;
    int m0 = blockIdx.x << 6;

    f32x4 acc[4][4];
    f32x4 z = {0.f, 0.f, 0.f, 0.f};
    #pragma unroll
    for (int mi = 0; mi < 4; ++mi)
        #pragma unroll
        for (int ni = 0; ni < 4; ++ni) acc[mi][ni] = z;

    int koff = (t & 3) << 3;
    const u16* aSrc = A + (size_t)(m0 + (t >> 2)) * K + koff;
    const u16* bSrc0 = W + (size_t)(t >> 2) * K + koff;
    const u16* bSrc1 = W + (size_t)((t >> 2) + 128) * K + koff;
    const u16* bSrc2 = W + (size_t)((t >> 2) + 256) * K + koff;
    const u16* bSrc3 = W + (size_t)((t >> 2) + 384) * K + koff;
    short* aDst = As + t * 8;
    short* bDst0 = Bs + t * 8;
    short* bDst1 = Bs + (t + 512) * 8;
    short* bDst2 = Bs + (t + 1024) * 8;
    short* bDst3 = Bs + (t + 1536) * 8;

    int nk = K >> 5;
    for (int kc = 0; kc < nk; ++kc) {
        if (kc) __syncthreads();
        if (t < 256) gload16(aSrc, aDst);
        gload16(bSrc0, bDst0);
        gload16(bSrc1, bDst1);
        gload16(bSrc2, bDst2);
        gload16(bSrc3, bDst3);
        aSrc += 32; bSrc0 += 32; bSrc1 += 32; bSrc2 += 32; bSrc3 += 32;
        __syncthreads();

        bf16x8 af[4], bw[4];
        #pragma unroll
        for (int mi = 0; mi < 4; ++mi)
            af[mi] = *(const bf16x8*)(As + ((mi << 4) + l16) * 32 + (quad << 3));
        #pragma unroll
        for (int ni = 0; ni < 4; ++ni)
            bw[ni] = *(const bf16x8*)(Bs + ((wave << 6) + (ni << 4) + l16) * 32 + (quad << 3));
        #pragma unroll
        for (int mi = 0; mi < 4; ++mi)
            #pragma unroll
            for (int ni = 0; ni < 4; ++ni)
                acc[mi][ni] = __builtin_amdgcn_mfma_f32_16x16x32_bf16(af[mi], bw[ni], acc[mi][ni], 0, 0, 0);
    }

    float lwv[4], lbv[4];
    #pragma unroll
    for (int ni = 0; ni < 4; ++ni) {
        int col = (wave << 6) + (ni << 4) + l16;
        float bv = bias[col];
        lwv[ni] = lnw[col];
        lbv[ni] = lnb[col];
        #pragma unroll
        for (int mi = 0; mi < 4; ++mi)
            #pragma unroll
            for (int r = 0; r < 4; ++r) acc[mi][ni][r] += bv;
    }
    #pragma unroll
    for (int mi = 0; mi < 4; ++mi) {
        #pragma unroll
        for (int r = 0; r < 4; ++r) {
            float s = acc[mi][0][r] + acc[mi][1][r] + acc[mi][2][r] + acc[mi][3][r];
            float q = acc[mi][0][r]*acc[mi][0][r] + acc[mi][1][r]*acc[mi][1][r]
                    + acc[mi][2][r]*acc[mi][2][r] + acc[mi][3][r]*acc[mi][3][r];
            #pragma unroll
            for (int off = 1; off < 16; off <<= 1) {
                s += __shfl_xor(s, off);
                q += __shfl_xor(q, off);
            }
            if (l16 == 0) {
                int row = (mi << 4) + (quad << 2) + r;
                red_s[row][wave] = s;
                red_q[row][wave] = q;
            }
        }
    }
    __syncthreads();
    if (t < 64) {
        float s = 0.f, q = 0.f;
        #pragma unroll
        for (int w8 = 0; w8 < 8; ++w8) { s += red_s[t][w8]; q += red_q[t][w8]; }
        float mean = s * (1.f / 512.f);
        float var = q * (1.f / 512.f) - mean * mean;
        mrow[t] = mean;
        rrow[t] = rsqrtf(var + 1e-5f);
    }
    __syncthreads();
    #pragma unroll
    for (int mi = 0; mi < 4; ++mi) {
        #pragma unroll
        for (int r = 0; r < 4; ++r) {
            int lrow = (mi << 4) + (quad << 2) + r;
            float mean = mrow[lrow], rstd = rrow[lrow];
            size_t grow = (size_t)(m0 + lrow) * 512;
            #pragma unroll
            for (int ni = 0; ni < 4; ++ni) {
                int col = (wave << 6) + (ni << 4) + l16;
                float v = acc[mi][ni][r];
                float y = v + (v - mean) * rstd * lwv[ni] + lbv[ni];
                if (OUTMODE == 0) ((float*)outv)[grow + col] = y;
                else ((u16*)outv)[grow + col] = f2bf(y);
            }
        }
    }
}

// ---------------------------------------------------------------------------
// u_stage1: T1[b,r] = dot(Wt[r,:], Y2[b, last, :])    (Y2 now bf16)
// ---------------------------------------------------------------------------
__global__ __launch_bounds__(256) void u_stage1_kernel(
    const u16* __restrict__ Y2, const float* __restrict__ Wt,
    float* __restrict__ T1)
{
    __shared__ float yl[16][512];
    int t = threadIdx.x;
    int r0 = blockIdx.x << 6;
    int bg = blockIdx.y << 4;
    for (int l = t; l < 1024; l += 256) {       // 16 rows x 512 cols / 8
        int bb = l >> 6, seg = (l & 63) << 3;
        u16x8 v = *(const u16x8*)&Y2[((size_t)(bg + bb) * NS + 99) * ND + seg];
        #pragma unroll
        for (int j = 0; j < 8; ++j) yl[bb][seg + j] = bf2f(v[j]);
    }
    __syncthreads();
    int r = r0 + (t & 63);
    int b0 = t >> 6;
    const float* wr = Wt + (size_t)r * ND;
    float acc[4] = {0.f, 0.f, 0.f, 0.f};
    for (int d = 0; d < ND; d += 4) {
        float4 w4 = *(const float4*)(wr + d);
        #pragma unroll
        for (int bb = 0; bb < 4; ++bb) {
            int bl = (b0 << 2) + bb;
            acc[bb] += w4.x * yl[bl][d] + w4.y * yl[bl][d+1]
                     + w4.z * yl[bl][d+2] + w4.w * yl[bl][d+3];
        }
    }
    #pragma unroll
    for (int bb = 0; bb < 4; ++bb)
        T1[(size_t)(bg + (b0 << 2) + bb) * ND + r] = acc[bb];
}

__global__ __launch_bounds__(256) void u_stage2_kernel(
    const float* __restrict__ T1, const float* __restrict__ Wt,
    float* __restrict__ U)
{
    __shared__ float t1s[16][512];
    int t = threadIdx.x;
    int c0 = blockIdx.x << 6;
    int bg = blockIdx.y << 4;
    for (int l = t; l < 2048; l += 256) {
        int bb = l >> 7, seg = (l & 127) << 2;
        *(float4*)&t1s[bb][seg] = *(const float4*)&T1[(size_t)(bg + bb) * ND + seg];
    }
    __syncthreads();
    int c = c0 + (t & 63);
    int b0 = t >> 6;
    float acc[4] = {0.f, 0.f, 0.f, 0.f};
    for (int r = 0; r < ND; ++r) {
        float w = Wt[(size_t)r * ND + c];
        #pragma unroll
        for (int bb = 0; bb < 4; ++bb)
            acc[bb] += w * t1s[(b0 << 2) + bb][r];
    }
    #pragma unroll
    for (int bb = 0; bb < 4; ++bb)
        U[(size_t)(bg + (b0 << 2) + bb) * ND + c] = acc[bb];
}

// ---------------------------------------------------------------------------
// pool (Y2 bf16): lam = softmax_s(y2[b,s]·u[b]); out = (sum lam_s y2[b,s])·Wout+b
// ---------------------------------------------------------------------------
__global__ __launch_bounds__(256) void pool_kernel(
    const u16* __restrict__ Y2, const float* __restrict__ U,
    const float* __restrict__ Wout, const float* __restrict__ bout,
    float* __restrict__ out)
{
    __shared__ float u[ND];
    __shared__ float lam[128];
    __shared__ float red[4];
    int t = threadIdx.x;
    int b = blockIdx.x;
    const u16* y2b = Y2 + (size_t)b * NS * ND;
    u[t] = U[(size_t)b * ND + t];
    u[t + 256] = U[(size_t)b * ND + t + 256];
    __syncthreads();
    int wid = t >> 6, lane = t & 63;
    int c0 = lane << 2;
    for (int s = wid; s < NS; s += 4) {
        const u16* yr = y2b + (size_t)s * ND;
        ushort4 q0 = *(const ushort4*)(yr + c0);
        ushort4 q1 = *(const ushort4*)(yr + 256 + c0);
        float a = bf2f(q0.x)*u[c0] + bf2f(q0.y)*u[c0+1] + bf2f(q0.z)*u[c0+2] + bf2f(q0.w)*u[c0+3]
                + bf2f(q1.x)*u[256+c0] + bf2f(q1.y)*u[256+c0+1]
                + bf2f(q1.z)*u[256+c0+2] + bf2f(q1.w)*u[256+c0+3];
        #pragma unroll
        for (int off = 32; off > 0; off >>= 1) a += __shfl_xor(a, off);
        if (lane == 0) lam[s] = a;
    }
    __syncthreads();
    if (t < 64) {
        float l0 = lam[t];
        float l1 = (t + 64 < NS) ? lam[t + 64] : -3.0e38f;
        float mx = fmaxf(l0, l1);
        #pragma unroll
        for (int off = 32; off > 0; off >>= 1) mx = fmaxf(mx, __shfl_xor(mx, off));
        float e0 = expf(l0 - mx);
        float e1 = (t + 64 < NS) ? expf(l1 - mx) : 0.f;
        float ssum = e0 + e1;
        #pragma unroll
        for (int off = 32; off > 0; off >>= 1) ssum += __shfl_xor(ssum, off);
        float inv = 1.f / ssum;
        lam[t] = e0 * inv;
        if (t + 64 < NS) lam[t + 64] = e1 * inv;
    }
    __syncthreads();
    float p0 = 0.f, p1 = 0.f;
    for (int s = 0; s < NS; ++s) {
        float lm = lam[s];
        const u16* yr = y2b + (size_t)s * ND;
        p0 += lm * bf2f(yr[t]);
        p1 += lm * bf2f(yr[t + 256]);
    }
    float vd = p0 * Wout[t] + p1 * Wout[t + 256];
    #pragma unroll
    for (int off = 32; off > 0; off >>= 1) vd += __shfl_xor(vd, off);
    if (lane == 0) red[wid] = vd;
    __syncthreads();
    if (t == 0) out[b] = red[0] + red[1] + red[2] + red[3] + bout[0];
}

// ---------------------------------------------------------------------------
static size_t ws_need(int CBc) {
    size_t cm = (size_t)CBc * NS;
    size_t b = 0;
    b += cm * 512 * 2;         // AO16
    b += cm * 512 * 2;         // Y116
    b += cm * 256 * 2;         // ACT16
    b += cm * 512 * 2;         // Y2 (bf16)
    b += (size_t)CBc * 512 * 4 * 2;  // T1, U
    b += 1536 * 160 * 2;       // Wf
    b += 512 * 512 * 2 + 256 * 512 * 2 + 512 * 256 * 2;
    b += 3 * 8 * 100 * 64 * 4; // T4
    b += 256 * 4;
    b += 64 * 1024;
    return b;
}

extern "C" void kernel_launch(void* const* d_in, const int* in_sizes, int n_in,
                              void* d_out, int out_size, void* d_ws, size_t ws_size,
                              hipStream_t stream)
{
    const float* src   = (const float*)d_in[0];
    const float* Wfeat = (const float*)d_in[1];
    const float* bfeat = (const float*)d_in[2];
    const float* pe    = (const float*)d_in[3];
    const float* Wq    = (const float*)d_in[4];
    const float* bq    = (const float*)d_in[5];
    const float* Wk    = (const float*)d_in[6];
    const float* bk    = (const float*)d_in[7];
    const float* Wv    = (const float*)d_in[8];
    const float* bv    = (const float*)d_in[9];
    const float* Wo    = (const float*)d_in[10];
    const float* bo    = (const float*)d_in[11];
    const float* lnw   = (const float*)d_in[12];
    const float* lnb   = (const float*)d_in[13];
    const float* W1    = (const float*)d_in[14];
    const float* b1    = (const float*)d_in[15];
    const float* W2    = (const float*)d_in[16];
    const float* b2    = (const float*)d_in[17];
    const float* Wt    = (const float*)d_in[18];
    const float* Wout  = (const float*)d_in[19];
    const float* bout  = (const float*)d_in[20];
    float* out = (float*)d_out;

    int CBc = (ws_size >= ws_need(1024)) ? 1024
            : (ws_size >= ws_need(512))  ? 512
            : (ws_size >= ws_need(256))  ? 256 : 128;
    int NCH = NB / CBc;
    size_t CMc = (size_t)CBc * NS;

    char* p = (char*)d_ws;
    auto alloc = [&](size_t bytes) { char* r = p; p += (bytes + 255) & ~(size_t)255; return r; };
    u16*   AO16  = (u16*)  alloc(CMc * 512 * 2);
    u16*   Y116  = (u16*)  alloc(CMc * 512 * 2);
    u16*   ACT16 = (u16*)  alloc(CMc * 256 * 2);
    u16*   Y2    = (u16*)  alloc(CMc * 512 * 2);
    float* T1    = (float*)alloc((size_t)CBc * 512 * 4);
    float* U     = (float*)alloc((size_t)CBc * 512 * 4);
    u16*   Wf    = (u16*)  alloc(1536 * 160 * 2);
    u16*   Wo16  = (u16*)  alloc(512 * 512 * 2);
    u16*   W116  = (u16*)  alloc(256 * 512 * 2);
    u16*   W216  = (u16*)  alloc(512 * 256 * 2);
    float* T4    = (float*)alloc(3 * 8 * 100 * 64 * 4);
    float* b1p   = (float*)alloc(256 * 4);

    prep_w_kernel<<<1536, 256, 0, stream>>>(Wq, Wk, Wv, Wfeat, Wf);
    prep_c_kernel<<<300, 256, 0, stream>>>(Wq, Wk, Wv, bq, bk, bv, bfeat, pe, T4);
    pad_cast_kernel<<<(512 * 512) / 256, 256, 0, stream>>>(Wo, Wo16, 512, 512, 512, 512 * 512);
    pad_cast_kernel<<<(256 * 512) / 256, 256, 0, stream>>>(W1, W116, NF, 512, 512, 256 * 512);
    pad_cast_kernel<<<(512 * 256) / 256, 256, 0, stream>>>(W2, W216, 512, NF, 256, 512 * 256);
    pad_b1_kernel<<<1, 256, 0, stream>>>(b1, b1p);

    dim3 g256(2, CMc / 128);
    dim3 gU(8, CBc / 16);
    int gLN = CMc / 64;

    for (int c = 0; c < NCH; ++c) {
        const float* srcC = src + (size_t)c * CMc * NF;
        float* outC = out + (size_t)c * CBc;

        // fused QKV + attention -> AO16 (bf16)
        qkv_attn_kernel<<<CBc, 512, 0, stream>>>(srcC, Wf, T4, AO16);
        // y1 = (AO16@Wo^T + bo) + LN(...) -> bf16 (fused)
        gemm_ln<1><<<gLN, 512, 0, stream>>>(AO16, Wo16, bo, lnw, lnb, Y116, 512);
        // act = relu(y1 @ W116^T + b1p) -> bf16 [CMc,256]
        gemm_bf16<1, true><<<g256, 256, 0, stream>>>(Y116, W116, b1p, ACT16, 512, 256);
        // y2 = (act@W2^T + b2) + LN(...) -> bf16 (fused)
        gemm_ln<1><<<gLN, 512, 0, stream>>>(ACT16, W216, b2, lnw, lnb, Y2, 256);
        // pooling head
        u_stage1_kernel<<<gU, 256, 0, stream>>>(Y2, Wt, T1);
        u_stage2_kernel<<<gU, 256, 0, stream>>>(T1, Wt, U);
        pool_kernel<<<CBc, 256, 0, stream>>>(Y2, U, Wout, bout, outC);
    }

    (void)in_sizes; (void)n_in; (void)out_size; (void)ws_size;
}